// Round 2
// baseline (1457.314 us; speedup 1.0000x reference)
//
#include <hip/hip_runtime.h>
#include <math.h>

// ---------------------------------------------------------------------------
// CoarseMVSNet fused implementation, depth-chunked for occupancy.
//  setup_mats_kernel  : compose K@E per view, invert ref, P = src @ inv(ref)
//  transpose_cl_kernel: (V,C,H,W) -> (V,H,W,C) channel-last copy in ws
//  cost_kernel        : warp + variance + conv3d for a DC-slice depth chunk;
//                       EPI=true additionally fuses the softmax head (DC==D)
//  epilogue_kernel    : softmax/depth/conf/exp-var from global cost volume
// ---------------------------------------------------------------------------

__global__ void setup_mats_kernel(const float* __restrict__ proj1,
                                  const float* __restrict__ proj2,
                                  const float* __restrict__ depthv, int nd,
                                  float* __restrict__ ws) {
  if (threadIdx.x != 0 || blockIdx.x != 0) return;
  for (int s = 0; s < 2; ++s) {
    const float* P = s ? proj2 : proj1;  // (3,2,4,4) flat
    double comp[3][4][4];
    for (int v = 0; v < 3; ++v) {
      const float* E = P + v * 32;       // [v][0]
      const float* K = P + v * 32 + 16;  // [v][1]
      for (int r = 0; r < 3; ++r)
        for (int c = 0; c < 4; ++c) {
          double acc = 0.0;
          for (int k = 0; k < 3; ++k) acc += (double)K[r * 4 + k] * (double)E[k * 4 + c];
          comp[v][r][c] = acc;
        }
      for (int c = 0; c < 4; ++c) comp[v][3][c] = (double)E[12 + c];
    }
    double a[4][8];
    for (int r = 0; r < 4; ++r)
      for (int c = 0; c < 4; ++c) {
        a[r][c] = comp[0][r][c];
        a[r][4 + c] = (r == c) ? 1.0 : 0.0;
      }
    for (int col = 0; col < 4; ++col) {
      int piv = col;
      double best = fabs(a[col][col]);
      for (int r = col + 1; r < 4; ++r) {
        double t = fabs(a[r][col]);
        if (t > best) { best = t; piv = r; }
      }
      if (piv != col)
        for (int c = 0; c < 8; ++c) { double t = a[col][c]; a[col][c] = a[piv][c]; a[piv][c] = t; }
      double dv = a[col][col];
      for (int c = 0; c < 8; ++c) a[col][c] /= dv;
      for (int r = 0; r < 4; ++r)
        if (r != col) {
          double f = a[r][col];
          if (f != 0.0)
            for (int c = 0; c < 8; ++c) a[r][c] -= f * a[col][c];
        }
    }
    for (int v = 1; v < 3; ++v) {
      double Pm[3][4];
      for (int r = 0; r < 3; ++r)
        for (int c = 0; c < 4; ++c) {
          double acc = 0.0;
          for (int k = 0; k < 4; ++k) acc += comp[v][r][k] * a[k][4 + c];
          Pm[r][c] = acc;
        }
      float* o = ws + s * 24 + (v - 1) * 12;
      o[0] = (float)Pm[0][0]; o[1] = (float)Pm[0][1]; o[2] = (float)Pm[0][2];
      o[3] = (float)Pm[1][0]; o[4] = (float)Pm[1][1]; o[5] = (float)Pm[1][2];
      o[6] = (float)Pm[2][0]; o[7] = (float)Pm[2][1]; o[8] = (float)Pm[2][2];
      o[9] = (float)Pm[0][3]; o[10] = (float)Pm[1][3]; o[11] = (float)Pm[2][3];
    }
  }
  ws[48] = depthv[0];
  ws[49] = (depthv[nd - 1] - depthv[0]) / 47.0f;  // (dmax-dmin)/(ND1-1)
}

__global__ void transpose_cl_kernel(const float* __restrict__ in, float* __restrict__ out,
                                    int C, int H, int W) {
  int total = 3 * C * H * W;
  int idx = blockIdx.x * 256 + threadIdx.x;
  if (idx >= total) return;
  int c = idx % C;
  int t = idx / C;
  int w = t % W;
  int t2 = t / W;
  int h = t2 % H;
  int v = t2 / H;
  out[idx] = in[((size_t)(v * C + c) * H + h) * W + w];
}

// C channels, DTOT total depths, DC owned cost slices per block (blockIdx.z),
// TH x TW tile, H x W image. STAGE2: per-pixel samples from upsampled d1/v1.
// CL: channel-last feats. EPI: DC==DTOT, fuse softmax head, no global cost.
template <int C, int DTOT, int DC, int TH, int TW, int H, int W, bool STAGE2, bool CL, bool EPI>
__launch_bounds__(256, 4)
__global__ void cost_kernel(const float* __restrict__ feats,
                            const float* __restrict__ wconv,
                            const float* __restrict__ bconv,
                            const float* __restrict__ mats,
                            const float* __restrict__ dpar,
                            const float* __restrict__ prev_d,
                            const float* __restrict__ prev_v,
                            float* __restrict__ g_cost,
                            float* __restrict__ out_d,
                            float* __restrict__ out_c,
                            float* __restrict__ out_v) {
  constexpr int HB = TH + 2, WB = TW + 2, HALO = HB * WB, NPX = TH * TW;
  constexpr int HP = HALO + 1;  // pad leading dim -> conv reads conflict-light
  constexpr int C4 = C / 4;
  constexpr int CG = C / 4;     // channels per conv thread group (4 groups)
  constexpr int NS = DC + 2;

  __shared__ float s_var[C * HP];
  __shared__ float s_cost[DC * NPX];
  __shared__ float s_w[C * 27];
  __shared__ float s_rx[2][HALO], s_ry[2][HALO], s_rz[2][HALO];
  __shared__ float s_w00[2][HALO], s_w10[2][HALO], s_w01[2][HALO], s_w11[2][HALO];
  __shared__ int s_i00[2][HALO], s_i10[2][HALO], s_i01[2][HALO], s_i11[2][HALO];
  __shared__ int s_gidx[HALO];
  __shared__ float s_dbase[HALO], s_dstep[HALO];
  __shared__ unsigned char s_inb[HALO];

  const int tid = threadIdx.x;
  const int h0 = blockIdx.y * TH;
  const int w0 = blockIdx.x * TW;
  const int d0 = EPI ? 0 : blockIdx.z * DC;

  for (int i = tid; i < C * 27; i += 256) s_w[i] = wconv[i];

  // per-halo-pixel precompute: rot@[x,y,1] per view; depth sample base/step
  for (int i = tid; i < HALO; i += 256) {
    int hy = i / WB, hx = i - hy * WB;
    int gy = h0 + hy - 1, gx = w0 + hx - 1;
    bool inb = (gy >= 0) && (gy < H) && (gx >= 0) && (gx < W);
    s_inb[i] = inb ? 1 : 0;
    s_gidx[i] = inb ? (gy * W + gx) : 0;
    float fx = (float)gx, fy = (float)gy;
#pragma unroll
    for (int v = 0; v < 2; ++v) {
      const float* M = mats + v * 12;
      s_rx[v][i] = M[0] * fx + M[1] * fy + M[2];
      s_ry[v][i] = M[3] * fx + M[4] * fy + M[5];
      s_rz[v][i] = M[6] * fx + M[7] * fy + M[8];
    }
    if constexpr (STAGE2) {
      constexpr int SH = H / 2, SW = W / 2;
      // jax.image.resize bilinear 2x: src = (i+0.5)*0.5-0.5, edge-clamped
      float syf = 0.5f * (float)gy - 0.25f;
      float sxf = 0.5f * (float)gx - 0.25f;
      syf = fminf(fmaxf(syf, 0.0f), (float)(SH - 1));
      sxf = fminf(fmaxf(sxf, 0.0f), (float)(SW - 1));
      int sy0 = (int)syf, sx0 = (int)sxf;
      float fy2 = syf - (float)sy0, fx2 = sxf - (float)sx0;
      int sy1 = min(sy0 + 1, SH - 1), sx1 = min(sx0 + 1, SW - 1);
      int j00 = sy0 * SW + sx0, j01 = sy0 * SW + sx1;
      int j10 = sy1 * SW + sx0, j11 = sy1 * SW + sx1;
      float cd = (prev_d[j00] * (1.f - fx2) + prev_d[j01] * fx2) * (1.f - fy2) +
                 (prev_d[j10] * (1.f - fx2) + prev_d[j11] * fx2) * fy2;
      float cv = (prev_v[j00] * (1.f - fx2) + prev_v[j01] * fx2) * (1.f - fy2) +
                 (prev_v[j10] * (1.f - fx2) + prev_v[j11] * fx2) * fy2;
      float lo = -fminf(cd, cv);
      s_dbase[i] = cd + lo + 1e-12f;
      s_dstep[i] = (cv - lo) / (float)(DTOT - 1);
    } else {
      s_dbase[i] = dpar[0];
      s_dstep[i] = dpar[1];
    }
  }
  {
    float bias = bconv[0];
    for (int i = tid; i < DC * NPX; i += 256) s_cost[i] = bias;
  }
  __syncthreads();

  // scatter conv contribution of variance slice ds into owned cost slices
  auto conv_accum = [&](int ds) {
    for (int i = tid; i < NPX * 4; i += 256) {
      int grp = i / NPX, opx = i - grp * NPX;  // grp wave-uniform (NPX=64)
      int py = opx / TW, pxx = opx - py * TW;
      float a0 = 0.f, a1 = 0.f, a2 = 0.f;  // kd = 0,1,2
      int cbase = grp * CG;
#pragma unroll
      for (int kh = 0; kh < 3; ++kh) {
#pragma unroll
        for (int kw = 0; kw < 3; ++kw) {
          int hp = (py + kh) * WB + (pxx + kw);
#pragma unroll
          for (int cc = 0; cc < CG; ++cc) {
            int c = cbase + cc;
            float vv = s_var[c * HP + hp];
            const float* wp = s_w + c * 27 + kh * 3 + kw;
            a0 += vv * wp[0];
            a1 += vv * wp[9];
            a2 += vv * wp[18];
          }
        }
      }
      int t0 = ds + 1 - d0;  // cost slice fed by kd=0
      int t1 = ds - d0;      // kd=1
      int t2 = ds - 1 - d0;  // kd=2
      if (t0 >= 0 && t0 < DC) atomicAdd(&s_cost[t0 * NPX + opx], a0);
      if (t1 >= 0 && t1 < DC) atomicAdd(&s_cost[t1 * NPX + opx], a1);
      if (t2 >= 0 && t2 < DC) atomicAdd(&s_cost[t2 * NPX + opx], a2);
    }
  };

  int prev_ds = 0;
  bool prev_valid = false;
  for (int s = 0; s < NS; ++s) {
    const int ds = d0 - 1 + s;
    const bool valid = (ds >= 0) && (ds < DTOT);
    if (prev_valid) conv_accum(prev_ds);  // reads s_var, disjoint from coords
    if (valid) {
      for (int i = tid; i < 2 * HALO; i += 256) {
        int v = (i >= HALO) ? 1 : 0;
        int px = i - v * HALO;
        float dep = s_dbase[px] + (float)ds * s_dstep[px];
        const float* M = mats + v * 12;
        float X = s_rx[v][px] * dep + M[9];
        float Y = s_ry[v][px] * dep + M[10];
        float Z = s_rz[v][px] * dep + M[11];
        float xz = X / Z, yz = Y / Z;
        float gxn = xz * (2.0f / (float)(W - 1)) - 1.0f;
        float gyn = yz * (2.0f / (float)(H - 1)) - 1.0f;
        float ix = ((gxn + 1.0f) * (float)W - 1.0f) * 0.5f;
        float iy = ((gyn + 1.0f) * (float)H - 1.0f) * 0.5f;
        float x0f = floorf(ix), y0f = floorf(iy);
        float wx = ix - x0f, wy = iy - y0f;
        float x1f = x0f + 1.0f, y1f = y0f + 1.0f;
        bool vx0 = (x0f >= 0.0f) && (x0f <= (float)(W - 1));
        bool vx1 = (x1f >= 0.0f) && (x1f <= (float)(W - 1));
        bool vy0 = (y0f >= 0.0f) && (y0f <= (float)(H - 1));
        bool vy1 = (y1f >= 0.0f) && (y1f <= (float)(H - 1));
        int xc0 = (int)fminf(fmaxf(x0f, 0.0f), (float)(W - 1));
        int xc1 = (int)fminf(fmaxf(x1f, 0.0f), (float)(W - 1));
        int yc0 = (int)fminf(fmaxf(y0f, 0.0f), (float)(H - 1));
        int yc1 = (int)fminf(fmaxf(y1f, 0.0f), (float)(H - 1));
        s_i00[v][px] = yc0 * W + xc0;
        s_i10[v][px] = yc0 * W + xc1;
        s_i01[v][px] = yc1 * W + xc0;
        s_i11[v][px] = yc1 * W + xc1;
        float wxm = 1.0f - wx, wym = 1.0f - wy;
        s_w00[v][px] = (vx0 && vy0) ? wxm * wym : 0.0f;
        s_w10[v][px] = (vx1 && vy0) ? wx * wym : 0.0f;
        s_w01[v][px] = (vx0 && vy1) ? wxm * wy : 0.0f;
        s_w11[v][px] = (vx1 && vy1) ? wx * wy : 0.0f;
      }
    }
    __syncthreads();
    if (valid) {
      if constexpr (CL) {
        for (int i = tid; i < HALO * C4; i += 256) {
          int cg = i / HALO, px = i - cg * HALO;
          float o0 = 0.f, o1 = 0.f, o2 = 0.f, o3 = 0.f;
          if (s_inb[px]) {
            const float4* fp = (const float4*)feats;
            float4 r = fp[(size_t)s_gidx[px] * C4 + cg];
            float s0 = r.x, s1 = r.y, s2 = r.z, s3 = r.w;
            float q0 = r.x * r.x, q1 = r.y * r.y, q2 = r.z * r.z, q3 = r.w * r.w;
#pragma unroll
            for (int v = 0; v < 2; ++v) {
              const float4* fv = fp + (size_t)(v + 1) * H * W * C4 + cg;
              float a00 = s_w00[v][px], a10 = s_w10[v][px];
              float a01 = s_w01[v][px], a11 = s_w11[v][px];
              float4 p00 = fv[(size_t)s_i00[v][px] * C4];
              float4 p10 = fv[(size_t)s_i10[v][px] * C4];
              float4 p01 = fv[(size_t)s_i01[v][px] * C4];
              float4 p11 = fv[(size_t)s_i11[v][px] * C4];
              float g0 = a00 * p00.x + a10 * p10.x + a01 * p01.x + a11 * p11.x;
              float g1 = a00 * p00.y + a10 * p10.y + a01 * p01.y + a11 * p11.y;
              float g2 = a00 * p00.z + a10 * p10.z + a01 * p01.z + a11 * p11.z;
              float g3 = a00 * p00.w + a10 * p10.w + a01 * p01.w + a11 * p11.w;
              s0 += g0; q0 += g0 * g0;
              s1 += g1; q1 += g1 * g1;
              s2 += g2; q2 += g2 * g2;
              s3 += g3; q3 += g3 * g3;
            }
            float m;
            m = s0 / 3.0f; o0 = q0 / 3.0f - m * m;
            m = s1 / 3.0f; o1 = q1 / 3.0f - m * m;
            m = s2 / 3.0f; o2 = q2 / 3.0f - m * m;
            m = s3 / 3.0f; o3 = q3 / 3.0f - m * m;
          }
          int cb = cg * 4;
          s_var[(cb + 0) * HP + px] = o0;
          s_var[(cb + 1) * HP + px] = o1;
          s_var[(cb + 2) * HP + px] = o2;
          s_var[(cb + 3) * HP + px] = o3;
        }
      } else {
        for (int i = tid; i < HALO * C; i += 256) {
          int c = i / HALO, px = i - c * HALO;
          float var = 0.f;
          if (s_inb[px]) {
            const float* f0 = feats + (size_t)c * (H * W);
            float rr = f0[s_gidx[px]];
            float sum = rr, ssq = rr * rr;
#pragma unroll
            for (int v = 0; v < 2; ++v) {
              const float* fv = feats + ((size_t)(v + 1) * C + c) * (H * W);
              float val = s_w00[v][px] * fv[s_i00[v][px]] + s_w10[v][px] * fv[s_i10[v][px]] +
                          s_w01[v][px] * fv[s_i01[v][px]] + s_w11[v][px] * fv[s_i11[v][px]];
              sum += val;
              ssq += val * val;
            }
            float m = sum / 3.0f;
            var = ssq / 3.0f - m * m;
          }
          s_var[c * HP + px] = var;
        }
      }
    }
    __syncthreads();
    prev_ds = ds;
    prev_valid = valid;
  }
  if (prev_valid) conv_accum(prev_ds);
  __syncthreads();

  if constexpr (!EPI) {
    // write owned cost slices, [d][pix] layout (coalesced epilogue reads)
    for (int i = tid; i < DC * NPX; i += 256) {
      int dd = i / NPX, opx = i - dd * NPX;
      int py = opx / TW, pxx = opx - py * TW;
      g_cost[(size_t)(d0 + dd) * (H * W) + (h0 + py) * W + (w0 + pxx)] = s_cost[i];
    }
  } else if (tid < NPX) {
    // fused epilogue: softmax over D, depth, conf (4-tap), exp-var
    const int opx = tid;
    const int py = opx / TW, pxx = opx - py * TW;
    const int hp = (py + 1) * WB + (pxx + 1);
    const float base = s_dbase[hp], st = s_dstep[hp];
    float mx = -3.0e38f;
    for (int dd = 0; dd < DTOT; ++dd) mx = fmaxf(mx, s_cost[dd * NPX + opx]);
    float se = 0.f;
    for (int dd = 0; dd < DTOT; ++dd) {
      float e = expf(s_cost[dd * NPX + opx] - mx);
      s_cost[dd * NPX + opx] = e;
      se += e;
    }
    float depth = 0.f, dif = 0.f;
    for (int dd = 0; dd < DTOT; ++dd) {
      float p = s_cost[dd * NPX + opx] / se;
      s_cost[dd * NPX + opx] = p;
      depth += p * (base + (float)dd * st);
      dif += p * (float)dd;
    }
    int di = (int)dif;
    di = min(max(di, 0), DTOT - 1);
    float conf = 0.f;
    for (int k = di - 1; k <= di + 2; ++k)
      if (k >= 0 && k < DTOT) conf += s_cost[k * NPX + opx];
    float ev = 0.f;
    for (int dd = 0; dd < DTOT; ++dd) {
      float sv = base + (float)dd * st - depth;
      ev += sv * sv * s_cost[dd * NPX + opx];
    }
    ev = 1.5f * sqrtf(ev);
    int gy = h0 + py, gx = w0 + pxx;
    out_d[gy * W + gx] = depth;
    out_c[gy * W + gx] = conf;
    out_v[gy * W + gx] = ev;
  }
}

template <int D, int H, int W>
__global__ void epilogue_kernel(const float* __restrict__ g_cost,
                                const float* __restrict__ dpar,
                                float* __restrict__ out_d,
                                float* __restrict__ out_c,
                                float* __restrict__ out_v) {
  int pix = blockIdx.x * 256 + threadIdx.x;
  if (pix >= H * W) return;
  const float base = dpar[0], st = dpar[1];
  float c[D];
#pragma unroll
  for (int dd = 0; dd < D; ++dd) c[dd] = g_cost[(size_t)dd * (H * W) + pix];
  float mx = -3.0e38f;
#pragma unroll
  for (int dd = 0; dd < D; ++dd) mx = fmaxf(mx, c[dd]);
  float se = 0.f;
#pragma unroll
  for (int dd = 0; dd < D; ++dd) {
    float e = expf(c[dd] - mx);
    c[dd] = e;
    se += e;
  }
  float depth = 0.f, dif = 0.f;
#pragma unroll
  for (int dd = 0; dd < D; ++dd) {
    float p = c[dd] / se;
    c[dd] = p;
    depth += p * (base + (float)dd * st);
    dif += p * (float)dd;
  }
  int di = (int)dif;
  di = min(max(di, 0), D - 1);
  float conf = 0.f;
#pragma unroll
  for (int dd = 0; dd < D; ++dd)
    if (dd >= di - 1 && dd <= di + 2) conf += c[dd];
  float depth2 = 0.f;
  float ev = 0.f;
#pragma unroll
  for (int dd = 0; dd < D; ++dd) {
    float sv = base + (float)dd * st - depth;
    ev += sv * sv * c[dd];
  }
  (void)depth2;
  ev = 1.5f * sqrtf(ev);
  out_d[pix] = depth;
  out_c[pix] = conf;
  out_v[pix] = ev;
}

extern "C" void kernel_launch(void* const* d_in, const int* in_sizes, int n_in,
                              void* d_out, int out_size, void* d_ws, size_t ws_size,
                              hipStream_t stream) {
  const float* feats1 = (const float*)d_in[0];
  const float* feats2 = (const float*)d_in[1];
  const float* proj1 = (const float*)d_in[2];
  const float* proj2 = (const float*)d_in[3];
  const float* depthv = (const float*)d_in[4];
  const float* w1 = (const float*)d_in[6];
  const float* b1 = (const float*)d_in[7];
  const float* w2 = (const float*)d_in[8];
  const float* b2 = (const float*)d_in[9];
  float* out = (float*)d_out;
  float* ws = (float*)d_ws;

  const int nd = in_sizes[4];
  const size_t F1 = (size_t)3 * 32 * 128 * 160;
  const size_t F2 = (size_t)3 * 16 * 256 * 320;
  const size_t COST1 = (size_t)48 * 128 * 160;  // 983040 floats
  const bool mid = ws_size >= (64 + COST1) * sizeof(float);
  const bool big = ws_size >= (64 + COST1 + F1 + F2) * sizeof(float);

  setup_mats_kernel<<<1, 64, 0, stream>>>(proj1, proj2, depthv, nd, ws);

  float* d1 = out;
  float* c1 = out + 20480;
  float* v1 = out + 40960;
  float* d2 = out + 61440;
  float* c2 = out + 143360;
  float* v2 = out + 225280;

  float* cost1 = ws + 64;
  dim3 g1c(160 / 8, 128 / 8, 6), g1f(160 / 8, 128 / 8, 1), g2(320 / 8, 256 / 8, 1);

  if (big) {
    float* f1t = ws + 64 + COST1;
    float* f2t = f1t + F1;
    transpose_cl_kernel<<<(int)((F1 + 255) / 256), 256, 0, stream>>>(feats1, f1t, 32, 128, 160);
    transpose_cl_kernel<<<(int)((F2 + 255) / 256), 256, 0, stream>>>(feats2, f2t, 16, 256, 320);
    cost_kernel<32, 48, 8, 8, 8, 128, 160, false, true, false><<<g1c, 256, 0, stream>>>(
        f1t, w1, b1, ws, ws + 48, nullptr, nullptr, cost1, nullptr, nullptr, nullptr);
    epilogue_kernel<48, 128, 160><<<80, 256, 0, stream>>>(cost1, ws + 48, d1, c1, v1);
    cost_kernel<16, 8, 8, 8, 8, 256, 320, true, true, true><<<g2, 256, 0, stream>>>(
        f2t, w2, b2, ws + 24, ws + 48, d1, v1, nullptr, d2, c2, v2);
  } else if (mid) {
    cost_kernel<32, 48, 8, 8, 8, 128, 160, false, false, false><<<g1c, 256, 0, stream>>>(
        feats1, w1, b1, ws, ws + 48, nullptr, nullptr, cost1, nullptr, nullptr, nullptr);
    epilogue_kernel<48, 128, 160><<<80, 256, 0, stream>>>(cost1, ws + 48, d1, c1, v1);
    cost_kernel<16, 8, 8, 8, 8, 256, 320, true, false, true><<<g2, 256, 0, stream>>>(
        feats2, w2, b2, ws + 24, ws + 48, d1, v1, nullptr, d2, c2, v2);
  } else {
    cost_kernel<32, 48, 48, 8, 8, 128, 160, false, false, true><<<g1f, 256, 0, stream>>>(
        feats1, w1, b1, ws, ws + 48, nullptr, nullptr, nullptr, d1, c1, v1);
    cost_kernel<16, 8, 8, 8, 8, 256, 320, true, false, true><<<g2, 256, 0, stream>>>(
        feats2, w2, b2, ws + 24, ws + 48, d1, v1, nullptr, d2, c2, v2);
  }
}

// Round 3
// 768.127 us; speedup vs baseline: 1.8972x; 1.8972x over previous
//
#include <hip/hip_runtime.h>
#include <math.h>

// ---------------------------------------------------------------------------
// CoarseMVSNet fused implementation, depth-chunked for occupancy.
//  setup_mats_kernel  : compose K@E per view, invert ref, P = src @ inv(ref)
//  transpose_cl_kernel: (V,C,H,W) -> (V,H,W,C) channel-last copy in ws
//  cost_kernel        : warp + variance + conv3d for a DC-slice depth chunk;
//                       EPI=true additionally fuses the softmax head (DC==D)
//  epilogue_kernel    : softmax/depth/conf/exp-var from global cost volume
// NOTE: __launch_bounds__(256) ONLY — (256,4) forced VGPR 132->64 and caused
// 4.2 GB/dispatch of scratch spill traffic (R2 post-mortem).
// ---------------------------------------------------------------------------

__global__ void setup_mats_kernel(const float* __restrict__ proj1,
                                  const float* __restrict__ proj2,
                                  const float* __restrict__ depthv, int nd,
                                  float* __restrict__ ws) {
  if (threadIdx.x != 0 || blockIdx.x != 0) return;
  for (int s = 0; s < 2; ++s) {
    const float* P = s ? proj2 : proj1;  // (3,2,4,4) flat
    double comp[3][4][4];
    for (int v = 0; v < 3; ++v) {
      const float* E = P + v * 32;       // [v][0]
      const float* K = P + v * 32 + 16;  // [v][1]
      for (int r = 0; r < 3; ++r)
        for (int c = 0; c < 4; ++c) {
          double acc = 0.0;
          for (int k = 0; k < 3; ++k) acc += (double)K[r * 4 + k] * (double)E[k * 4 + c];
          comp[v][r][c] = acc;
        }
      for (int c = 0; c < 4; ++c) comp[v][3][c] = (double)E[12 + c];
    }
    double a[4][8];
    for (int r = 0; r < 4; ++r)
      for (int c = 0; c < 4; ++c) {
        a[r][c] = comp[0][r][c];
        a[r][4 + c] = (r == c) ? 1.0 : 0.0;
      }
    for (int col = 0; col < 4; ++col) {
      int piv = col;
      double best = fabs(a[col][col]);
      for (int r = col + 1; r < 4; ++r) {
        double t = fabs(a[r][col]);
        if (t > best) { best = t; piv = r; }
      }
      if (piv != col)
        for (int c = 0; c < 8; ++c) { double t = a[col][c]; a[col][c] = a[piv][c]; a[piv][c] = t; }
      double dv = a[col][col];
      for (int c = 0; c < 8; ++c) a[col][c] /= dv;
      for (int r = 0; r < 4; ++r)
        if (r != col) {
          double f = a[r][col];
          if (f != 0.0)
            for (int c = 0; c < 8; ++c) a[r][c] -= f * a[col][c];
        }
    }
    for (int v = 1; v < 3; ++v) {
      double Pm[3][4];
      for (int r = 0; r < 3; ++r)
        for (int c = 0; c < 4; ++c) {
          double acc = 0.0;
          for (int k = 0; k < 4; ++k) acc += comp[v][r][k] * a[k][4 + c];
          Pm[r][c] = acc;
        }
      float* o = ws + s * 24 + (v - 1) * 12;
      o[0] = (float)Pm[0][0]; o[1] = (float)Pm[0][1]; o[2] = (float)Pm[0][2];
      o[3] = (float)Pm[1][0]; o[4] = (float)Pm[1][1]; o[5] = (float)Pm[1][2];
      o[6] = (float)Pm[2][0]; o[7] = (float)Pm[2][1]; o[8] = (float)Pm[2][2];
      o[9] = (float)Pm[0][3]; o[10] = (float)Pm[1][3]; o[11] = (float)Pm[2][3];
    }
  }
  ws[48] = depthv[0];
  ws[49] = (depthv[nd - 1] - depthv[0]) / 47.0f;  // (dmax-dmin)/(ND1-1)
}

__global__ void transpose_cl_kernel(const float* __restrict__ in, float* __restrict__ out,
                                    int C, int H, int W) {
  int total = 3 * C * H * W;
  int idx = blockIdx.x * 256 + threadIdx.x;
  if (idx >= total) return;
  int c = idx % C;
  int t = idx / C;
  int w = t % W;
  int t2 = t / W;
  int h = t2 % H;
  int v = t2 / H;
  out[idx] = in[((size_t)(v * C + c) * H + h) * W + w];
}

// C channels, DTOT total depths, DC owned cost slices per block (blockIdx.z),
// TH x TW tile, H x W image. STAGE2: per-pixel samples from upsampled d1/v1.
// CL: channel-last feats. EPI: DC==DTOT, fuse softmax head, no global cost.
template <int C, int DTOT, int DC, int TH, int TW, int H, int W, bool STAGE2, bool CL, bool EPI>
__launch_bounds__(256)
__global__ void cost_kernel(const float* __restrict__ feats,
                            const float* __restrict__ wconv,
                            const float* __restrict__ bconv,
                            const float* __restrict__ mats,
                            const float* __restrict__ dpar,
                            const float* __restrict__ prev_d,
                            const float* __restrict__ prev_v,
                            float* __restrict__ g_cost,
                            float* __restrict__ out_d,
                            float* __restrict__ out_c,
                            float* __restrict__ out_v) {
  constexpr int HB = TH + 2, WB = TW + 2, HALO = HB * WB, NPX = TH * TW;
  constexpr int HP = HALO + 1;  // pad leading dim -> conv reads conflict-light
  constexpr int C4 = C / 4;
  constexpr int CG = C / 4;     // channels per conv thread group (4 groups)
  constexpr int NS = DC + 2;

  __shared__ float s_var[C * HP];
  __shared__ float s_cost[DC * NPX];
  __shared__ float s_w[C * 27];
  __shared__ float s_rx[2][HALO], s_ry[2][HALO], s_rz[2][HALO];
  __shared__ float s_w00[2][HALO], s_w10[2][HALO], s_w01[2][HALO], s_w11[2][HALO];
  __shared__ int s_i00[2][HALO], s_i10[2][HALO], s_i01[2][HALO], s_i11[2][HALO];
  __shared__ int s_gidx[HALO];
  __shared__ float s_dbase[HALO], s_dstep[HALO];
  __shared__ unsigned char s_inb[HALO];

  const int tid = threadIdx.x;
  const int h0 = blockIdx.y * TH;
  const int w0 = blockIdx.x * TW;
  const int d0 = EPI ? 0 : blockIdx.z * DC;

  for (int i = tid; i < C * 27; i += 256) s_w[i] = wconv[i];

  // per-halo-pixel precompute: rot@[x,y,1] per view; depth sample base/step
  for (int i = tid; i < HALO; i += 256) {
    int hy = i / WB, hx = i - hy * WB;
    int gy = h0 + hy - 1, gx = w0 + hx - 1;
    bool inb = (gy >= 0) && (gy < H) && (gx >= 0) && (gx < W);
    s_inb[i] = inb ? 1 : 0;
    s_gidx[i] = inb ? (gy * W + gx) : 0;
    float fx = (float)gx, fy = (float)gy;
#pragma unroll
    for (int v = 0; v < 2; ++v) {
      const float* M = mats + v * 12;
      s_rx[v][i] = M[0] * fx + M[1] * fy + M[2];
      s_ry[v][i] = M[3] * fx + M[4] * fy + M[5];
      s_rz[v][i] = M[6] * fx + M[7] * fy + M[8];
    }
    if constexpr (STAGE2) {
      constexpr int SH = H / 2, SW = W / 2;
      // jax.image.resize bilinear 2x: src = (i+0.5)*0.5-0.5, edge-clamped
      float syf = 0.5f * (float)gy - 0.25f;
      float sxf = 0.5f * (float)gx - 0.25f;
      syf = fminf(fmaxf(syf, 0.0f), (float)(SH - 1));
      sxf = fminf(fmaxf(sxf, 0.0f), (float)(SW - 1));
      int sy0 = (int)syf, sx0 = (int)sxf;
      float fy2 = syf - (float)sy0, fx2 = sxf - (float)sx0;
      int sy1 = min(sy0 + 1, SH - 1), sx1 = min(sx0 + 1, SW - 1);
      int j00 = sy0 * SW + sx0, j01 = sy0 * SW + sx1;
      int j10 = sy1 * SW + sx0, j11 = sy1 * SW + sx1;
      float cd = (prev_d[j00] * (1.f - fx2) + prev_d[j01] * fx2) * (1.f - fy2) +
                 (prev_d[j10] * (1.f - fx2) + prev_d[j11] * fx2) * fy2;
      float cv = (prev_v[j00] * (1.f - fx2) + prev_v[j01] * fx2) * (1.f - fy2) +
                 (prev_v[j10] * (1.f - fx2) + prev_v[j11] * fx2) * fy2;
      float lo = -fminf(cd, cv);
      s_dbase[i] = cd + lo + 1e-12f;
      s_dstep[i] = (cv - lo) / (float)(DTOT - 1);
    } else {
      s_dbase[i] = dpar[0];
      s_dstep[i] = dpar[1];
    }
  }
  {
    float bias = bconv[0];
    for (int i = tid; i < DC * NPX; i += 256) s_cost[i] = bias;
  }
  __syncthreads();

  // scatter conv contribution of variance slice ds into owned cost slices
  auto conv_accum = [&](int ds) {
    for (int i = tid; i < NPX * 4; i += 256) {
      int grp = i / NPX, opx = i - grp * NPX;  // grp wave-uniform (NPX=64)
      int py = opx / TW, pxx = opx - py * TW;
      float a0 = 0.f, a1 = 0.f, a2 = 0.f;  // kd = 0,1,2
      int cbase = grp * CG;
#pragma unroll
      for (int kh = 0; kh < 3; ++kh) {
#pragma unroll
        for (int kw = 0; kw < 3; ++kw) {
          int hp = (py + kh) * WB + (pxx + kw);
#pragma unroll
          for (int cc = 0; cc < CG; ++cc) {
            int c = cbase + cc;
            float vv = s_var[c * HP + hp];
            const float* wp = s_w + c * 27 + kh * 3 + kw;
            a0 += vv * wp[0];
            a1 += vv * wp[9];
            a2 += vv * wp[18];
          }
        }
      }
      int t0 = ds + 1 - d0;  // cost slice fed by kd=0
      int t1 = ds - d0;      // kd=1
      int t2 = ds - 1 - d0;  // kd=2
      if (t0 >= 0 && t0 < DC) atomicAdd(&s_cost[t0 * NPX + opx], a0);
      if (t1 >= 0 && t1 < DC) atomicAdd(&s_cost[t1 * NPX + opx], a1);
      if (t2 >= 0 && t2 < DC) atomicAdd(&s_cost[t2 * NPX + opx], a2);
    }
  };

  int prev_ds = 0;
  bool prev_valid = false;
  for (int s = 0; s < NS; ++s) {
    const int ds = d0 - 1 + s;
    const bool valid = (ds >= 0) && (ds < DTOT);
    if (prev_valid) conv_accum(prev_ds);  // reads s_var, disjoint from coords
    if (valid) {
      for (int i = tid; i < 2 * HALO; i += 256) {
        int v = (i >= HALO) ? 1 : 0;
        int px = i - v * HALO;
        float dep = s_dbase[px] + (float)ds * s_dstep[px];
        const float* M = mats + v * 12;
        float X = s_rx[v][px] * dep + M[9];
        float Y = s_ry[v][px] * dep + M[10];
        float Z = s_rz[v][px] * dep + M[11];
        float xz = X / Z, yz = Y / Z;
        float gxn = xz * (2.0f / (float)(W - 1)) - 1.0f;
        float gyn = yz * (2.0f / (float)(H - 1)) - 1.0f;
        float ix = ((gxn + 1.0f) * (float)W - 1.0f) * 0.5f;
        float iy = ((gyn + 1.0f) * (float)H - 1.0f) * 0.5f;
        float x0f = floorf(ix), y0f = floorf(iy);
        float wx = ix - x0f, wy = iy - y0f;
        float x1f = x0f + 1.0f, y1f = y0f + 1.0f;
        bool vx0 = (x0f >= 0.0f) && (x0f <= (float)(W - 1));
        bool vx1 = (x1f >= 0.0f) && (x1f <= (float)(W - 1));
        bool vy0 = (y0f >= 0.0f) && (y0f <= (float)(H - 1));
        bool vy1 = (y1f >= 0.0f) && (y1f <= (float)(H - 1));
        int xc0 = (int)fminf(fmaxf(x0f, 0.0f), (float)(W - 1));
        int xc1 = (int)fminf(fmaxf(x1f, 0.0f), (float)(W - 1));
        int yc0 = (int)fminf(fmaxf(y0f, 0.0f), (float)(H - 1));
        int yc1 = (int)fminf(fmaxf(y1f, 0.0f), (float)(H - 1));
        s_i00[v][px] = yc0 * W + xc0;
        s_i10[v][px] = yc0 * W + xc1;
        s_i01[v][px] = yc1 * W + xc0;
        s_i11[v][px] = yc1 * W + xc1;
        float wxm = 1.0f - wx, wym = 1.0f - wy;
        s_w00[v][px] = (vx0 && vy0) ? wxm * wym : 0.0f;
        s_w10[v][px] = (vx1 && vy0) ? wx * wym : 0.0f;
        s_w01[v][px] = (vx0 && vy1) ? wxm * wy : 0.0f;
        s_w11[v][px] = (vx1 && vy1) ? wx * wy : 0.0f;
      }
    }
    __syncthreads();
    if (valid) {
      if constexpr (CL) {
        for (int i = tid; i < HALO * C4; i += 256) {
          int cg = i / HALO, px = i - cg * HALO;
          float o0 = 0.f, o1 = 0.f, o2 = 0.f, o3 = 0.f;
          if (s_inb[px]) {
            const float4* fp = (const float4*)feats;
            float4 r = fp[(size_t)s_gidx[px] * C4 + cg];
            float s0 = r.x, s1 = r.y, s2 = r.z, s3 = r.w;
            float q0 = r.x * r.x, q1 = r.y * r.y, q2 = r.z * r.z, q3 = r.w * r.w;
#pragma unroll
            for (int v = 0; v < 2; ++v) {
              const float4* fv = fp + (size_t)(v + 1) * H * W * C4 + cg;
              float a00 = s_w00[v][px], a10 = s_w10[v][px];
              float a01 = s_w01[v][px], a11 = s_w11[v][px];
              float4 p00 = fv[(size_t)s_i00[v][px] * C4];
              float4 p10 = fv[(size_t)s_i10[v][px] * C4];
              float4 p01 = fv[(size_t)s_i01[v][px] * C4];
              float4 p11 = fv[(size_t)s_i11[v][px] * C4];
              float g0 = a00 * p00.x + a10 * p10.x + a01 * p01.x + a11 * p11.x;
              float g1 = a00 * p00.y + a10 * p10.y + a01 * p01.y + a11 * p11.y;
              float g2 = a00 * p00.z + a10 * p10.z + a01 * p01.z + a11 * p11.z;
              float g3 = a00 * p00.w + a10 * p10.w + a01 * p01.w + a11 * p11.w;
              s0 += g0; q0 += g0 * g0;
              s1 += g1; q1 += g1 * g1;
              s2 += g2; q2 += g2 * g2;
              s3 += g3; q3 += g3 * g3;
            }
            float m;
            m = s0 / 3.0f; o0 = q0 / 3.0f - m * m;
            m = s1 / 3.0f; o1 = q1 / 3.0f - m * m;
            m = s2 / 3.0f; o2 = q2 / 3.0f - m * m;
            m = s3 / 3.0f; o3 = q3 / 3.0f - m * m;
          }
          int cb = cg * 4;
          s_var[(cb + 0) * HP + px] = o0;
          s_var[(cb + 1) * HP + px] = o1;
          s_var[(cb + 2) * HP + px] = o2;
          s_var[(cb + 3) * HP + px] = o3;
        }
      } else {
        for (int i = tid; i < HALO * C; i += 256) {
          int c = i / HALO, px = i - c * HALO;
          float var = 0.f;
          if (s_inb[px]) {
            const float* f0 = feats + (size_t)c * (H * W);
            float rr = f0[s_gidx[px]];
            float sum = rr, ssq = rr * rr;
#pragma unroll
            for (int v = 0; v < 2; ++v) {
              const float* fv = feats + ((size_t)(v + 1) * C + c) * (H * W);
              float val = s_w00[v][px] * fv[s_i00[v][px]] + s_w10[v][px] * fv[s_i10[v][px]] +
                          s_w01[v][px] * fv[s_i01[v][px]] + s_w11[v][px] * fv[s_i11[v][px]];
              sum += val;
              ssq += val * val;
            }
            float m = sum / 3.0f;
            var = ssq / 3.0f - m * m;
          }
          s_var[c * HP + px] = var;
        }
      }
    }
    __syncthreads();
    prev_ds = ds;
    prev_valid = valid;
  }
  if (prev_valid) conv_accum(prev_ds);
  __syncthreads();

  if constexpr (!EPI) {
    // write owned cost slices, [d][pix] layout (coalesced epilogue reads)
    for (int i = tid; i < DC * NPX; i += 256) {
      int dd = i / NPX, opx = i - dd * NPX;
      int py = opx / TW, pxx = opx - py * TW;
      g_cost[(size_t)(d0 + dd) * (H * W) + (h0 + py) * W + (w0 + pxx)] = s_cost[i];
    }
  } else if (tid < NPX) {
    // fused epilogue: softmax over D, depth, conf (4-tap), exp-var
    const int opx = tid;
    const int py = opx / TW, pxx = opx - py * TW;
    const int hp = (py + 1) * WB + (pxx + 1);
    const float base = s_dbase[hp], st = s_dstep[hp];
    float mx = -3.0e38f;
    for (int dd = 0; dd < DTOT; ++dd) mx = fmaxf(mx, s_cost[dd * NPX + opx]);
    float se = 0.f;
    for (int dd = 0; dd < DTOT; ++dd) {
      float e = expf(s_cost[dd * NPX + opx] - mx);
      s_cost[dd * NPX + opx] = e;
      se += e;
    }
    float depth = 0.f, dif = 0.f;
    for (int dd = 0; dd < DTOT; ++dd) {
      float p = s_cost[dd * NPX + opx] / se;
      s_cost[dd * NPX + opx] = p;
      depth += p * (base + (float)dd * st);
      dif += p * (float)dd;
    }
    int di = (int)dif;
    di = min(max(di, 0), DTOT - 1);
    float conf = 0.f;
    for (int k = di - 1; k <= di + 2; ++k)
      if (k >= 0 && k < DTOT) conf += s_cost[k * NPX + opx];
    float ev = 0.f;
    for (int dd = 0; dd < DTOT; ++dd) {
      float sv = base + (float)dd * st - depth;
      ev += sv * sv * s_cost[dd * NPX + opx];
    }
    ev = 1.5f * sqrtf(ev);
    int gy = h0 + py, gx = w0 + pxx;
    out_d[gy * W + gx] = depth;
    out_c[gy * W + gx] = conf;
    out_v[gy * W + gx] = ev;
  }
}

template <int D, int H, int W>
__global__ void epilogue_kernel(const float* __restrict__ g_cost,
                                const float* __restrict__ dpar,
                                float* __restrict__ out_d,
                                float* __restrict__ out_c,
                                float* __restrict__ out_v) {
  int pix = blockIdx.x * 256 + threadIdx.x;
  if (pix >= H * W) return;
  const float base = dpar[0], st = dpar[1];
  float c[D];
#pragma unroll
  for (int dd = 0; dd < D; ++dd) c[dd] = g_cost[(size_t)dd * (H * W) + pix];
  float mx = -3.0e38f;
#pragma unroll
  for (int dd = 0; dd < D; ++dd) mx = fmaxf(mx, c[dd]);
  float se = 0.f;
#pragma unroll
  for (int dd = 0; dd < D; ++dd) {
    float e = expf(c[dd] - mx);
    c[dd] = e;
    se += e;
  }
  float depth = 0.f, dif = 0.f;
#pragma unroll
  for (int dd = 0; dd < D; ++dd) {
    float p = c[dd] / se;
    c[dd] = p;
    depth += p * (base + (float)dd * st);
    dif += p * (float)dd;
  }
  int di = (int)dif;
  di = min(max(di, 0), D - 1);
  float conf = 0.f;
#pragma unroll
  for (int dd = 0; dd < D; ++dd)
    if (dd >= di - 1 && dd <= di + 2) conf += c[dd];
  float ev = 0.f;
#pragma unroll
  for (int dd = 0; dd < D; ++dd) {
    float sv = base + (float)dd * st - depth;
    ev += sv * sv * c[dd];
  }
  ev = 1.5f * sqrtf(ev);
  out_d[pix] = depth;
  out_c[pix] = conf;
  out_v[pix] = ev;
}

extern "C" void kernel_launch(void* const* d_in, const int* in_sizes, int n_in,
                              void* d_out, int out_size, void* d_ws, size_t ws_size,
                              hipStream_t stream) {
  const float* feats1 = (const float*)d_in[0];
  const float* feats2 = (const float*)d_in[1];
  const float* proj1 = (const float*)d_in[2];
  const float* proj2 = (const float*)d_in[3];
  const float* depthv = (const float*)d_in[4];
  const float* w1 = (const float*)d_in[6];
  const float* b1 = (const float*)d_in[7];
  const float* w2 = (const float*)d_in[8];
  const float* b2 = (const float*)d_in[9];
  float* out = (float*)d_out;
  float* ws = (float*)d_ws;

  const int nd = in_sizes[4];
  const size_t F1 = (size_t)3 * 32 * 128 * 160;
  const size_t F2 = (size_t)3 * 16 * 256 * 320;
  const size_t COST1 = (size_t)48 * 128 * 160;  // 983040 floats
  const bool mid = ws_size >= (64 + COST1) * sizeof(float);
  const bool big = ws_size >= (64 + COST1 + F1 + F2) * sizeof(float);

  setup_mats_kernel<<<1, 64, 0, stream>>>(proj1, proj2, depthv, nd, ws);

  float* d1 = out;
  float* c1 = out + 20480;
  float* v1 = out + 40960;
  float* d2 = out + 61440;
  float* c2 = out + 143360;
  float* v2 = out + 225280;

  float* cost1 = ws + 64;
  dim3 g1c(160 / 8, 128 / 8, 6), g1f(160 / 8, 128 / 8, 1), g2(320 / 8, 256 / 8, 1);

  if (big) {
    float* f1t = ws + 64 + COST1;
    float* f2t = f1t + F1;
    transpose_cl_kernel<<<(int)((F1 + 255) / 256), 256, 0, stream>>>(feats1, f1t, 32, 128, 160);
    transpose_cl_kernel<<<(int)((F2 + 255) / 256), 256, 0, stream>>>(feats2, f2t, 16, 256, 320);
    cost_kernel<32, 48, 8, 8, 8, 128, 160, false, true, false><<<g1c, 256, 0, stream>>>(
        f1t, w1, b1, ws, ws + 48, nullptr, nullptr, cost1, nullptr, nullptr, nullptr);
    epilogue_kernel<48, 128, 160><<<80, 256, 0, stream>>>(cost1, ws + 48, d1, c1, v1);
    cost_kernel<16, 8, 8, 8, 8, 256, 320, true, true, true><<<g2, 256, 0, stream>>>(
        f2t, w2, b2, ws + 24, ws + 48, d1, v1, nullptr, d2, c2, v2);
  } else if (mid) {
    cost_kernel<32, 48, 8, 8, 8, 128, 160, false, false, false><<<g1c, 256, 0, stream>>>(
        feats1, w1, b1, ws, ws + 48, nullptr, nullptr, cost1, nullptr, nullptr, nullptr);
    epilogue_kernel<48, 128, 160><<<80, 256, 0, stream>>>(cost1, ws + 48, d1, c1, v1);
    cost_kernel<16, 8, 8, 8, 8, 256, 320, true, false, true><<<g2, 256, 0, stream>>>(
        feats2, w2, b2, ws + 24, ws + 48, d1, v1, nullptr, d2, c2, v2);
  } else {
    cost_kernel<32, 48, 48, 8, 8, 128, 160, false, false, true><<<g1f, 256, 0, stream>>>(
        feats1, w1, b1, ws, ws + 48, nullptr, nullptr, nullptr, d1, c1, v1);
    cost_kernel<16, 8, 8, 8, 8, 256, 320, true, false, true><<<g2, 256, 0, stream>>>(
        feats2, w2, b2, ws + 24, ws + 48, d1, v1, nullptr, d2, c2, v2);
  }
}

// Round 4
// 622.220 us; speedup vs baseline: 2.3421x; 1.2345x over previous
//
#include <hip/hip_runtime.h>
#include <math.h>

// ---------------------------------------------------------------------------
// CoarseMVSNet fused implementation, depth-chunked + single-barrier pipeline.
//  setup_mats_kernel  : compose K@E per view, invert ref, P = src @ inv(ref)
//  transpose_cl_kernel: (V,C,H,W) -> (V,H,W,C) channel-last copy in ws
//  cost_kernel        : per interval: variance(d) || coords(d+1) || conv(d-1)
//                       on double-buffered LDS, ONE barrier per slice.
//  epilogue_kernel    : softmax/depth/conf/exp-var from global cost volume
// NOTES:
//  - __launch_bounds__(256) ONLY: (256,4) forced VGPR->64, 4.2 GB spill (R2).
//  - variance lanes: cg fastest (px = i/C4) so 8 lanes read 128 B contiguous
//    per gather corner -> ~4x fewer distinct L1 lines per wave-load (R3 fix).
// ---------------------------------------------------------------------------

__global__ void setup_mats_kernel(const float* __restrict__ proj1,
                                  const float* __restrict__ proj2,
                                  const float* __restrict__ depthv, int nd,
                                  float* __restrict__ ws) {
  if (threadIdx.x != 0 || blockIdx.x != 0) return;
  for (int s = 0; s < 2; ++s) {
    const float* P = s ? proj2 : proj1;  // (3,2,4,4) flat
    double comp[3][4][4];
    for (int v = 0; v < 3; ++v) {
      const float* E = P + v * 32;       // [v][0]
      const float* K = P + v * 32 + 16;  // [v][1]
      for (int r = 0; r < 3; ++r)
        for (int c = 0; c < 4; ++c) {
          double acc = 0.0;
          for (int k = 0; k < 3; ++k) acc += (double)K[r * 4 + k] * (double)E[k * 4 + c];
          comp[v][r][c] = acc;
        }
      for (int c = 0; c < 4; ++c) comp[v][3][c] = (double)E[12 + c];
    }
    double a[4][8];
    for (int r = 0; r < 4; ++r)
      for (int c = 0; c < 4; ++c) {
        a[r][c] = comp[0][r][c];
        a[r][4 + c] = (r == c) ? 1.0 : 0.0;
      }
    for (int col = 0; col < 4; ++col) {
      int piv = col;
      double best = fabs(a[col][col]);
      for (int r = col + 1; r < 4; ++r) {
        double t = fabs(a[r][col]);
        if (t > best) { best = t; piv = r; }
      }
      if (piv != col)
        for (int c = 0; c < 8; ++c) { double t = a[col][c]; a[col][c] = a[piv][c]; a[piv][c] = t; }
      double dv = a[col][col];
      for (int c = 0; c < 8; ++c) a[col][c] /= dv;
      for (int r = 0; r < 4; ++r)
        if (r != col) {
          double f = a[r][col];
          if (f != 0.0)
            for (int c = 0; c < 8; ++c) a[r][c] -= f * a[col][c];
        }
    }
    for (int v = 1; v < 3; ++v) {
      double Pm[3][4];
      for (int r = 0; r < 3; ++r)
        for (int c = 0; c < 4; ++c) {
          double acc = 0.0;
          for (int k = 0; k < 4; ++k) acc += comp[v][r][k] * a[k][4 + c];
          Pm[r][c] = acc;
        }
      float* o = ws + s * 24 + (v - 1) * 12;
      o[0] = (float)Pm[0][0]; o[1] = (float)Pm[0][1]; o[2] = (float)Pm[0][2];
      o[3] = (float)Pm[1][0]; o[4] = (float)Pm[1][1]; o[5] = (float)Pm[1][2];
      o[6] = (float)Pm[2][0]; o[7] = (float)Pm[2][1]; o[8] = (float)Pm[2][2];
      o[9] = (float)Pm[0][3]; o[10] = (float)Pm[1][3]; o[11] = (float)Pm[2][3];
    }
  }
  ws[48] = depthv[0];
  ws[49] = (depthv[nd - 1] - depthv[0]) / 47.0f;  // (dmax-dmin)/(ND1-1)
}

__global__ void transpose_cl_kernel(const float* __restrict__ in, float* __restrict__ out,
                                    int C, int H, int W) {
  int total = 3 * C * H * W;
  int idx = blockIdx.x * 256 + threadIdx.x;
  if (idx >= total) return;
  int c = idx % C;
  int t = idx / C;
  int w = t % W;
  int t2 = t / W;
  int h = t2 % H;
  int v = t2 / H;
  out[idx] = in[((size_t)(v * C + c) * H + h) * W + w];
}

// C channels, DTOT total depths, DC owned cost slices per block (blockIdx.z),
// TH x TW tile, H x W image. STAGE2: per-pixel samples from upsampled d1/v1.
// CL: channel-last feats. EPI: DC==DTOT, fuse softmax head, no global cost.
template <int C, int DTOT, int DC, int TH, int TW, int H, int W, bool STAGE2, bool CL, bool EPI>
__launch_bounds__(256)
__global__ void cost_kernel(const float* __restrict__ feats,
                            const float* __restrict__ wconv,
                            const float* __restrict__ bconv,
                            const float* __restrict__ mats,
                            const float* __restrict__ dpar,
                            const float* __restrict__ prev_d,
                            const float* __restrict__ prev_v,
                            float* __restrict__ g_cost,
                            float* __restrict__ out_d,
                            float* __restrict__ out_c,
                            float* __restrict__ out_v) {
  constexpr int HB = TH + 2, WB = TW + 2, HALO = HB * WB, NPX = TH * TW;
  constexpr int HP = HALO + 1;  // pad leading dim for conv reads
  constexpr int C4 = C / 4;
  constexpr int CG = C / 4;     // channels per conv thread group (4 groups)
  constexpr int NS = DC + 2;
  constexpr int VITEMS = CL ? (HALO * C4) : (HALO * C);

  __shared__ float s_var[2][C * HP];
  __shared__ float s_cost[DC * NPX];
  __shared__ float s_w[C * 27];
  __shared__ float s_rx[2][HALO], s_ry[2][HALO], s_rz[2][HALO];
  __shared__ float s_cw[2][2][4][HALO];  // [buf][view][corner][px]
  __shared__ int s_ci[2][2][4][HALO];
  __shared__ int s_gidx[HALO];
  __shared__ float s_dbase[HALO], s_dstep[HALO];
  __shared__ unsigned char s_inb[HALO];

  const int tid = threadIdx.x;
  const int h0 = blockIdx.y * TH;
  const int w0 = blockIdx.x * TW;
  const int d0 = EPI ? 0 : blockIdx.z * DC;

  for (int i = tid; i < C * 27; i += 256) s_w[i] = wconv[i];

  // per-halo-pixel precompute: rot@[x,y,1] per view; depth sample base/step
  for (int i = tid; i < HALO; i += 256) {
    int hy = i / WB, hx = i - hy * WB;
    int gy = h0 + hy - 1, gx = w0 + hx - 1;
    bool inb = (gy >= 0) && (gy < H) && (gx >= 0) && (gx < W);
    s_inb[i] = inb ? 1 : 0;
    s_gidx[i] = inb ? (gy * W + gx) : 0;
    float fx = (float)gx, fy = (float)gy;
#pragma unroll
    for (int v = 0; v < 2; ++v) {
      const float* M = mats + v * 12;
      s_rx[v][i] = M[0] * fx + M[1] * fy + M[2];
      s_ry[v][i] = M[3] * fx + M[4] * fy + M[5];
      s_rz[v][i] = M[6] * fx + M[7] * fy + M[8];
    }
    if constexpr (STAGE2) {
      constexpr int SH = H / 2, SW = W / 2;
      // jax.image.resize bilinear 2x: src = (i+0.5)*0.5-0.5, edge-clamped
      float syf = 0.5f * (float)gy - 0.25f;
      float sxf = 0.5f * (float)gx - 0.25f;
      syf = fminf(fmaxf(syf, 0.0f), (float)(SH - 1));
      sxf = fminf(fmaxf(sxf, 0.0f), (float)(SW - 1));
      int sy0 = (int)syf, sx0 = (int)sxf;
      float fy2 = syf - (float)sy0, fx2 = sxf - (float)sx0;
      int sy1 = min(sy0 + 1, SH - 1), sx1 = min(sx0 + 1, SW - 1);
      int j00 = sy0 * SW + sx0, j01 = sy0 * SW + sx1;
      int j10 = sy1 * SW + sx0, j11 = sy1 * SW + sx1;
      float cd = (prev_d[j00] * (1.f - fx2) + prev_d[j01] * fx2) * (1.f - fy2) +
                 (prev_d[j10] * (1.f - fx2) + prev_d[j11] * fx2) * fy2;
      float cv = (prev_v[j00] * (1.f - fx2) + prev_v[j01] * fx2) * (1.f - fy2) +
                 (prev_v[j10] * (1.f - fx2) + prev_v[j11] * fx2) * fy2;
      float lo = -fminf(cd, cv);
      s_dbase[i] = cd + lo + 1e-12f;
      s_dstep[i] = (cv - lo) / (float)(DTOT - 1);
    } else {
      s_dbase[i] = dpar[0];
      s_dstep[i] = dpar[1];
    }
  }
  {
    float bias = bconv[0];
    for (int i = tid; i < DC * NPX; i += 256) s_cost[i] = bias;
  }
  __syncthreads();

  // project halo pixel for slice ds, both views, into coord buffer b
  auto do_coords = [&](int ds, int b, int i) {
    int v = (i >= HALO) ? 1 : 0;
    int px = i - v * HALO;
    float dep = s_dbase[px] + (float)ds * s_dstep[px];
    const float* M = mats + v * 12;
    float X = s_rx[v][px] * dep + M[9];
    float Y = s_ry[v][px] * dep + M[10];
    float Z = s_rz[v][px] * dep + M[11];
    float inv = 1.0f / Z;
    float xz = X * inv, yz = Y * inv;
    float gxn = xz * (2.0f / (float)(W - 1)) - 1.0f;
    float gyn = yz * (2.0f / (float)(H - 1)) - 1.0f;
    float ix = ((gxn + 1.0f) * (float)W - 1.0f) * 0.5f;
    float iy = ((gyn + 1.0f) * (float)H - 1.0f) * 0.5f;
    float x0f = floorf(ix), y0f = floorf(iy);
    float wx = ix - x0f, wy = iy - y0f;
    float x1f = x0f + 1.0f, y1f = y0f + 1.0f;
    bool vx0 = (x0f >= 0.0f) && (x0f <= (float)(W - 1));
    bool vx1 = (x1f >= 0.0f) && (x1f <= (float)(W - 1));
    bool vy0 = (y0f >= 0.0f) && (y0f <= (float)(H - 1));
    bool vy1 = (y1f >= 0.0f) && (y1f <= (float)(H - 1));
    int xc0 = (int)fminf(fmaxf(x0f, 0.0f), (float)(W - 1));
    int xc1 = (int)fminf(fmaxf(x1f, 0.0f), (float)(W - 1));
    int yc0 = (int)fminf(fmaxf(y0f, 0.0f), (float)(H - 1));
    int yc1 = (int)fminf(fmaxf(y1f, 0.0f), (float)(H - 1));
    s_ci[b][v][0][px] = yc0 * W + xc0;
    s_ci[b][v][1][px] = yc0 * W + xc1;
    s_ci[b][v][2][px] = yc1 * W + xc0;
    s_ci[b][v][3][px] = yc1 * W + xc1;
    float wxm = 1.0f - wx, wym = 1.0f - wy;
    s_cw[b][v][0][px] = (vx0 && vy0) ? wxm * wym : 0.0f;
    s_cw[b][v][1][px] = (vx1 && vy0) ? wx * wym : 0.0f;
    s_cw[b][v][2][px] = (vx0 && vy1) ? wxm * wy : 0.0f;
    s_cw[b][v][3][px] = (vx1 && vy1) ? wx * wy : 0.0f;
  };

  // variance for one item, reading coord buffer b, writing s_var[b2]
  auto do_variance = [&](int b, int b2, int i) {
    if constexpr (CL) {
      int px = i / C4, cg = i - (i / C4) * C4;  // cg fastest -> coalesced lanes
      float o0 = 0.f, o1 = 0.f, o2 = 0.f, o3 = 0.f;
      if (s_inb[px]) {
        const float4* fp = (const float4*)feats;
        float4 r = fp[(size_t)s_gidx[px] * C4 + cg];
        float s0 = r.x, s1 = r.y, s2 = r.z, s3 = r.w;
        float q0 = r.x * r.x, q1 = r.y * r.y, q2 = r.z * r.z, q3 = r.w * r.w;
#pragma unroll
        for (int v = 0; v < 2; ++v) {
          const float4* fv = fp + (size_t)(v + 1) * H * W * C4 + cg;
          float a00 = s_cw[b][v][0][px], a10 = s_cw[b][v][1][px];
          float a01 = s_cw[b][v][2][px], a11 = s_cw[b][v][3][px];
          float4 p00 = fv[(size_t)s_ci[b][v][0][px] * C4];
          float4 p10 = fv[(size_t)s_ci[b][v][1][px] * C4];
          float4 p01 = fv[(size_t)s_ci[b][v][2][px] * C4];
          float4 p11 = fv[(size_t)s_ci[b][v][3][px] * C4];
          float g0 = a00 * p00.x + a10 * p10.x + a01 * p01.x + a11 * p11.x;
          float g1 = a00 * p00.y + a10 * p10.y + a01 * p01.y + a11 * p11.y;
          float g2 = a00 * p00.z + a10 * p10.z + a01 * p01.z + a11 * p11.z;
          float g3 = a00 * p00.w + a10 * p10.w + a01 * p01.w + a11 * p11.w;
          s0 += g0; q0 += g0 * g0;
          s1 += g1; q1 += g1 * g1;
          s2 += g2; q2 += g2 * g2;
          s3 += g3; q3 += g3 * g3;
        }
        float m;
        m = s0 / 3.0f; o0 = q0 / 3.0f - m * m;
        m = s1 / 3.0f; o1 = q1 / 3.0f - m * m;
        m = s2 / 3.0f; o2 = q2 / 3.0f - m * m;
        m = s3 / 3.0f; o3 = q3 / 3.0f - m * m;
      }
      int cb = cg * 4;
      s_var[b2][(cb + 0) * HP + px] = o0;
      s_var[b2][(cb + 1) * HP + px] = o1;
      s_var[b2][(cb + 2) * HP + px] = o2;
      s_var[b2][(cb + 3) * HP + px] = o3;
    } else {
      int c = i / HALO, px = i - (i / HALO) * HALO;
      float var = 0.f;
      if (s_inb[px]) {
        const float* f0 = feats + (size_t)c * (H * W);
        float rr = f0[s_gidx[px]];
        float sum = rr, ssq = rr * rr;
#pragma unroll
        for (int v = 0; v < 2; ++v) {
          const float* fv = feats + ((size_t)(v + 1) * C + c) * (H * W);
          float val = s_cw[b][v][0][px] * fv[s_ci[b][v][0][px]] +
                      s_cw[b][v][1][px] * fv[s_ci[b][v][1][px]] +
                      s_cw[b][v][2][px] * fv[s_ci[b][v][2][px]] +
                      s_cw[b][v][3][px] * fv[s_ci[b][v][3][px]];
          sum += val;
          ssq += val * val;
        }
        float m = sum / 3.0f;
        var = ssq / 3.0f - m * m;
      }
      s_var[b2][c * HP + px] = var;
    }
  };

  // scatter conv contribution of variance slice ds (in s_var[sb]) into s_cost
  auto conv_accum = [&](int ds, int sb) {
    for (int i = tid; i < NPX * 4; i += 256) {
      int grp = i / NPX, opx = i - grp * NPX;  // grp wave-uniform (NPX=64)
      int py = opx / TW, pxx = opx - py * TW;
      float a0 = 0.f, a1 = 0.f, a2 = 0.f;  // kd = 0,1,2
      int cbase = grp * CG;
#pragma unroll
      for (int kh = 0; kh < 3; ++kh) {
#pragma unroll
        for (int kw = 0; kw < 3; ++kw) {
          int hp = (py + kh) * WB + (pxx + kw);
#pragma unroll
          for (int cc = 0; cc < CG; ++cc) {
            int c = cbase + cc;
            float vv = s_var[sb][c * HP + hp];
            const float* wp = s_w + c * 27 + kh * 3 + kw;
            a0 += vv * wp[0];
            a1 += vv * wp[9];
            a2 += vv * wp[18];
          }
        }
      }
      int t0 = ds + 1 - d0;  // cost slice fed by kd=0
      int t1 = ds - d0;      // kd=1
      int t2 = ds - 1 - d0;  // kd=2
      if (t0 >= 0 && t0 < DC) atomicAdd(&s_cost[t0 * NPX + opx], a0);
      if (t1 >= 0 && t1 < DC) atomicAdd(&s_cost[t1 * NPX + opx], a1);
      if (t2 >= 0 && t2 < DC) atomicAdd(&s_cost[t2 * NPX + opx], a2);
    }
  };

  // prologue: coords for pipeline slot 0 (slice d0-1) if valid
  {
    int ds0 = d0 - 1;
    if (ds0 >= 0 && ds0 < DTOT)
      for (int i = tid; i < 2 * HALO; i += 256) do_coords(ds0, 0, i);
  }
  __syncthreads();

  // pipeline: interval s runs variance(s) || coords(s+1) || conv(s-1),
  // one barrier per interval. Buffers: coords buf = s&1, var buf = s&1.
  for (int s = 0; s <= NS; ++s) {
    const int ds = d0 - 1 + s;
    const bool val_cur = (s < NS) && (ds >= 0) && (ds < DTOT);
    const bool val_next = (s + 1 < NS) && (ds + 1 >= 0) && (ds + 1 < DTOT);
    const bool val_prev = (s >= 1) && (ds - 1 >= 0) && (ds - 1 < DTOT);
    if (val_cur)
      for (int i = tid; i < VITEMS; i += 256) do_variance(s & 1, s & 1, i);
    if (val_next)
      for (int i = tid; i < 2 * HALO; i += 256) do_coords(ds + 1, (s + 1) & 1, i);
    if (val_prev) conv_accum(ds - 1, (s - 1) & 1);
    __syncthreads();
  }

  if constexpr (!EPI) {
    // write owned cost slices, [d][pix] layout (coalesced epilogue reads)
    for (int i = tid; i < DC * NPX; i += 256) {
      int dd = i / NPX, opx = i - dd * NPX;
      int py = opx / TW, pxx = opx - py * TW;
      g_cost[(size_t)(d0 + dd) * (H * W) + (h0 + py) * W + (w0 + pxx)] = s_cost[i];
    }
  } else if (tid < NPX) {
    // fused epilogue: softmax over D, depth, conf (4-tap), exp-var
    const int opx = tid;
    const int py = opx / TW, pxx = opx - py * TW;
    const int hp = (py + 1) * WB + (pxx + 1);
    const float base = s_dbase[hp], st = s_dstep[hp];
    float mx = -3.0e38f;
    for (int dd = 0; dd < DTOT; ++dd) mx = fmaxf(mx, s_cost[dd * NPX + opx]);
    float se = 0.f;
    for (int dd = 0; dd < DTOT; ++dd) {
      float e = expf(s_cost[dd * NPX + opx] - mx);
      s_cost[dd * NPX + opx] = e;
      se += e;
    }
    float depth = 0.f, dif = 0.f;
    for (int dd = 0; dd < DTOT; ++dd) {
      float p = s_cost[dd * NPX + opx] / se;
      s_cost[dd * NPX + opx] = p;
      depth += p * (base + (float)dd * st);
      dif += p * (float)dd;
    }
    int di = (int)dif;
    di = min(max(di, 0), DTOT - 1);
    float conf = 0.f;
    for (int k = di - 1; k <= di + 2; ++k)
      if (k >= 0 && k < DTOT) conf += s_cost[k * NPX + opx];
    float ev = 0.f;
    for (int dd = 0; dd < DTOT; ++dd) {
      float sv = base + (float)dd * st - depth;
      ev += sv * sv * s_cost[dd * NPX + opx];
    }
    ev = 1.5f * sqrtf(ev);
    int gy = h0 + py, gx = w0 + pxx;
    out_d[gy * W + gx] = depth;
    out_c[gy * W + gx] = conf;
    out_v[gy * W + gx] = ev;
  }
}

template <int D, int H, int W>
__global__ void epilogue_kernel(const float* __restrict__ g_cost,
                                const float* __restrict__ dpar,
                                float* __restrict__ out_d,
                                float* __restrict__ out_c,
                                float* __restrict__ out_v) {
  int pix = blockIdx.x * 256 + threadIdx.x;
  if (pix >= H * W) return;
  const float base = dpar[0], st = dpar[1];
  float c[D];
#pragma unroll
  for (int dd = 0; dd < D; ++dd) c[dd] = g_cost[(size_t)dd * (H * W) + pix];
  float mx = -3.0e38f;
#pragma unroll
  for (int dd = 0; dd < D; ++dd) mx = fmaxf(mx, c[dd]);
  float se = 0.f;
#pragma unroll
  for (int dd = 0; dd < D; ++dd) {
    float e = expf(c[dd] - mx);
    c[dd] = e;
    se += e;
  }
  float depth = 0.f, dif = 0.f;
#pragma unroll
  for (int dd = 0; dd < D; ++dd) {
    float p = c[dd] / se;
    c[dd] = p;
    depth += p * (base + (float)dd * st);
    dif += p * (float)dd;
  }
  int di = (int)dif;
  di = min(max(di, 0), D - 1);
  float conf = 0.f;
#pragma unroll
  for (int dd = 0; dd < D; ++dd)
    if (dd >= di - 1 && dd <= di + 2) conf += c[dd];
  float ev = 0.f;
#pragma unroll
  for (int dd = 0; dd < D; ++dd) {
    float sv = base + (float)dd * st - depth;
    ev += sv * sv * c[dd];
  }
  ev = 1.5f * sqrtf(ev);
  out_d[pix] = depth;
  out_c[pix] = conf;
  out_v[pix] = ev;
}

extern "C" void kernel_launch(void* const* d_in, const int* in_sizes, int n_in,
                              void* d_out, int out_size, void* d_ws, size_t ws_size,
                              hipStream_t stream) {
  const float* feats1 = (const float*)d_in[0];
  const float* feats2 = (const float*)d_in[1];
  const float* proj1 = (const float*)d_in[2];
  const float* proj2 = (const float*)d_in[3];
  const float* depthv = (const float*)d_in[4];
  const float* w1 = (const float*)d_in[6];
  const float* b1 = (const float*)d_in[7];
  const float* w2 = (const float*)d_in[8];
  const float* b2 = (const float*)d_in[9];
  float* out = (float*)d_out;
  float* ws = (float*)d_ws;

  const int nd = in_sizes[4];
  const size_t F1 = (size_t)3 * 32 * 128 * 160;
  const size_t F2 = (size_t)3 * 16 * 256 * 320;
  const size_t COST1 = (size_t)48 * 128 * 160;  // 983040 floats
  const bool mid = ws_size >= (64 + COST1) * sizeof(float);
  const bool big = ws_size >= (64 + COST1 + F1 + F2) * sizeof(float);

  setup_mats_kernel<<<1, 64, 0, stream>>>(proj1, proj2, depthv, nd, ws);

  float* d1 = out;
  float* c1 = out + 20480;
  float* v1 = out + 40960;
  float* d2 = out + 61440;
  float* c2 = out + 143360;
  float* v2 = out + 225280;

  float* cost1 = ws + 64;
  dim3 g1c(160 / 8, 128 / 8, 6), g1f(160 / 8, 128 / 8, 1), g2(320 / 8, 256 / 8, 1);

  if (big) {
    float* f1t = ws + 64 + COST1;
    float* f2t = f1t + F1;
    transpose_cl_kernel<<<(int)((F1 + 255) / 256), 256, 0, stream>>>(feats1, f1t, 32, 128, 160);
    transpose_cl_kernel<<<(int)((F2 + 255) / 256), 256, 0, stream>>>(feats2, f2t, 16, 256, 320);
    cost_kernel<32, 48, 8, 8, 8, 128, 160, false, true, false><<<g1c, 256, 0, stream>>>(
        f1t, w1, b1, ws, ws + 48, nullptr, nullptr, cost1, nullptr, nullptr, nullptr);
    epilogue_kernel<48, 128, 160><<<80, 256, 0, stream>>>(cost1, ws + 48, d1, c1, v1);
    cost_kernel<16, 8, 8, 8, 8, 256, 320, true, true, true><<<g2, 256, 0, stream>>>(
        f2t, w2, b2, ws + 24, ws + 48, d1, v1, nullptr, d2, c2, v2);
  } else if (mid) {
    cost_kernel<32, 48, 8, 8, 8, 128, 160, false, false, false><<<g1c, 256, 0, stream>>>(
        feats1, w1, b1, ws, ws + 48, nullptr, nullptr, cost1, nullptr, nullptr, nullptr);
    epilogue_kernel<48, 128, 160><<<80, 256, 0, stream>>>(cost1, ws + 48, d1, c1, v1);
    cost_kernel<16, 8, 8, 8, 8, 256, 320, true, false, true><<<g2, 256, 0, stream>>>(
        feats2, w2, b2, ws + 24, ws + 48, d1, v1, nullptr, d2, c2, v2);
  } else {
    cost_kernel<32, 48, 48, 8, 8, 128, 160, false, false, true><<<g1f, 256, 0, stream>>>(
        feats1, w1, b1, ws, ws + 48, nullptr, nullptr, nullptr, d1, c1, v1);
    cost_kernel<16, 8, 8, 8, 8, 256, 320, true, false, true><<<g2, 256, 0, stream>>>(
        feats2, w2, b2, ws + 24, ws + 48, d1, v1, nullptr, d2, c2, v2);
  }
}

// Round 5
// 558.036 us; speedup vs baseline: 2.6115x; 1.1150x over previous
//
#include <hip/hip_runtime.h>
#include <math.h>

// ---------------------------------------------------------------------------
// CoarseMVSNet, de-fused for latency hiding (R4 post-mortem: fused kernel is
// 72% gather-latency stall, capped at 3 blocks/CU by LDS+VGPR; block count
// doesn't help). New structure (huge-ws path):
//   gather_var_kernel : 1 thread = 1 (d,px,cg) float4 of variance volume.
//                       NO LDS, NO barriers, branchless -> max TLP.
//   conv_cost_kernel  : LDS-tiled 3x3x3 conv over var volume (coalesced
//                       staging, double-buffered, 1 barrier/slice).
//   epilogue_kernel   : softmax/depth/conf/exp-var (STAGE2 recomputes
//                       per-pixel base/step from upsampled d1/v1).
// Fallbacks: R4's fused cost_kernel for smaller ws tiers.
// __launch_bounds__(256) ONLY (R2: (256,4) forced VGPR->64, 4.2 GB spill).
// ---------------------------------------------------------------------------

__global__ void setup_mats_kernel(const float* __restrict__ proj1,
                                  const float* __restrict__ proj2,
                                  const float* __restrict__ depthv, int nd,
                                  float* __restrict__ ws) {
  if (threadIdx.x != 0 || blockIdx.x != 0) return;
  for (int s = 0; s < 2; ++s) {
    const float* P = s ? proj2 : proj1;  // (3,2,4,4) flat
    double comp[3][4][4];
    for (int v = 0; v < 3; ++v) {
      const float* E = P + v * 32;       // [v][0]
      const float* K = P + v * 32 + 16;  // [v][1]
      for (int r = 0; r < 3; ++r)
        for (int c = 0; c < 4; ++c) {
          double acc = 0.0;
          for (int k = 0; k < 3; ++k) acc += (double)K[r * 4 + k] * (double)E[k * 4 + c];
          comp[v][r][c] = acc;
        }
      for (int c = 0; c < 4; ++c) comp[v][3][c] = (double)E[12 + c];
    }
    double a[4][8];
    for (int r = 0; r < 4; ++r)
      for (int c = 0; c < 4; ++c) {
        a[r][c] = comp[0][r][c];
        a[r][4 + c] = (r == c) ? 1.0 : 0.0;
      }
    for (int col = 0; col < 4; ++col) {
      int piv = col;
      double best = fabs(a[col][col]);
      for (int r = col + 1; r < 4; ++r) {
        double t = fabs(a[r][col]);
        if (t > best) { best = t; piv = r; }
      }
      if (piv != col)
        for (int c = 0; c < 8; ++c) { double t = a[col][c]; a[col][c] = a[piv][c]; a[piv][c] = t; }
      double dv = a[col][col];
      for (int c = 0; c < 8; ++c) a[col][c] /= dv;
      for (int r = 0; r < 4; ++r)
        if (r != col) {
          double f = a[r][col];
          if (f != 0.0)
            for (int c = 0; c < 8; ++c) a[r][c] -= f * a[col][c];
        }
    }
    for (int v = 1; v < 3; ++v) {
      double Pm[3][4];
      for (int r = 0; r < 3; ++r)
        for (int c = 0; c < 4; ++c) {
          double acc = 0.0;
          for (int k = 0; k < 4; ++k) acc += comp[v][r][k] * a[k][4 + c];
          Pm[r][c] = acc;
        }
      float* o = ws + s * 24 + (v - 1) * 12;
      o[0] = (float)Pm[0][0]; o[1] = (float)Pm[0][1]; o[2] = (float)Pm[0][2];
      o[3] = (float)Pm[1][0]; o[4] = (float)Pm[1][1]; o[5] = (float)Pm[1][2];
      o[6] = (float)Pm[2][0]; o[7] = (float)Pm[2][1]; o[8] = (float)Pm[2][2];
      o[9] = (float)Pm[0][3]; o[10] = (float)Pm[1][3]; o[11] = (float)Pm[2][3];
    }
  }
  ws[48] = depthv[0];
  ws[49] = (depthv[nd - 1] - depthv[0]) / 47.0f;  // (dmax-dmin)/(ND1-1)
}

__global__ void transpose_cl_kernel(const float* __restrict__ in, float* __restrict__ out,
                                    int C, int H, int W) {
  int total = 3 * C * H * W;
  int idx = blockIdx.x * 256 + threadIdx.x;
  if (idx >= total) return;
  int c = idx % C;
  int t = idx / C;
  int w = t % W;
  int t2 = t / W;
  int h = t2 % H;
  int v = t2 / H;
  out[idx] = in[((size_t)(v * C + c) * H + h) * W + w];
}

// -------------------- de-fused path kernels --------------------

// Per-pixel depth range for STAGE2: bilinear 2x upsample of d1/v1.
template <int D, int H, int W>
__device__ inline void stage2_range(const float* __restrict__ prev_d,
                                    const float* __restrict__ prev_v,
                                    int gy, int gx, float& base, float& st) {
  constexpr int SH = H / 2, SW = W / 2;
  float syf = 0.5f * (float)gy - 0.25f;
  float sxf = 0.5f * (float)gx - 0.25f;
  syf = fminf(fmaxf(syf, 0.0f), (float)(SH - 1));
  sxf = fminf(fmaxf(sxf, 0.0f), (float)(SW - 1));
  int sy0 = (int)syf, sx0 = (int)sxf;
  float fy2 = syf - (float)sy0, fx2 = sxf - (float)sx0;
  int sy1 = min(sy0 + 1, SH - 1), sx1 = min(sx0 + 1, SW - 1);
  int j00 = sy0 * SW + sx0, j01 = sy0 * SW + sx1;
  int j10 = sy1 * SW + sx0, j11 = sy1 * SW + sx1;
  float cd = (prev_d[j00] * (1.f - fx2) + prev_d[j01] * fx2) * (1.f - fy2) +
             (prev_d[j10] * (1.f - fx2) + prev_d[j11] * fx2) * fy2;
  float cv = (prev_v[j00] * (1.f - fx2) + prev_v[j01] * fx2) * (1.f - fy2) +
             (prev_v[j10] * (1.f - fx2) + prev_v[j11] * fx2) * fy2;
  float lo = -fminf(cd, cv);
  base = cd + lo + 1e-12f;
  st = (cv - lo) / (float)(D - 1);
}

// One thread computes one float4 (4 channels) of the variance volume at
// (d, gy, gx). feats channel-last (V,H,W,C). Branchless, no LDS, no barriers.
template <int C, int DTOT, int H, int W, bool STAGE2>
__launch_bounds__(256)
__global__ void gather_var_kernel(const float* __restrict__ feats,
                                  const float* __restrict__ mats,
                                  const float* __restrict__ dpar,
                                  const float* __restrict__ prev_d,
                                  const float* __restrict__ prev_v,
                                  float4* __restrict__ var_out) {
  constexpr int C4 = C / 4;
  const int idx = blockIdx.x * 256 + threadIdx.x;
  if (idx >= DTOT * H * W * C4) return;
  const int cg = idx % C4;
  const int t = idx / C4;          // (d*H + gy)*W + gx
  const int gx = t % W;
  const int t2 = t / W;
  const int gy = t2 % H;
  const int d = t2 / H;
  const int pix = gy * W + gx;

  float base, st;
  if constexpr (STAGE2) {
    stage2_range<DTOT, H, W>(prev_d, prev_v, gy, gx, base, st);
  } else {
    base = dpar[0];
    st = dpar[1];
  }
  const float dep = base + (float)d * st;

  const float4* fp = (const float4*)feats;
  float4 r = fp[(size_t)pix * C4 + cg];
  float s0 = r.x, s1 = r.y, s2 = r.z, s3 = r.w;
  float q0 = r.x * r.x, q1 = r.y * r.y, q2 = r.z * r.z, q3 = r.w * r.w;

#pragma unroll
  for (int v = 0; v < 2; ++v) {
    const float* M = mats + v * 12;
    float fx = (float)gx, fy = (float)gy;
    float X = (M[0] * fx + M[1] * fy + M[2]) * dep + M[9];
    float Y = (M[3] * fx + M[4] * fy + M[5]) * dep + M[10];
    float Z = (M[6] * fx + M[7] * fy + M[8]) * dep + M[11];
    float inv = 1.0f / Z;
    float xz = X * inv, yz = Y * inv;
    float gxn = xz * (2.0f / (float)(W - 1)) - 1.0f;
    float gyn = yz * (2.0f / (float)(H - 1)) - 1.0f;
    float ix = ((gxn + 1.0f) * (float)W - 1.0f) * 0.5f;
    float iy = ((gyn + 1.0f) * (float)H - 1.0f) * 0.5f;
    float x0f = floorf(ix), y0f = floorf(iy);
    float wx = ix - x0f, wy = iy - y0f;
    float x1f = x0f + 1.0f, y1f = y0f + 1.0f;
    bool vx0 = (x0f >= 0.0f) && (x0f <= (float)(W - 1));
    bool vx1 = (x1f >= 0.0f) && (x1f <= (float)(W - 1));
    bool vy0 = (y0f >= 0.0f) && (y0f <= (float)(H - 1));
    bool vy1 = (y1f >= 0.0f) && (y1f <= (float)(H - 1));
    int xc0 = (int)fminf(fmaxf(x0f, 0.0f), (float)(W - 1));
    int xc1 = (int)fminf(fmaxf(x1f, 0.0f), (float)(W - 1));
    int yc0 = (int)fminf(fmaxf(y0f, 0.0f), (float)(H - 1));
    int yc1 = (int)fminf(fmaxf(y1f, 0.0f), (float)(H - 1));
    float wxm = 1.0f - wx, wym = 1.0f - wy;
    float a00 = (vx0 && vy0) ? wxm * wym : 0.0f;
    float a10 = (vx1 && vy0) ? wx * wym : 0.0f;
    float a01 = (vx0 && vy1) ? wxm * wy : 0.0f;
    float a11 = (vx1 && vy1) ? wx * wy : 0.0f;
    const float4* fv = fp + (size_t)(v + 1) * H * W * C4 + cg;
    float4 p00 = fv[(size_t)(yc0 * W + xc0) * C4];
    float4 p10 = fv[(size_t)(yc0 * W + xc1) * C4];
    float4 p01 = fv[(size_t)(yc1 * W + xc0) * C4];
    float4 p11 = fv[(size_t)(yc1 * W + xc1) * C4];
    float g0 = a00 * p00.x + a10 * p10.x + a01 * p01.x + a11 * p11.x;
    float g1 = a00 * p00.y + a10 * p10.y + a01 * p01.y + a11 * p11.y;
    float g2 = a00 * p00.z + a10 * p10.z + a01 * p01.z + a11 * p11.z;
    float g3 = a00 * p00.w + a10 * p10.w + a01 * p01.w + a11 * p11.w;
    s0 += g0; q0 += g0 * g0;
    s1 += g1; q1 += g1 * g1;
    s2 += g2; q2 += g2 * g2;
    s3 += g3; q3 += g3 * g3;
  }
  float m;
  float4 o;
  m = s0 / 3.0f; o.x = q0 / 3.0f - m * m;
  m = s1 / 3.0f; o.y = q1 / 3.0f - m * m;
  m = s2 / 3.0f; o.z = q2 / 3.0f - m * m;
  m = s3 / 3.0f; o.w = q3 / 3.0f - m * m;
  var_out[idx] = o;
}

// 3x3x3 conv over the variance volume -> cost volume [d][pix].
// Block: TH x TW tile, DC owned cost slices (blockIdx.z). Double-buffered
// LDS staging of var slices (coalesced float4 reads), 1 barrier/slice.
template <int C, int DTOT, int DC, int TH, int TW, int H, int W>
__launch_bounds__(256)
__global__ void conv_cost_kernel(const float4* __restrict__ var_in,
                                 const float* __restrict__ wconv,
                                 const float* __restrict__ bconv,
                                 float* __restrict__ g_cost) {
  constexpr int HB = TH + 2, WB = TW + 2, HALO = HB * WB, NPX = TH * TW;
  constexpr int HP = HALO + 1;
  constexpr int C4 = C / 4;
  constexpr int CG = C / 4;  // channels per conv thread group (4 groups)
  constexpr int NS = DC + 2;

  __shared__ float s_in[2][C * HP];
  __shared__ float s_cost[DC * NPX];
  __shared__ float s_w[C * 27];

  const int tid = threadIdx.x;
  const int h0 = blockIdx.y * TH;
  const int w0 = blockIdx.x * TW;
  const int d0 = blockIdx.z * DC;

  for (int i = tid; i < C * 27; i += 256) s_w[i] = wconv[i];
  {
    float bias = bconv[0];
    for (int i = tid; i < DC * NPX; i += 256) s_cost[i] = bias;
  }

  auto stage = [&](int ds, int b) {
    for (int i = tid; i < HALO * C4; i += 256) {
      int px = i / C4, cg = i - (i / C4) * C4;  // cg fastest -> coalesced
      int hy = px / WB, hx = px - hy * WB;
      int gy = h0 + hy - 1, gx = w0 + hx - 1;
      float4 r = make_float4(0.f, 0.f, 0.f, 0.f);
      if (ds >= 0 && ds < DTOT && gy >= 0 && gy < H && gx >= 0 && gx < W)
        r = var_in[((size_t)(ds * H + gy) * W + gx) * C4 + cg];
      int cb = cg * 4;
      s_in[b][(cb + 0) * HP + px] = r.x;
      s_in[b][(cb + 1) * HP + px] = r.y;
      s_in[b][(cb + 2) * HP + px] = r.z;
      s_in[b][(cb + 3) * HP + px] = r.w;
    }
  };

  auto conv_accum = [&](int ds, int sb) {
    for (int i = tid; i < NPX * 4; i += 256) {
      int grp = i / NPX, opx = i - grp * NPX;  // grp wave-uniform (NPX=64)
      int py = opx / TW, pxx = opx - py * TW;
      float a0 = 0.f, a1 = 0.f, a2 = 0.f;  // kd = 0,1,2
      int cbase = grp * CG;
#pragma unroll
      for (int kh = 0; kh < 3; ++kh) {
#pragma unroll
        for (int kw = 0; kw < 3; ++kw) {
          int hp = (py + kh) * WB + (pxx + kw);
#pragma unroll
          for (int cc = 0; cc < CG; ++cc) {
            int c = cbase + cc;
            float vv = s_in[sb][c * HP + hp];
            const float* wp = s_w + c * 27 + kh * 3 + kw;
            a0 += vv * wp[0];
            a1 += vv * wp[9];
            a2 += vv * wp[18];
          }
        }
      }
      int t0 = ds + 1 - d0;
      int t1 = ds - d0;
      int t2 = ds - 1 - d0;
      if (t0 >= 0 && t0 < DC) atomicAdd(&s_cost[t0 * NPX + opx], a0);
      if (t1 >= 0 && t1 < DC) atomicAdd(&s_cost[t1 * NPX + opx], a1);
      if (t2 >= 0 && t2 < DC) atomicAdd(&s_cost[t2 * NPX + opx], a2);
    }
  };

  stage(d0 - 1, 0);
  __syncthreads();
  for (int s = 1; s <= NS; ++s) {
    if (s < NS) stage(d0 - 1 + s, s & 1);
    conv_accum(d0 - 1 + (s - 1), (s - 1) & 1);
    __syncthreads();
  }

  for (int i = tid; i < DC * NPX; i += 256) {
    int dd = i / NPX, opx = i - dd * NPX;
    int py = opx / TW, pxx = opx - py * TW;
    g_cost[(size_t)(d0 + dd) * (H * W) + (h0 + py) * W + (w0 + pxx)] = s_cost[i];
  }
}

template <int D, int H, int W, bool STAGE2>
__global__ void epilogue_kernel(const float* __restrict__ g_cost,
                                const float* __restrict__ dpar,
                                const float* __restrict__ prev_d,
                                const float* __restrict__ prev_v,
                                float* __restrict__ out_d,
                                float* __restrict__ out_c,
                                float* __restrict__ out_v) {
  int pix = blockIdx.x * 256 + threadIdx.x;
  if (pix >= H * W) return;
  float base, st;
  if constexpr (STAGE2) {
    stage2_range<D, H, W>(prev_d, prev_v, pix / W, pix % W, base, st);
  } else {
    base = dpar[0];
    st = dpar[1];
  }
  float c[D];
#pragma unroll
  for (int dd = 0; dd < D; ++dd) c[dd] = g_cost[(size_t)dd * (H * W) + pix];
  float mx = -3.0e38f;
#pragma unroll
  for (int dd = 0; dd < D; ++dd) mx = fmaxf(mx, c[dd]);
  float se = 0.f;
#pragma unroll
  for (int dd = 0; dd < D; ++dd) {
    float e = expf(c[dd] - mx);
    c[dd] = e;
    se += e;
  }
  float depth = 0.f, dif = 0.f;
#pragma unroll
  for (int dd = 0; dd < D; ++dd) {
    float p = c[dd] / se;
    c[dd] = p;
    depth += p * (base + (float)dd * st);
    dif += p * (float)dd;
  }
  int di = (int)dif;
  di = min(max(di, 0), D - 1);
  float conf = 0.f;
#pragma unroll
  for (int dd = 0; dd < D; ++dd)
    if (dd >= di - 1 && dd <= di + 2) conf += c[dd];
  float ev = 0.f;
#pragma unroll
  for (int dd = 0; dd < D; ++dd) {
    float sv = base + (float)dd * st - depth;
    ev += sv * sv * c[dd];
  }
  ev = 1.5f * sqrtf(ev);
  out_d[pix] = depth;
  out_c[pix] = conf;
  out_v[pix] = ev;
}

// -------------------- fused fallback (R4) --------------------

template <int C, int DTOT, int DC, int TH, int TW, int H, int W, bool STAGE2, bool CL, bool EPI>
__launch_bounds__(256)
__global__ void cost_kernel(const float* __restrict__ feats,
                            const float* __restrict__ wconv,
                            const float* __restrict__ bconv,
                            const float* __restrict__ mats,
                            const float* __restrict__ dpar,
                            const float* __restrict__ prev_d,
                            const float* __restrict__ prev_v,
                            float* __restrict__ g_cost,
                            float* __restrict__ out_d,
                            float* __restrict__ out_c,
                            float* __restrict__ out_v) {
  constexpr int HB = TH + 2, WB = TW + 2, HALO = HB * WB, NPX = TH * TW;
  constexpr int HP = HALO + 1;
  constexpr int C4 = C / 4;
  constexpr int CG = C / 4;
  constexpr int NS = DC + 2;
  constexpr int VITEMS = CL ? (HALO * C4) : (HALO * C);

  __shared__ float s_var[2][C * HP];
  __shared__ float s_cost[DC * NPX];
  __shared__ float s_w[C * 27];
  __shared__ float s_rx[2][HALO], s_ry[2][HALO], s_rz[2][HALO];
  __shared__ float s_cw[2][2][4][HALO];
  __shared__ int s_ci[2][2][4][HALO];
  __shared__ int s_gidx[HALO];
  __shared__ float s_dbase[HALO], s_dstep[HALO];
  __shared__ unsigned char s_inb[HALO];

  const int tid = threadIdx.x;
  const int h0 = blockIdx.y * TH;
  const int w0 = blockIdx.x * TW;
  const int d0 = EPI ? 0 : blockIdx.z * DC;

  for (int i = tid; i < C * 27; i += 256) s_w[i] = wconv[i];

  for (int i = tid; i < HALO; i += 256) {
    int hy = i / WB, hx = i - hy * WB;
    int gy = h0 + hy - 1, gx = w0 + hx - 1;
    bool inb = (gy >= 0) && (gy < H) && (gx >= 0) && (gx < W);
    s_inb[i] = inb ? 1 : 0;
    s_gidx[i] = inb ? (gy * W + gx) : 0;
    float fx = (float)gx, fy = (float)gy;
#pragma unroll
    for (int v = 0; v < 2; ++v) {
      const float* M = mats + v * 12;
      s_rx[v][i] = M[0] * fx + M[1] * fy + M[2];
      s_ry[v][i] = M[3] * fx + M[4] * fy + M[5];
      s_rz[v][i] = M[6] * fx + M[7] * fy + M[8];
    }
    if constexpr (STAGE2) {
      float b, stp;
      stage2_range<DTOT, H, W>(prev_d, prev_v, gy, gx, b, stp);
      s_dbase[i] = b;
      s_dstep[i] = stp;
    } else {
      s_dbase[i] = dpar[0];
      s_dstep[i] = dpar[1];
    }
  }
  {
    float bias = bconv[0];
    for (int i = tid; i < DC * NPX; i += 256) s_cost[i] = bias;
  }
  __syncthreads();

  auto do_coords = [&](int ds, int b, int i) {
    int v = (i >= HALO) ? 1 : 0;
    int px = i - v * HALO;
    float dep = s_dbase[px] + (float)ds * s_dstep[px];
    const float* M = mats + v * 12;
    float X = s_rx[v][px] * dep + M[9];
    float Y = s_ry[v][px] * dep + M[10];
    float Z = s_rz[v][px] * dep + M[11];
    float inv = 1.0f / Z;
    float xz = X * inv, yz = Y * inv;
    float gxn = xz * (2.0f / (float)(W - 1)) - 1.0f;
    float gyn = yz * (2.0f / (float)(H - 1)) - 1.0f;
    float ix = ((gxn + 1.0f) * (float)W - 1.0f) * 0.5f;
    float iy = ((gyn + 1.0f) * (float)H - 1.0f) * 0.5f;
    float x0f = floorf(ix), y0f = floorf(iy);
    float wx = ix - x0f, wy = iy - y0f;
    float x1f = x0f + 1.0f, y1f = y0f + 1.0f;
    bool vx0 = (x0f >= 0.0f) && (x0f <= (float)(W - 1));
    bool vx1 = (x1f >= 0.0f) && (x1f <= (float)(W - 1));
    bool vy0 = (y0f >= 0.0f) && (y0f <= (float)(H - 1));
    bool vy1 = (y1f >= 0.0f) && (y1f <= (float)(H - 1));
    int xc0 = (int)fminf(fmaxf(x0f, 0.0f), (float)(W - 1));
    int xc1 = (int)fminf(fmaxf(x1f, 0.0f), (float)(W - 1));
    int yc0 = (int)fminf(fmaxf(y0f, 0.0f), (float)(H - 1));
    int yc1 = (int)fminf(fmaxf(y1f, 0.0f), (float)(H - 1));
    s_ci[b][v][0][px] = yc0 * W + xc0;
    s_ci[b][v][1][px] = yc0 * W + xc1;
    s_ci[b][v][2][px] = yc1 * W + xc0;
    s_ci[b][v][3][px] = yc1 * W + xc1;
    float wxm = 1.0f - wx, wym = 1.0f - wy;
    s_cw[b][v][0][px] = (vx0 && vy0) ? wxm * wym : 0.0f;
    s_cw[b][v][1][px] = (vx1 && vy0) ? wx * wym : 0.0f;
    s_cw[b][v][2][px] = (vx0 && vy1) ? wxm * wy : 0.0f;
    s_cw[b][v][3][px] = (vx1 && vy1) ? wx * wy : 0.0f;
  };

  auto do_variance = [&](int b, int b2, int i) {
    if constexpr (CL) {
      int px = i / C4, cg = i - (i / C4) * C4;
      float o0 = 0.f, o1 = 0.f, o2 = 0.f, o3 = 0.f;
      if (s_inb[px]) {
        const float4* fp = (const float4*)feats;
        float4 r = fp[(size_t)s_gidx[px] * C4 + cg];
        float s0 = r.x, s1 = r.y, s2 = r.z, s3 = r.w;
        float q0 = r.x * r.x, q1 = r.y * r.y, q2 = r.z * r.z, q3 = r.w * r.w;
#pragma unroll
        for (int v = 0; v < 2; ++v) {
          const float4* fv = fp + (size_t)(v + 1) * H * W * C4 + cg;
          float a00 = s_cw[b][v][0][px], a10 = s_cw[b][v][1][px];
          float a01 = s_cw[b][v][2][px], a11 = s_cw[b][v][3][px];
          float4 p00 = fv[(size_t)s_ci[b][v][0][px] * C4];
          float4 p10 = fv[(size_t)s_ci[b][v][1][px] * C4];
          float4 p01 = fv[(size_t)s_ci[b][v][2][px] * C4];
          float4 p11 = fv[(size_t)s_ci[b][v][3][px] * C4];
          float g0 = a00 * p00.x + a10 * p10.x + a01 * p01.x + a11 * p11.x;
          float g1 = a00 * p00.y + a10 * p10.y + a01 * p01.y + a11 * p11.y;
          float g2 = a00 * p00.z + a10 * p10.z + a01 * p01.z + a11 * p11.z;
          float g3 = a00 * p00.w + a10 * p10.w + a01 * p01.w + a11 * p11.w;
          s0 += g0; q0 += g0 * g0;
          s1 += g1; q1 += g1 * g1;
          s2 += g2; q2 += g2 * g2;
          s3 += g3; q3 += g3 * g3;
        }
        float m;
        m = s0 / 3.0f; o0 = q0 / 3.0f - m * m;
        m = s1 / 3.0f; o1 = q1 / 3.0f - m * m;
        m = s2 / 3.0f; o2 = q2 / 3.0f - m * m;
        m = s3 / 3.0f; o3 = q3 / 3.0f - m * m;
      }
      int cb = cg * 4;
      s_var[b2][(cb + 0) * HP + px] = o0;
      s_var[b2][(cb + 1) * HP + px] = o1;
      s_var[b2][(cb + 2) * HP + px] = o2;
      s_var[b2][(cb + 3) * HP + px] = o3;
    } else {
      int c = i / HALO, px = i - (i / HALO) * HALO;
      float var = 0.f;
      if (s_inb[px]) {
        const float* f0 = feats + (size_t)c * (H * W);
        float rr = f0[s_gidx[px]];
        float sum = rr, ssq = rr * rr;
#pragma unroll
        for (int v = 0; v < 2; ++v) {
          const float* fv = feats + ((size_t)(v + 1) * C + c) * (H * W);
          float val = s_cw[b][v][0][px] * fv[s_ci[b][v][0][px]] +
                      s_cw[b][v][1][px] * fv[s_ci[b][v][1][px]] +
                      s_cw[b][v][2][px] * fv[s_ci[b][v][2][px]] +
                      s_cw[b][v][3][px] * fv[s_ci[b][v][3][px]];
          sum += val;
          ssq += val * val;
        }
        float m = sum / 3.0f;
        var = ssq / 3.0f - m * m;
      }
      s_var[b2][c * HP + px] = var;
    }
  };

  auto conv_accum = [&](int ds, int sb) {
    for (int i = tid; i < NPX * 4; i += 256) {
      int grp = i / NPX, opx = i - grp * NPX;
      int py = opx / TW, pxx = opx - py * TW;
      float a0 = 0.f, a1 = 0.f, a2 = 0.f;
      int cbase = grp * CG;
#pragma unroll
      for (int kh = 0; kh < 3; ++kh) {
#pragma unroll
        for (int kw = 0; kw < 3; ++kw) {
          int hp = (py + kh) * WB + (pxx + kw);
#pragma unroll
          for (int cc = 0; cc < CG; ++cc) {
            int c = cbase + cc;
            float vv = s_var[sb][c * HP + hp];
            const float* wp = s_w + c * 27 + kh * 3 + kw;
            a0 += vv * wp[0];
            a1 += vv * wp[9];
            a2 += vv * wp[18];
          }
        }
      }
      int t0 = ds + 1 - d0;
      int t1 = ds - d0;
      int t2 = ds - 1 - d0;
      if (t0 >= 0 && t0 < DC) atomicAdd(&s_cost[t0 * NPX + opx], a0);
      if (t1 >= 0 && t1 < DC) atomicAdd(&s_cost[t1 * NPX + opx], a1);
      if (t2 >= 0 && t2 < DC) atomicAdd(&s_cost[t2 * NPX + opx], a2);
    }
  };

  {
    int ds0 = d0 - 1;
    if (ds0 >= 0 && ds0 < DTOT)
      for (int i = tid; i < 2 * HALO; i += 256) do_coords(ds0, 0, i);
  }
  __syncthreads();

  for (int s = 0; s <= NS; ++s) {
    const int ds = d0 - 1 + s;
    const bool val_cur = (s < NS) && (ds >= 0) && (ds < DTOT);
    const bool val_next = (s + 1 < NS) && (ds + 1 >= 0) && (ds + 1 < DTOT);
    const bool val_prev = (s >= 1) && (ds - 1 >= 0) && (ds - 1 < DTOT);
    if (val_cur)
      for (int i = tid; i < VITEMS; i += 256) do_variance(s & 1, s & 1, i);
    if (val_next)
      for (int i = tid; i < 2 * HALO; i += 256) do_coords(ds + 1, (s + 1) & 1, i);
    if (val_prev) conv_accum(ds - 1, (s - 1) & 1);
    __syncthreads();
  }

  if constexpr (!EPI) {
    for (int i = tid; i < DC * NPX; i += 256) {
      int dd = i / NPX, opx = i - dd * NPX;
      int py = opx / TW, pxx = opx - py * TW;
      g_cost[(size_t)(d0 + dd) * (H * W) + (h0 + py) * W + (w0 + pxx)] = s_cost[i];
    }
  } else if (tid < NPX) {
    const int opx = tid;
    const int py = opx / TW, pxx = opx - py * TW;
    const int hp = (py + 1) * WB + (pxx + 1);
    const float base = s_dbase[hp], st = s_dstep[hp];
    float mx = -3.0e38f;
    for (int dd = 0; dd < DTOT; ++dd) mx = fmaxf(mx, s_cost[dd * NPX + opx]);
    float se = 0.f;
    for (int dd = 0; dd < DTOT; ++dd) {
      float e = expf(s_cost[dd * NPX + opx] - mx);
      s_cost[dd * NPX + opx] = e;
      se += e;
    }
    float depth = 0.f, dif = 0.f;
    for (int dd = 0; dd < DTOT; ++dd) {
      float p = s_cost[dd * NPX + opx] / se;
      s_cost[dd * NPX + opx] = p;
      depth += p * (base + (float)dd * st);
      dif += p * (float)dd;
    }
    int di = (int)dif;
    di = min(max(di, 0), DTOT - 1);
    float conf = 0.f;
    for (int k = di - 1; k <= di + 2; ++k)
      if (k >= 0 && k < DTOT) conf += s_cost[k * NPX + opx];
    float ev = 0.f;
    for (int dd = 0; dd < DTOT; ++dd) {
      float sv = base + (float)dd * st - depth;
      ev += sv * sv * s_cost[dd * NPX + opx];
    }
    ev = 1.5f * sqrtf(ev);
    int gy = h0 + py, gx = w0 + pxx;
    out_d[gy * W + gx] = depth;
    out_c[gy * W + gx] = conf;
    out_v[gy * W + gx] = ev;
  }
}

extern "C" void kernel_launch(void* const* d_in, const int* in_sizes, int n_in,
                              void* d_out, int out_size, void* d_ws, size_t ws_size,
                              hipStream_t stream) {
  const float* feats1 = (const float*)d_in[0];
  const float* feats2 = (const float*)d_in[1];
  const float* proj1 = (const float*)d_in[2];
  const float* proj2 = (const float*)d_in[3];
  const float* depthv = (const float*)d_in[4];
  const float* w1 = (const float*)d_in[6];
  const float* b1 = (const float*)d_in[7];
  const float* w2 = (const float*)d_in[8];
  const float* b2 = (const float*)d_in[9];
  float* out = (float*)d_out;
  float* ws = (float*)d_ws;

  const int nd = in_sizes[4];
  const size_t F1 = (size_t)3 * 32 * 128 * 160;   // 1,966,080
  const size_t F2 = (size_t)3 * 16 * 256 * 320;   // 3,932,160
  const size_t COST1 = (size_t)48 * 128 * 160;    // 983,040
  const size_t COST2 = (size_t)8 * 256 * 320;     // 655,360
  const size_t VAR1 = (size_t)48 * 128 * 160 * 32;  // 31,457,280
  const size_t VAR2 = (size_t)8 * 256 * 320 * 16;   // 10,485,760
  const size_t HUGE_FLOATS = 64 + COST1 + COST2 + F1 + F2 + VAR1 + VAR2;
  const bool huge = ws_size >= HUGE_FLOATS * sizeof(float);
  const bool big = ws_size >= (64 + COST1 + F1 + F2) * sizeof(float);
  const bool mid = ws_size >= (64 + COST1) * sizeof(float);

  setup_mats_kernel<<<1, 64, 0, stream>>>(proj1, proj2, depthv, nd, ws);

  float* d1 = out;
  float* c1 = out + 20480;
  float* v1 = out + 40960;
  float* d2 = out + 61440;
  float* c2 = out + 143360;
  float* v2 = out + 225280;

  dim3 g1c(160 / 8, 128 / 8, 6), g1f(160 / 8, 128 / 8, 1), g2(320 / 8, 256 / 8, 1);

  if (huge) {
    float* cost1 = ws + 64;
    float* cost2 = cost1 + COST1;
    float* f1t = cost2 + COST2;
    float* f2t = f1t + F1;
    float* var1 = f2t + F2;
    float* var2 = var1 + VAR1;
    transpose_cl_kernel<<<(int)((F1 + 255) / 256), 256, 0, stream>>>(feats1, f1t, 32, 128, 160);
    transpose_cl_kernel<<<(int)((F2 + 255) / 256), 256, 0, stream>>>(feats2, f2t, 16, 256, 320);
    // stage 1
    gather_var_kernel<32, 48, 128, 160, false><<<(int)(VAR1 / 4 / 256), 256, 0, stream>>>(
        f1t, ws, ws + 48, nullptr, nullptr, (float4*)var1);
    conv_cost_kernel<32, 48, 8, 8, 8, 128, 160><<<g1c, 256, 0, stream>>>(
        (const float4*)var1, w1, b1, cost1);
    epilogue_kernel<48, 128, 160, false><<<80, 256, 0, stream>>>(
        cost1, ws + 48, nullptr, nullptr, d1, c1, v1);
    // stage 2
    gather_var_kernel<16, 8, 256, 320, true><<<(int)(VAR2 / 4 / 256), 256, 0, stream>>>(
        f2t, ws + 24, ws + 48, d1, v1, (float4*)var2);
    conv_cost_kernel<16, 8, 8, 8, 8, 256, 320><<<dim3(40, 32, 1), 256, 0, stream>>>(
        (const float4*)var2, w2, b2, cost2);
    epilogue_kernel<8, 256, 320, true><<<320, 256, 0, stream>>>(
        cost2, ws + 48, d1, v1, d2, c2, v2);
  } else if (big) {
    float* cost1 = ws + 64;
    float* f1t = ws + 64 + COST1;
    float* f2t = f1t + F1;
    transpose_cl_kernel<<<(int)((F1 + 255) / 256), 256, 0, stream>>>(feats1, f1t, 32, 128, 160);
    transpose_cl_kernel<<<(int)((F2 + 255) / 256), 256, 0, stream>>>(feats2, f2t, 16, 256, 320);
    cost_kernel<32, 48, 8, 8, 8, 128, 160, false, true, false><<<g1c, 256, 0, stream>>>(
        f1t, w1, b1, ws, ws + 48, nullptr, nullptr, cost1, nullptr, nullptr, nullptr);
    epilogue_kernel<48, 128, 160, false><<<80, 256, 0, stream>>>(
        cost1, ws + 48, nullptr, nullptr, d1, c1, v1);
    cost_kernel<16, 8, 8, 8, 8, 256, 320, true, true, true><<<g2, 256, 0, stream>>>(
        f2t, w2, b2, ws + 24, ws + 48, d1, v1, nullptr, d2, c2, v2);
  } else if (mid) {
    float* cost1 = ws + 64;
    cost_kernel<32, 48, 8, 8, 8, 128, 160, false, false, false><<<g1c, 256, 0, stream>>>(
        feats1, w1, b1, ws, ws + 48, nullptr, nullptr, cost1, nullptr, nullptr, nullptr);
    epilogue_kernel<48, 128, 160, false><<<80, 256, 0, stream>>>(
        cost1, ws + 48, nullptr, nullptr, d1, c1, v1);
    cost_kernel<16, 8, 8, 8, 8, 256, 320, true, false, true><<<g2, 256, 0, stream>>>(
        feats2, w2, b2, ws + 24, ws + 48, d1, v1, nullptr, d2, c2, v2);
  } else {
    cost_kernel<32, 48, 48, 8, 8, 128, 160, false, false, true><<<g1f, 256, 0, stream>>>(
        feats1, w1, b1, ws, ws + 48, nullptr, nullptr, nullptr, d1, c1, v1);
    cost_kernel<16, 8, 8, 8, 8, 256, 320, true, false, true><<<g2, 256, 0, stream>>>(
        feats2, w2, b2, ws + 24, ws + 48, d1, v1, nullptr, d2, c2, v2);
  }
}

// Round 6
// 461.859 us; speedup vs baseline: 3.1553x; 1.2082x over previous
//
#include <hip/hip_runtime.h>
#include <math.h>

// ---------------------------------------------------------------------------
// CoarseMVSNet, de-fused pipeline (R5) with LDS-lean conv (R6):
//   gather_var_kernel : 1 thread = 1 (d,px,cg) float4 of variance volume.
//   conv_cost_kernel  : 3x3x3 conv; var via ds_read_b128 ([px][C+4] layout),
//                       weights via SCALAR loads (wave-uniform readfirstlane),
//                       register-prefetch staging, 1 barrier/slice.
//   range_kernel      : stage-2 per-pixel (base,step) precompute.
//   epilogue_kernel   : softmax/depth/conf/exp-var.
// R5 post-mortem: old conv spent ~75% of its LDS-pipe time broadcasting
// WEIGHTS from LDS (216 of 288 ds_read per item). Weights are wave-uniform ->
// scalar pipe; var reads vectorized to b128.
// __launch_bounds__(256) ONLY (R2: (256,4) forced VGPR->64, 4.2 GB spill).
// ---------------------------------------------------------------------------

__global__ void setup_mats_kernel(const float* __restrict__ proj1,
                                  const float* __restrict__ proj2,
                                  const float* __restrict__ depthv, int nd,
                                  float* __restrict__ ws) {
  if (threadIdx.x != 0 || blockIdx.x != 0) return;
  for (int s = 0; s < 2; ++s) {
    const float* P = s ? proj2 : proj1;  // (3,2,4,4) flat
    double comp[3][4][4];
    for (int v = 0; v < 3; ++v) {
      const float* E = P + v * 32;       // [v][0]
      const float* K = P + v * 32 + 16;  // [v][1]
      for (int r = 0; r < 3; ++r)
        for (int c = 0; c < 4; ++c) {
          double acc = 0.0;
          for (int k = 0; k < 3; ++k) acc += (double)K[r * 4 + k] * (double)E[k * 4 + c];
          comp[v][r][c] = acc;
        }
      for (int c = 0; c < 4; ++c) comp[v][3][c] = (double)E[12 + c];
    }
    double a[4][8];
    for (int r = 0; r < 4; ++r)
      for (int c = 0; c < 4; ++c) {
        a[r][c] = comp[0][r][c];
        a[r][4 + c] = (r == c) ? 1.0 : 0.0;
      }
    for (int col = 0; col < 4; ++col) {
      int piv = col;
      double best = fabs(a[col][col]);
      for (int r = col + 1; r < 4; ++r) {
        double t = fabs(a[r][col]);
        if (t > best) { best = t; piv = r; }
      }
      if (piv != col)
        for (int c = 0; c < 8; ++c) { double t = a[col][c]; a[col][c] = a[piv][c]; a[piv][c] = t; }
      double dv = a[col][col];
      for (int c = 0; c < 8; ++c) a[col][c] /= dv;
      for (int r = 0; r < 4; ++r)
        if (r != col) {
          double f = a[r][col];
          if (f != 0.0)
            for (int c = 0; c < 8; ++c) a[r][c] -= f * a[col][c];
        }
    }
    for (int v = 1; v < 3; ++v) {
      double Pm[3][4];
      for (int r = 0; r < 3; ++r)
        for (int c = 0; c < 4; ++c) {
          double acc = 0.0;
          for (int k = 0; k < 4; ++k) acc += comp[v][r][k] * a[k][4 + c];
          Pm[r][c] = acc;
        }
      float* o = ws + s * 24 + (v - 1) * 12;
      o[0] = (float)Pm[0][0]; o[1] = (float)Pm[0][1]; o[2] = (float)Pm[0][2];
      o[3] = (float)Pm[1][0]; o[4] = (float)Pm[1][1]; o[5] = (float)Pm[1][2];
      o[6] = (float)Pm[2][0]; o[7] = (float)Pm[2][1]; o[8] = (float)Pm[2][2];
      o[9] = (float)Pm[0][3]; o[10] = (float)Pm[1][3]; o[11] = (float)Pm[2][3];
    }
  }
  ws[48] = depthv[0];
  ws[49] = (depthv[nd - 1] - depthv[0]) / 47.0f;  // (dmax-dmin)/(ND1-1)
}

__global__ void transpose_cl_kernel(const float* __restrict__ in, float* __restrict__ out,
                                    int C, int H, int W) {
  int total = 3 * C * H * W;
  int idx = blockIdx.x * 256 + threadIdx.x;
  if (idx >= total) return;
  int c = idx % C;
  int t = idx / C;
  int w = t % W;
  int t2 = t / W;
  int h = t2 % H;
  int v = t2 / H;
  out[idx] = in[((size_t)(v * C + c) * H + h) * W + w];
}

// Per-pixel depth range for STAGE2: bilinear 2x upsample of d1/v1.
template <int D, int H, int W>
__device__ inline void stage2_range(const float* __restrict__ prev_d,
                                    const float* __restrict__ prev_v,
                                    int gy, int gx, float& base, float& st) {
  constexpr int SH = H / 2, SW = W / 2;
  float syf = 0.5f * (float)gy - 0.25f;
  float sxf = 0.5f * (float)gx - 0.25f;
  syf = fminf(fmaxf(syf, 0.0f), (float)(SH - 1));
  sxf = fminf(fmaxf(sxf, 0.0f), (float)(SW - 1));
  int sy0 = (int)syf, sx0 = (int)sxf;
  float fy2 = syf - (float)sy0, fx2 = sxf - (float)sx0;
  int sy1 = min(sy0 + 1, SH - 1), sx1 = min(sx0 + 1, SW - 1);
  int j00 = sy0 * SW + sx0, j01 = sy0 * SW + sx1;
  int j10 = sy1 * SW + sx0, j11 = sy1 * SW + sx1;
  float cd = (prev_d[j00] * (1.f - fx2) + prev_d[j01] * fx2) * (1.f - fy2) +
             (prev_d[j10] * (1.f - fx2) + prev_d[j11] * fx2) * fy2;
  float cv = (prev_v[j00] * (1.f - fx2) + prev_v[j01] * fx2) * (1.f - fy2) +
             (prev_v[j10] * (1.f - fx2) + prev_v[j11] * fx2) * fy2;
  float lo = -fminf(cd, cv);
  base = cd + lo + 1e-12f;
  st = (cv - lo) / (float)(D - 1);
}

template <int D, int H, int W>
__global__ void range_kernel(const float* __restrict__ prev_d,
                             const float* __restrict__ prev_v,
                             float2* __restrict__ rng) {
  int pix = blockIdx.x * 256 + threadIdx.x;
  if (pix >= H * W) return;
  float b, s;
  stage2_range<D, H, W>(prev_d, prev_v, pix / W, pix % W, b, s);
  rng[pix] = make_float2(b, s);
}

// One thread computes one float4 (4 channels) of the variance volume at
// (d, gy, gx). feats channel-last (V,H,W,C). Branchless, no LDS, no barriers.
template <int C, int DTOT, int H, int W, bool STAGE2>
__launch_bounds__(256)
__global__ void gather_var_kernel(const float* __restrict__ feats,
                                  const float* __restrict__ mats,
                                  const float* __restrict__ dpar,
                                  const float2* __restrict__ rng,
                                  float4* __restrict__ var_out) {
  constexpr int C4 = C / 4;
  const int idx = blockIdx.x * 256 + threadIdx.x;
  if (idx >= DTOT * H * W * C4) return;
  const int cg = idx % C4;
  const int t = idx / C4;          // (d*H + gy)*W + gx
  const int gx = t % W;
  const int t2 = t / W;
  const int gy = t2 % H;
  const int d = t2 / H;
  const int pix = gy * W + gx;

  float base, st;
  if constexpr (STAGE2) {
    float2 r = rng[pix];
    base = r.x;
    st = r.y;
  } else {
    base = dpar[0];
    st = dpar[1];
  }
  const float dep = base + (float)d * st;

  const float4* fp = (const float4*)feats;
  float4 r = fp[(size_t)pix * C4 + cg];
  float s0 = r.x, s1 = r.y, s2 = r.z, s3 = r.w;
  float q0 = r.x * r.x, q1 = r.y * r.y, q2 = r.z * r.z, q3 = r.w * r.w;

#pragma unroll
  for (int v = 0; v < 2; ++v) {
    const float* M = mats + v * 12;
    float fx = (float)gx, fy = (float)gy;
    float X = (M[0] * fx + M[1] * fy + M[2]) * dep + M[9];
    float Y = (M[3] * fx + M[4] * fy + M[5]) * dep + M[10];
    float Z = (M[6] * fx + M[7] * fy + M[8]) * dep + M[11];
    float inv = 1.0f / Z;
    float xz = X * inv, yz = Y * inv;
    float gxn = xz * (2.0f / (float)(W - 1)) - 1.0f;
    float gyn = yz * (2.0f / (float)(H - 1)) - 1.0f;
    float ix = ((gxn + 1.0f) * (float)W - 1.0f) * 0.5f;
    float iy = ((gyn + 1.0f) * (float)H - 1.0f) * 0.5f;
    float x0f = floorf(ix), y0f = floorf(iy);
    float wx = ix - x0f, wy = iy - y0f;
    float x1f = x0f + 1.0f, y1f = y0f + 1.0f;
    bool vx0 = (x0f >= 0.0f) && (x0f <= (float)(W - 1));
    bool vx1 = (x1f >= 0.0f) && (x1f <= (float)(W - 1));
    bool vy0 = (y0f >= 0.0f) && (y0f <= (float)(H - 1));
    bool vy1 = (y1f >= 0.0f) && (y1f <= (float)(H - 1));
    int xc0 = (int)fminf(fmaxf(x0f, 0.0f), (float)(W - 1));
    int xc1 = (int)fminf(fmaxf(x1f, 0.0f), (float)(W - 1));
    int yc0 = (int)fminf(fmaxf(y0f, 0.0f), (float)(H - 1));
    int yc1 = (int)fminf(fmaxf(y1f, 0.0f), (float)(H - 1));
    float wxm = 1.0f - wx, wym = 1.0f - wy;
    float a00 = (vx0 && vy0) ? wxm * wym : 0.0f;
    float a10 = (vx1 && vy0) ? wx * wym : 0.0f;
    float a01 = (vx0 && vy1) ? wxm * wy : 0.0f;
    float a11 = (vx1 && vy1) ? wx * wy : 0.0f;
    const float4* fv = fp + (size_t)(v + 1) * H * W * C4 + cg;
    float4 p00 = fv[(size_t)(yc0 * W + xc0) * C4];
    float4 p10 = fv[(size_t)(yc0 * W + xc1) * C4];
    float4 p01 = fv[(size_t)(yc1 * W + xc0) * C4];
    float4 p11 = fv[(size_t)(yc1 * W + xc1) * C4];
    float g0 = a00 * p00.x + a10 * p10.x + a01 * p01.x + a11 * p11.x;
    float g1 = a00 * p00.y + a10 * p10.y + a01 * p01.y + a11 * p11.y;
    float g2 = a00 * p00.z + a10 * p10.z + a01 * p01.z + a11 * p11.z;
    float g3 = a00 * p00.w + a10 * p10.w + a01 * p01.w + a11 * p11.w;
    s0 += g0; q0 += g0 * g0;
    s1 += g1; q1 += g1 * g1;
    s2 += g2; q2 += g2 * g2;
    s3 += g3; q3 += g3 * g3;
  }
  float m;
  float4 o;
  m = s0 / 3.0f; o.x = q0 / 3.0f - m * m;
  m = s1 / 3.0f; o.y = q1 / 3.0f - m * m;
  m = s2 / 3.0f; o.z = q2 / 3.0f - m * m;
  m = s3 / 3.0f; o.w = q3 / 3.0f - m * m;
  var_out[idx] = o;
}

// 3x3x3 conv over the variance volume -> cost volume [d][pix].
// 8x8 tile, DC owned cost slices (blockIdx.z). Var slices staged to LDS in
// [px][C+4] layout (b128 reads, spread banks); weights read via SCALAR loads
// (grp is wave-uniform); register-prefetch staging, 1 barrier/slice.
template <int C, int DTOT, int DC, int H, int W>
__launch_bounds__(256)
__global__ void conv_cost_kernel(const float4* __restrict__ var_in,
                                 const float* __restrict__ wconv,
                                 const float* __restrict__ bconv,
                                 float* __restrict__ g_cost) {
  constexpr int TH = 8, TW = 8, HB = 10, WB = 10, HALO = 100, NPX = 64;
  constexpr int C4 = C / 4;
  constexpr int CG = C / 4;       // channels per conv group (4 groups)
  constexpr int Q = C / 16;       // float4s per group per position
  constexpr int SROW4 = C4 + 1;   // float4 stride per px (pad 16 B)
  constexpr int NS = DC + 2;
  constexpr int PFN = (HALO * C4 + 255) / 256;

  __shared__ float4 s_in[2][HALO * SROW4];
  __shared__ float s_cost[DC * NPX];

  const int tid = threadIdx.x;
  const int h0 = blockIdx.y * TH;
  const int w0 = blockIdx.x * TW;
  const int d0 = blockIdx.z * DC;

  {
    float bias = bconv[0];
    for (int i = tid; i < DC * NPX; i += 256) s_cost[i] = bias;
  }

  float4 pf[PFN];
  auto prefetch = [&](int ds) {
#pragma unroll
    for (int k = 0; k < PFN; ++k) {
      int i = tid + k * 256;
      float4 r = make_float4(0.f, 0.f, 0.f, 0.f);
      if (i < HALO * C4) {
        int px = i / C4, cg = i - (i / C4) * C4;
        int hy = px / WB, hx = px - hy * WB;
        int gy = h0 + hy - 1, gx = w0 + hx - 1;
        if (ds >= 0 && ds < DTOT && gy >= 0 && gy < H && gx >= 0 && gx < W)
          r = var_in[((size_t)(ds * H + gy) * W + gx) * C4 + cg];
      }
      pf[k] = r;
    }
  };
  auto commit = [&](int b) {
#pragma unroll
    for (int k = 0; k < PFN; ++k) {
      int i = tid + k * 256;
      if (i < HALO * C4) {
        int px = i / C4, cg = i - (i / C4) * C4;
        s_in[b][px * SROW4 + cg] = pf[k];
      }
    }
  };

  const int grp = tid >> 6;   // wave id -> wave-uniform
  const int opx = tid & 63;
  const int py = opx >> 3, pxx = opx & 7;
  // force weight indexing onto the scalar pipe
  const int gofs = __builtin_amdgcn_readfirstlane(grp * CG * 27);
  const float* __restrict__ wbase = wconv + gofs;
  const int gq = __builtin_amdgcn_readfirstlane(grp * Q);

  auto conv_accum = [&](int ds, int sb) {
    float a0 = 0.f, a1 = 0.f, a2 = 0.f;  // kd = 0,1,2
#pragma unroll
    for (int kh = 0; kh < 3; ++kh) {
#pragma unroll
      for (int kw = 0; kw < 3; ++kw) {
        int hp = (py + kh) * WB + (pxx + kw);
        const float4* vp = &s_in[sb][hp * SROW4 + gq];
#pragma unroll
        for (int q = 0; q < Q; ++q) {
          float4 v = vp[q];
          const float* wp = wbase + (q * 4) * 27 + kh * 3 + kw;  // uniform
          a0 += v.x * wp[0]  + v.y * wp[27] + v.z * wp[54] + v.w * wp[81];
          a1 += v.x * wp[9]  + v.y * wp[36] + v.z * wp[63] + v.w * wp[90];
          a2 += v.x * wp[18] + v.y * wp[45] + v.z * wp[72] + v.w * wp[99];
        }
      }
    }
    int t0 = ds + 1 - d0;  // kd=0 feeds cost slice ds+1
    int t1 = ds - d0;      // kd=1
    int t2 = ds - 1 - d0;  // kd=2
    if (t0 >= 0 && t0 < DC) atomicAdd(&s_cost[t0 * NPX + opx], a0);
    if (t1 >= 0 && t1 < DC) atomicAdd(&s_cost[t1 * NPX + opx], a1);
    if (t2 >= 0 && t2 < DC) atomicAdd(&s_cost[t2 * NPX + opx], a2);
  };

  prefetch(d0 - 1);
  commit(0);
  __syncthreads();
  for (int s = 1; s <= NS; ++s) {
    if (s < NS) prefetch(d0 - 1 + s);     // global loads in flight...
    conv_accum(d0 - 1 + (s - 1), (s - 1) & 1);  // ...hidden under conv
    if (s < NS) commit(s & 1);
    __syncthreads();
  }

  for (int i = tid; i < DC * NPX; i += 256) {
    int dd = i / NPX, o = i - dd * NPX;
    int oy = o / TW, ox = o - oy * TW;
    g_cost[(size_t)(d0 + dd) * (H * W) + (h0 + oy) * W + (w0 + ox)] = s_cost[i];
  }
}

template <int D, int H, int W, bool STAGE2>
__global__ void epilogue_kernel(const float* __restrict__ g_cost,
                                const float* __restrict__ dpar,
                                const float2* __restrict__ rng,
                                float* __restrict__ out_d,
                                float* __restrict__ out_c,
                                float* __restrict__ out_v) {
  int pix = blockIdx.x * 256 + threadIdx.x;
  if (pix >= H * W) return;
  float base, st;
  if constexpr (STAGE2) {
    float2 r = rng[pix];
    base = r.x;
    st = r.y;
  } else {
    base = dpar[0];
    st = dpar[1];
  }
  float c[D];
#pragma unroll
  for (int dd = 0; dd < D; ++dd) c[dd] = g_cost[(size_t)dd * (H * W) + pix];
  float mx = -3.0e38f;
#pragma unroll
  for (int dd = 0; dd < D; ++dd) mx = fmaxf(mx, c[dd]);
  float se = 0.f;
#pragma unroll
  for (int dd = 0; dd < D; ++dd) {
    float e = expf(c[dd] - mx);
    c[dd] = e;
    se += e;
  }
  float depth = 0.f, dif = 0.f;
#pragma unroll
  for (int dd = 0; dd < D; ++dd) {
    float p = c[dd] / se;
    c[dd] = p;
    depth += p * (base + (float)dd * st);
    dif += p * (float)dd;
  }
  int di = (int)dif;
  di = min(max(di, 0), D - 1);
  float conf = 0.f;
#pragma unroll
  for (int dd = 0; dd < D; ++dd)
    if (dd >= di - 1 && dd <= di + 2) conf += c[dd];
  float ev = 0.f;
#pragma unroll
  for (int dd = 0; dd < D; ++dd) {
    float sv = base + (float)dd * st - depth;
    ev += sv * sv * c[dd];
  }
  ev = 1.5f * sqrtf(ev);
  out_d[pix] = depth;
  out_c[pix] = conf;
  out_v[pix] = ev;
}

// -------------------- fused fallback (R4) --------------------

template <int C, int DTOT, int DC, int TH, int TW, int H, int W, bool STAGE2, bool CL, bool EPI>
__launch_bounds__(256)
__global__ void cost_kernel(const float* __restrict__ feats,
                            const float* __restrict__ wconv,
                            const float* __restrict__ bconv,
                            const float* __restrict__ mats,
                            const float* __restrict__ dpar,
                            const float* __restrict__ prev_d,
                            const float* __restrict__ prev_v,
                            float* __restrict__ g_cost,
                            float* __restrict__ out_d,
                            float* __restrict__ out_c,
                            float* __restrict__ out_v) {
  constexpr int HB = TH + 2, WB = TW + 2, HALO = HB * WB, NPX = TH * TW;
  constexpr int HP = HALO + 1;
  constexpr int C4 = C / 4;
  constexpr int CG = C / 4;
  constexpr int NS = DC + 2;
  constexpr int VITEMS = CL ? (HALO * C4) : (HALO * C);

  __shared__ float s_var[2][C * HP];
  __shared__ float s_cost[DC * NPX];
  __shared__ float s_w[C * 27];
  __shared__ float s_rx[2][HALO], s_ry[2][HALO], s_rz[2][HALO];
  __shared__ float s_cw[2][2][4][HALO];
  __shared__ int s_ci[2][2][4][HALO];
  __shared__ int s_gidx[HALO];
  __shared__ float s_dbase[HALO], s_dstep[HALO];
  __shared__ unsigned char s_inb[HALO];

  const int tid = threadIdx.x;
  const int h0 = blockIdx.y * TH;
  const int w0 = blockIdx.x * TW;
  const int d0 = EPI ? 0 : blockIdx.z * DC;

  for (int i = tid; i < C * 27; i += 256) s_w[i] = wconv[i];

  for (int i = tid; i < HALO; i += 256) {
    int hy = i / WB, hx = i - hy * WB;
    int gy = h0 + hy - 1, gx = w0 + hx - 1;
    bool inb = (gy >= 0) && (gy < H) && (gx >= 0) && (gx < W);
    s_inb[i] = inb ? 1 : 0;
    s_gidx[i] = inb ? (gy * W + gx) : 0;
    float fx = (float)gx, fy = (float)gy;
#pragma unroll
    for (int v = 0; v < 2; ++v) {
      const float* M = mats + v * 12;
      s_rx[v][i] = M[0] * fx + M[1] * fy + M[2];
      s_ry[v][i] = M[3] * fx + M[4] * fy + M[5];
      s_rz[v][i] = M[6] * fx + M[7] * fy + M[8];
    }
    if constexpr (STAGE2) {
      float b, stp;
      stage2_range<DTOT, H, W>(prev_d, prev_v, gy, gx, b, stp);
      s_dbase[i] = b;
      s_dstep[i] = stp;
    } else {
      s_dbase[i] = dpar[0];
      s_dstep[i] = dpar[1];
    }
  }
  {
    float bias = bconv[0];
    for (int i = tid; i < DC * NPX; i += 256) s_cost[i] = bias;
  }
  __syncthreads();

  auto do_coords = [&](int ds, int b, int i) {
    int v = (i >= HALO) ? 1 : 0;
    int px = i - v * HALO;
    float dep = s_dbase[px] + (float)ds * s_dstep[px];
    const float* M = mats + v * 12;
    float X = s_rx[v][px] * dep + M[9];
    float Y = s_ry[v][px] * dep + M[10];
    float Z = s_rz[v][px] * dep + M[11];
    float inv = 1.0f / Z;
    float xz = X * inv, yz = Y * inv;
    float gxn = xz * (2.0f / (float)(W - 1)) - 1.0f;
    float gyn = yz * (2.0f / (float)(H - 1)) - 1.0f;
    float ix = ((gxn + 1.0f) * (float)W - 1.0f) * 0.5f;
    float iy = ((gyn + 1.0f) * (float)H - 1.0f) * 0.5f;
    float x0f = floorf(ix), y0f = floorf(iy);
    float wx = ix - x0f, wy = iy - y0f;
    float x1f = x0f + 1.0f, y1f = y0f + 1.0f;
    bool vx0 = (x0f >= 0.0f) && (x0f <= (float)(W - 1));
    bool vx1 = (x1f >= 0.0f) && (x1f <= (float)(W - 1));
    bool vy0 = (y0f >= 0.0f) && (y0f <= (float)(H - 1));
    bool vy1 = (y1f >= 0.0f) && (y1f <= (float)(H - 1));
    int xc0 = (int)fminf(fmaxf(x0f, 0.0f), (float)(W - 1));
    int xc1 = (int)fminf(fmaxf(x1f, 0.0f), (float)(W - 1));
    int yc0 = (int)fminf(fmaxf(y0f, 0.0f), (float)(H - 1));
    int yc1 = (int)fminf(fmaxf(y1f, 0.0f), (float)(H - 1));
    s_ci[b][v][0][px] = yc0 * W + xc0;
    s_ci[b][v][1][px] = yc0 * W + xc1;
    s_ci[b][v][2][px] = yc1 * W + xc0;
    s_ci[b][v][3][px] = yc1 * W + xc1;
    float wxm = 1.0f - wx, wym = 1.0f - wy;
    s_cw[b][v][0][px] = (vx0 && vy0) ? wxm * wym : 0.0f;
    s_cw[b][v][1][px] = (vx1 && vy0) ? wx * wym : 0.0f;
    s_cw[b][v][2][px] = (vx0 && vy1) ? wxm * wy : 0.0f;
    s_cw[b][v][3][px] = (vx1 && vy1) ? wx * wy : 0.0f;
  };

  auto do_variance = [&](int b, int b2, int i) {
    if constexpr (CL) {
      int px = i / C4, cg = i - (i / C4) * C4;
      float o0 = 0.f, o1 = 0.f, o2 = 0.f, o3 = 0.f;
      if (s_inb[px]) {
        const float4* fp = (const float4*)feats;
        float4 r = fp[(size_t)s_gidx[px] * C4 + cg];
        float s0 = r.x, s1 = r.y, s2 = r.z, s3 = r.w;
        float q0 = r.x * r.x, q1 = r.y * r.y, q2 = r.z * r.z, q3 = r.w * r.w;
#pragma unroll
        for (int v = 0; v < 2; ++v) {
          const float4* fv = fp + (size_t)(v + 1) * H * W * C4 + cg;
          float a00 = s_cw[b][v][0][px], a10 = s_cw[b][v][1][px];
          float a01 = s_cw[b][v][2][px], a11 = s_cw[b][v][3][px];
          float4 p00 = fv[(size_t)s_ci[b][v][0][px] * C4];
          float4 p10 = fv[(size_t)s_ci[b][v][1][px] * C4];
          float4 p01 = fv[(size_t)s_ci[b][v][2][px] * C4];
          float4 p11 = fv[(size_t)s_ci[b][v][3][px] * C4];
          float g0 = a00 * p00.x + a10 * p10.x + a01 * p01.x + a11 * p11.x;
          float g1 = a00 * p00.y + a10 * p10.y + a01 * p01.y + a11 * p11.y;
          float g2 = a00 * p00.z + a10 * p10.z + a01 * p01.z + a11 * p11.z;
          float g3 = a00 * p00.w + a10 * p10.w + a01 * p01.w + a11 * p11.w;
          s0 += g0; q0 += g0 * g0;
          s1 += g1; q1 += g1 * g1;
          s2 += g2; q2 += g2 * g2;
          s3 += g3; q3 += g3 * g3;
        }
        float m;
        m = s0 / 3.0f; o0 = q0 / 3.0f - m * m;
        m = s1 / 3.0f; o1 = q1 / 3.0f - m * m;
        m = s2 / 3.0f; o2 = q2 / 3.0f - m * m;
        m = s3 / 3.0f; o3 = q3 / 3.0f - m * m;
      }
      int cb = cg * 4;
      s_var[b2][(cb + 0) * HP + px] = o0;
      s_var[b2][(cb + 1) * HP + px] = o1;
      s_var[b2][(cb + 2) * HP + px] = o2;
      s_var[b2][(cb + 3) * HP + px] = o3;
    } else {
      int c = i / HALO, px = i - (i / HALO) * HALO;
      float var = 0.f;
      if (s_inb[px]) {
        const float* f0 = feats + (size_t)c * (H * W);
        float rr = f0[s_gidx[px]];
        float sum = rr, ssq = rr * rr;
#pragma unroll
        for (int v = 0; v < 2; ++v) {
          const float* fv = feats + ((size_t)(v + 1) * C + c) * (H * W);
          float val = s_cw[b][v][0][px] * fv[s_ci[b][v][0][px]] +
                      s_cw[b][v][1][px] * fv[s_ci[b][v][1][px]] +
                      s_cw[b][v][2][px] * fv[s_ci[b][v][2][px]] +
                      s_cw[b][v][3][px] * fv[s_ci[b][v][3][px]];
          sum += val;
          ssq += val * val;
        }
        float m = sum / 3.0f;
        var = ssq / 3.0f - m * m;
      }
      s_var[b2][c * HP + px] = var;
    }
  };

  auto conv_accum = [&](int ds, int sb) {
    for (int i = tid; i < NPX * 4; i += 256) {
      int grp = i / NPX, opx = i - grp * NPX;
      int py = opx / TW, pxx = opx - py * TW;
      float a0 = 0.f, a1 = 0.f, a2 = 0.f;
      int cbase = grp * CG;
#pragma unroll
      for (int kh = 0; kh < 3; ++kh) {
#pragma unroll
        for (int kw = 0; kw < 3; ++kw) {
          int hp = (py + kh) * WB + (pxx + kw);
#pragma unroll
          for (int cc = 0; cc < CG; ++cc) {
            int c = cbase + cc;
            float vv = s_var[sb][c * HP + hp];
            const float* wp = s_w + c * 27 + kh * 3 + kw;
            a0 += vv * wp[0];
            a1 += vv * wp[9];
            a2 += vv * wp[18];
          }
        }
      }
      int t0 = ds + 1 - d0;
      int t1 = ds - d0;
      int t2 = ds - 1 - d0;
      if (t0 >= 0 && t0 < DC) atomicAdd(&s_cost[t0 * NPX + opx], a0);
      if (t1 >= 0 && t1 < DC) atomicAdd(&s_cost[t1 * NPX + opx], a1);
      if (t2 >= 0 && t2 < DC) atomicAdd(&s_cost[t2 * NPX + opx], a2);
    }
  };

  {
    int ds0 = d0 - 1;
    if (ds0 >= 0 && ds0 < DTOT)
      for (int i = tid; i < 2 * HALO; i += 256) do_coords(ds0, 0, i);
  }
  __syncthreads();

  for (int s = 0; s <= NS; ++s) {
    const int ds = d0 - 1 + s;
    const bool val_cur = (s < NS) && (ds >= 0) && (ds < DTOT);
    const bool val_next = (s + 1 < NS) && (ds + 1 >= 0) && (ds + 1 < DTOT);
    const bool val_prev = (s >= 1) && (ds - 1 >= 0) && (ds - 1 < DTOT);
    if (val_cur)
      for (int i = tid; i < VITEMS; i += 256) do_variance(s & 1, s & 1, i);
    if (val_next)
      for (int i = tid; i < 2 * HALO; i += 256) do_coords(ds + 1, (s + 1) & 1, i);
    if (val_prev) conv_accum(ds - 1, (s - 1) & 1);
    __syncthreads();
  }

  if constexpr (!EPI) {
    for (int i = tid; i < DC * NPX; i += 256) {
      int dd = i / NPX, opx = i - dd * NPX;
      int py = opx / TW, pxx = opx - py * TW;
      g_cost[(size_t)(d0 + dd) * (H * W) + (h0 + py) * W + (w0 + pxx)] = s_cost[i];
    }
  } else if (tid < NPX) {
    const int opx = tid;
    const int py = opx / TW, pxx = opx - py * TW;
    const int hp = (py + 1) * WB + (pxx + 1);
    const float base = s_dbase[hp], st = s_dstep[hp];
    float mx = -3.0e38f;
    for (int dd = 0; dd < DTOT; ++dd) mx = fmaxf(mx, s_cost[dd * NPX + opx]);
    float se = 0.f;
    for (int dd = 0; dd < DTOT; ++dd) {
      float e = expf(s_cost[dd * NPX + opx] - mx);
      s_cost[dd * NPX + opx] = e;
      se += e;
    }
    float depth = 0.f, dif = 0.f;
    for (int dd = 0; dd < DTOT; ++dd) {
      float p = s_cost[dd * NPX + opx] / se;
      s_cost[dd * NPX + opx] = p;
      depth += p * (base + (float)dd * st);
      dif += p * (float)dd;
    }
    int di = (int)dif;
    di = min(max(di, 0), DTOT - 1);
    float conf = 0.f;
    for (int k = di - 1; k <= di + 2; ++k)
      if (k >= 0 && k < DTOT) conf += s_cost[k * NPX + opx];
    float ev = 0.f;
    for (int dd = 0; dd < DTOT; ++dd) {
      float sv = base + (float)dd * st - depth;
      ev += sv * sv * s_cost[dd * NPX + opx];
    }
    ev = 1.5f * sqrtf(ev);
    int gy = h0 + py, gx = w0 + pxx;
    out_d[gy * W + gx] = depth;
    out_c[gy * W + gx] = conf;
    out_v[gy * W + gx] = ev;
  }
}

extern "C" void kernel_launch(void* const* d_in, const int* in_sizes, int n_in,
                              void* d_out, int out_size, void* d_ws, size_t ws_size,
                              hipStream_t stream) {
  const float* feats1 = (const float*)d_in[0];
  const float* feats2 = (const float*)d_in[1];
  const float* proj1 = (const float*)d_in[2];
  const float* proj2 = (const float*)d_in[3];
  const float* depthv = (const float*)d_in[4];
  const float* w1 = (const float*)d_in[6];
  const float* b1 = (const float*)d_in[7];
  const float* w2 = (const float*)d_in[8];
  const float* b2 = (const float*)d_in[9];
  float* out = (float*)d_out;
  float* ws = (float*)d_ws;

  const int nd = in_sizes[4];
  const size_t F1 = (size_t)3 * 32 * 128 * 160;     // 1,966,080
  const size_t F2 = (size_t)3 * 16 * 256 * 320;     // 3,932,160
  const size_t COST1 = (size_t)48 * 128 * 160;      // 983,040
  const size_t COST2 = (size_t)8 * 256 * 320;       // 655,360
  const size_t VAR1 = (size_t)48 * 128 * 160 * 32;  // 31,457,280
  const size_t VAR2 = (size_t)8 * 256 * 320 * 16;   // 10,485,760
  const size_t RNG2 = (size_t)2 * 256 * 320;        // 163,840 (float2 per px)
  const size_t HUGE_FLOATS = 64 + COST1 + COST2 + F1 + F2 + VAR1 + VAR2 + RNG2;
  const bool huge = ws_size >= HUGE_FLOATS * sizeof(float);
  const bool big = ws_size >= (64 + COST1 + F1 + F2) * sizeof(float);
  const bool mid = ws_size >= (64 + COST1) * sizeof(float);

  setup_mats_kernel<<<1, 64, 0, stream>>>(proj1, proj2, depthv, nd, ws);

  float* d1 = out;
  float* c1 = out + 20480;
  float* v1 = out + 40960;
  float* d2 = out + 61440;
  float* c2 = out + 143360;
  float* v2 = out + 225280;

  dim3 g1c(160 / 8, 128 / 8, 6), g1f(160 / 8, 128 / 8, 1), g2(320 / 8, 256 / 8, 1);

  if (huge) {
    float* cost1 = ws + 64;
    float* cost2 = cost1 + COST1;
    float* f1t = cost2 + COST2;
    float* f2t = f1t + F1;
    float* var1 = f2t + F2;
    float* var2 = var1 + VAR1;
    float2* rng2 = (float2*)(var2 + VAR2);
    transpose_cl_kernel<<<(int)((F1 + 255) / 256), 256, 0, stream>>>(feats1, f1t, 32, 128, 160);
    transpose_cl_kernel<<<(int)((F2 + 255) / 256), 256, 0, stream>>>(feats2, f2t, 16, 256, 320);
    // stage 1
    gather_var_kernel<32, 48, 128, 160, false><<<(int)(VAR1 / 4 / 256), 256, 0, stream>>>(
        f1t, ws, ws + 48, nullptr, (float4*)var1);
    conv_cost_kernel<32, 48, 8, 128, 160><<<g1c, 256, 0, stream>>>(
        (const float4*)var1, w1, b1, cost1);
    epilogue_kernel<48, 128, 160, false><<<80, 256, 0, stream>>>(
        cost1, ws + 48, nullptr, d1, c1, v1);
    // stage 2
    range_kernel<8, 256, 320><<<320, 256, 0, stream>>>(d1, v1, rng2);
    gather_var_kernel<16, 8, 256, 320, true><<<(int)(VAR2 / 4 / 256), 256, 0, stream>>>(
        f2t, ws + 24, ws + 48, rng2, (float4*)var2);
    conv_cost_kernel<16, 8, 8, 256, 320><<<dim3(40, 32, 1), 256, 0, stream>>>(
        (const float4*)var2, w2, b2, cost2);
    epilogue_kernel<8, 256, 320, true><<<320, 256, 0, stream>>>(
        cost2, ws + 48, rng2, d2, c2, v2);
  } else if (big) {
    float* cost1 = ws + 64;
    float* f1t = ws + 64 + COST1;
    float* f2t = f1t + F1;
    transpose_cl_kernel<<<(int)((F1 + 255) / 256), 256, 0, stream>>>(feats1, f1t, 32, 128, 160);
    transpose_cl_kernel<<<(int)((F2 + 255) / 256), 256, 0, stream>>>(feats2, f2t, 16, 256, 320);
    cost_kernel<32, 48, 8, 8, 8, 128, 160, false, true, false><<<g1c, 256, 0, stream>>>(
        f1t, w1, b1, ws, ws + 48, nullptr, nullptr, cost1, nullptr, nullptr, nullptr);
    epilogue_kernel<48, 128, 160, false><<<80, 256, 0, stream>>>(
        cost1, ws + 48, nullptr, d1, c1, v1);
    cost_kernel<16, 8, 8, 8, 8, 256, 320, true, true, true><<<g2, 256, 0, stream>>>(
        f2t, w2, b2, ws + 24, ws + 48, d1, v1, nullptr, d2, c2, v2);
  } else if (mid) {
    float* cost1 = ws + 64;
    cost_kernel<32, 48, 8, 8, 8, 128, 160, false, false, false><<<g1c, 256, 0, stream>>>(
        feats1, w1, b1, ws, ws + 48, nullptr, nullptr, cost1, nullptr, nullptr, nullptr);
    epilogue_kernel<48, 128, 160, false><<<80, 256, 0, stream>>>(
        cost1, ws + 48, nullptr, d1, c1, v1);
    cost_kernel<16, 8, 8, 8, 8, 256, 320, true, false, true><<<g2, 256, 0, stream>>>(
        feats2, w2, b2, ws + 24, ws + 48, d1, v1, nullptr, d2, c2, v2);
  } else {
    cost_kernel<32, 48, 48, 8, 8, 128, 160, false, false, true><<<g1f, 256, 0, stream>>>(
        feats1, w1, b1, ws, ws + 48, nullptr, nullptr, nullptr, d1, c1, v1);
    cost_kernel<16, 8, 8, 8, 8, 256, 320, true, false, true><<<g2, 256, 0, stream>>>(
        feats2, w2, b2, ws + 24, ws + 48, d1, v1, nullptr, d2, c2, v2);
  }
}

// Round 7
// 366.470 us; speedup vs baseline: 3.9766x; 1.2603x over previous
//
#include <hip/hip_runtime.h>
#include <math.h>

// ---------------------------------------------------------------------------
// CoarseMVSNet, de-fused pipeline (R5/R6) with batched-weight conv (R7):
//   gather_var_kernel : 1 thread = 1 (d,px,cg) float4 of variance volume.
//   relayout_w_kernel : w[c][kd][kh][kw] -> w2[kh*3+kw][kd][c] (c fastest)
//                       so a wave's per-tap weights are 6 contiguous
//                       s_load_dwordx4 instead of 216 dependent s_load_dword
//                       (R6 post-mortem: conv was scalar-load-latency bound).
//   conv_cost_kernel  : 3x3x3 conv; var via ds_read_b128, weights via batched
//                       uniform loads, hoisted staging addresses.
//   range_kernel      : stage-2 per-pixel (base,step) precompute.
//   epilogue_kernel   : softmax/depth/conf/exp-var.
// __launch_bounds__(256) ONLY (R2: (256,4) forced VGPR->64, 4.2 GB spill).
// ---------------------------------------------------------------------------

__global__ void setup_mats_kernel(const float* __restrict__ proj1,
                                  const float* __restrict__ proj2,
                                  const float* __restrict__ depthv, int nd,
                                  float* __restrict__ ws) {
  if (threadIdx.x != 0 || blockIdx.x != 0) return;
  for (int s = 0; s < 2; ++s) {
    const float* P = s ? proj2 : proj1;  // (3,2,4,4) flat
    double comp[3][4][4];
    for (int v = 0; v < 3; ++v) {
      const float* E = P + v * 32;       // [v][0]
      const float* K = P + v * 32 + 16;  // [v][1]
      for (int r = 0; r < 3; ++r)
        for (int c = 0; c < 4; ++c) {
          double acc = 0.0;
          for (int k = 0; k < 3; ++k) acc += (double)K[r * 4 + k] * (double)E[k * 4 + c];
          comp[v][r][c] = acc;
        }
      for (int c = 0; c < 4; ++c) comp[v][3][c] = (double)E[12 + c];
    }
    double a[4][8];
    for (int r = 0; r < 4; ++r)
      for (int c = 0; c < 4; ++c) {
        a[r][c] = comp[0][r][c];
        a[r][4 + c] = (r == c) ? 1.0 : 0.0;
      }
    for (int col = 0; col < 4; ++col) {
      int piv = col;
      double best = fabs(a[col][col]);
      for (int r = col + 1; r < 4; ++r) {
        double t = fabs(a[r][col]);
        if (t > best) { best = t; piv = r; }
      }
      if (piv != col)
        for (int c = 0; c < 8; ++c) { double t = a[col][c]; a[col][c] = a[piv][c]; a[piv][c] = t; }
      double dv = a[col][col];
      for (int c = 0; c < 8; ++c) a[col][c] /= dv;
      for (int r = 0; r < 4; ++r)
        if (r != col) {
          double f = a[r][col];
          if (f != 0.0)
            for (int c = 0; c < 8; ++c) a[r][c] -= f * a[col][c];
        }
    }
    for (int v = 1; v < 3; ++v) {
      double Pm[3][4];
      for (int r = 0; r < 3; ++r)
        for (int c = 0; c < 4; ++c) {
          double acc = 0.0;
          for (int k = 0; k < 4; ++k) acc += comp[v][r][k] * a[k][4 + c];
          Pm[r][c] = acc;
        }
      float* o = ws + s * 24 + (v - 1) * 12;
      o[0] = (float)Pm[0][0]; o[1] = (float)Pm[0][1]; o[2] = (float)Pm[0][2];
      o[3] = (float)Pm[1][0]; o[4] = (float)Pm[1][1]; o[5] = (float)Pm[1][2];
      o[6] = (float)Pm[2][0]; o[7] = (float)Pm[2][1]; o[8] = (float)Pm[2][2];
      o[9] = (float)Pm[0][3]; o[10] = (float)Pm[1][3]; o[11] = (float)Pm[2][3];
    }
  }
  ws[48] = depthv[0];
  ws[49] = (depthv[nd - 1] - depthv[0]) / 47.0f;  // (dmax-dmin)/(ND1-1)
}

__global__ void transpose_cl_kernel(const float* __restrict__ in, float* __restrict__ out,
                                    int C, int H, int W) {
  int total = 3 * C * H * W;
  int idx = blockIdx.x * 256 + threadIdx.x;
  if (idx >= total) return;
  int c = idx % C;
  int t = idx / C;
  int w = t % W;
  int t2 = t / W;
  int h = t2 % H;
  int v = t2 / H;
  out[idx] = in[((size_t)(v * C + c) * H + h) * W + w];
}

// w[c][kd][kh][kw] -> w2[kh*3+kw][kd][c]
__global__ void relayout_w_kernel(const float* __restrict__ w, float* __restrict__ w2, int C) {
  int i = blockIdx.x * 256 + threadIdx.x;
  if (i >= 27 * C) return;
  int c = i % C;
  int r = i / C;
  int kd = r % 3;
  int t = r / 3;  // kh*3+kw
  w2[(t * 3 + kd) * C + c] = w[c * 27 + kd * 9 + t];
}

// Per-pixel depth range for STAGE2: bilinear 2x upsample of d1/v1.
template <int D, int H, int W>
__device__ inline void stage2_range(const float* __restrict__ prev_d,
                                    const float* __restrict__ prev_v,
                                    int gy, int gx, float& base, float& st) {
  constexpr int SH = H / 2, SW = W / 2;
  float syf = 0.5f * (float)gy - 0.25f;
  float sxf = 0.5f * (float)gx - 0.25f;
  syf = fminf(fmaxf(syf, 0.0f), (float)(SH - 1));
  sxf = fminf(fmaxf(sxf, 0.0f), (float)(SW - 1));
  int sy0 = (int)syf, sx0 = (int)sxf;
  float fy2 = syf - (float)sy0, fx2 = sxf - (float)sx0;
  int sy1 = min(sy0 + 1, SH - 1), sx1 = min(sx0 + 1, SW - 1);
  int j00 = sy0 * SW + sx0, j01 = sy0 * SW + sx1;
  int j10 = sy1 * SW + sx0, j11 = sy1 * SW + sx1;
  float cd = (prev_d[j00] * (1.f - fx2) + prev_d[j01] * fx2) * (1.f - fy2) +
             (prev_d[j10] * (1.f - fx2) + prev_d[j11] * fx2) * fy2;
  float cv = (prev_v[j00] * (1.f - fx2) + prev_v[j01] * fx2) * (1.f - fy2) +
             (prev_v[j10] * (1.f - fx2) + prev_v[j11] * fx2) * fy2;
  float lo = -fminf(cd, cv);
  base = cd + lo + 1e-12f;
  st = (cv - lo) / (float)(D - 1);
}

template <int D, int H, int W>
__global__ void range_kernel(const float* __restrict__ prev_d,
                             const float* __restrict__ prev_v,
                             float2* __restrict__ rng) {
  int pix = blockIdx.x * 256 + threadIdx.x;
  if (pix >= H * W) return;
  float b, s;
  stage2_range<D, H, W>(prev_d, prev_v, pix / W, pix % W, b, s);
  rng[pix] = make_float2(b, s);
}

// One thread computes one float4 (4 channels) of the variance volume at
// (d, gy, gx). feats channel-last (V,H,W,C). Branchless, no LDS, no barriers.
template <int C, int DTOT, int H, int W, bool STAGE2>
__launch_bounds__(256)
__global__ void gather_var_kernel(const float* __restrict__ feats,
                                  const float* __restrict__ mats,
                                  const float* __restrict__ dpar,
                                  const float2* __restrict__ rng,
                                  float4* __restrict__ var_out) {
  constexpr int C4 = C / 4;
  const int idx = blockIdx.x * 256 + threadIdx.x;
  if (idx >= DTOT * H * W * C4) return;
  const int cg = idx % C4;
  const int t = idx / C4;          // (d*H + gy)*W + gx
  const int gx = t % W;
  const int t2 = t / W;
  const int gy = t2 % H;
  const int d = t2 / H;
  const int pix = gy * W + gx;

  float base, st;
  if constexpr (STAGE2) {
    float2 r = rng[pix];
    base = r.x;
    st = r.y;
  } else {
    base = dpar[0];
    st = dpar[1];
  }
  const float dep = base + (float)d * st;

  const float4* fp = (const float4*)feats;
  float4 r = fp[(size_t)pix * C4 + cg];
  float s0 = r.x, s1 = r.y, s2 = r.z, s3 = r.w;
  float q0 = r.x * r.x, q1 = r.y * r.y, q2 = r.z * r.z, q3 = r.w * r.w;

#pragma unroll
  for (int v = 0; v < 2; ++v) {
    const float* M = mats + v * 12;
    float fx = (float)gx, fy = (float)gy;
    float X = (M[0] * fx + M[1] * fy + M[2]) * dep + M[9];
    float Y = (M[3] * fx + M[4] * fy + M[5]) * dep + M[10];
    float Z = (M[6] * fx + M[7] * fy + M[8]) * dep + M[11];
    float inv = 1.0f / Z;
    float xz = X * inv, yz = Y * inv;
    float gxn = xz * (2.0f / (float)(W - 1)) - 1.0f;
    float gyn = yz * (2.0f / (float)(H - 1)) - 1.0f;
    float ix = ((gxn + 1.0f) * (float)W - 1.0f) * 0.5f;
    float iy = ((gyn + 1.0f) * (float)H - 1.0f) * 0.5f;
    float x0f = floorf(ix), y0f = floorf(iy);
    float wx = ix - x0f, wy = iy - y0f;
    float x1f = x0f + 1.0f, y1f = y0f + 1.0f;
    bool vx0 = (x0f >= 0.0f) && (x0f <= (float)(W - 1));
    bool vx1 = (x1f >= 0.0f) && (x1f <= (float)(W - 1));
    bool vy0 = (y0f >= 0.0f) && (y0f <= (float)(H - 1));
    bool vy1 = (y1f >= 0.0f) && (y1f <= (float)(H - 1));
    int xc0 = (int)fminf(fmaxf(x0f, 0.0f), (float)(W - 1));
    int xc1 = (int)fminf(fmaxf(x1f, 0.0f), (float)(W - 1));
    int yc0 = (int)fminf(fmaxf(y0f, 0.0f), (float)(H - 1));
    int yc1 = (int)fminf(fmaxf(y1f, 0.0f), (float)(H - 1));
    float wxm = 1.0f - wx, wym = 1.0f - wy;
    float a00 = (vx0 && vy0) ? wxm * wym : 0.0f;
    float a10 = (vx1 && vy0) ? wx * wym : 0.0f;
    float a01 = (vx0 && vy1) ? wxm * wy : 0.0f;
    float a11 = (vx1 && vy1) ? wx * wy : 0.0f;
    const float4* fv = fp + (size_t)(v + 1) * H * W * C4 + cg;
    float4 p00 = fv[(size_t)(yc0 * W + xc0) * C4];
    float4 p10 = fv[(size_t)(yc0 * W + xc1) * C4];
    float4 p01 = fv[(size_t)(yc1 * W + xc0) * C4];
    float4 p11 = fv[(size_t)(yc1 * W + xc1) * C4];
    float g0 = a00 * p00.x + a10 * p10.x + a01 * p01.x + a11 * p11.x;
    float g1 = a00 * p00.y + a10 * p10.y + a01 * p01.y + a11 * p11.y;
    float g2 = a00 * p00.z + a10 * p10.z + a01 * p01.z + a11 * p11.z;
    float g3 = a00 * p00.w + a10 * p10.w + a01 * p01.w + a11 * p11.w;
    s0 += g0; q0 += g0 * g0;
    s1 += g1; q1 += g1 * g1;
    s2 += g2; q2 += g2 * g2;
    s3 += g3; q3 += g3 * g3;
  }
  float m;
  float4 o;
  m = s0 / 3.0f; o.x = q0 / 3.0f - m * m;
  m = s1 / 3.0f; o.y = q1 / 3.0f - m * m;
  m = s2 / 3.0f; o.z = q2 / 3.0f - m * m;
  m = s3 / 3.0f; o.w = q3 / 3.0f - m * m;
  var_out[idx] = o;
}

// 3x3x3 conv over the variance volume -> cost volume [d][pix].
// 8x8 tile, DC owned cost slices (blockIdx.z). Var slices staged to LDS in
// [px][C/4+1 float4] layout (b128 reads, group-rotated banks); weights from
// w2[tap][kd][c] via batched uniform float4 loads (6/tap); staging addresses
// hoisted out of the interval loop; 1 barrier/slice.
template <int C, int DTOT, int DC, int H, int W>
__launch_bounds__(256)
__global__ void conv_cost_kernel(const float4* __restrict__ var_in,
                                 const float4* __restrict__ w2,  // [t][kd][c4]
                                 const float* __restrict__ bconv,
                                 float* __restrict__ g_cost) {
  constexpr int TH = 8, TW = 8, HB = 10, WB = 10, HALO = 100, NPX = 64;
  constexpr int C4 = C / 4;       // float4s per kd row
  constexpr int Q = C / 16;       // float4s per wave-group per position
  constexpr int SROW4 = C4 + 1;   // float4 stride per px
  constexpr int NS = DC + 2;
  constexpr int PFN = (HALO * C4 + 255) / 256;
  constexpr int SL = H * W * C4;  // float4s per var slice

  __shared__ float4 s_in[2][HALO * SROW4];
  __shared__ float s_cost[DC * NPX];

  const int tid = threadIdx.x;
  const int h0 = blockIdx.y * TH;
  const int w0 = blockIdx.x * TW;
  const int d0 = blockIdx.z * DC;

  {
    float bias = bconv[0];
    for (int i = tid; i < DC * NPX; i += 256) s_cost[i] = bias;
  }

  // hoisted staging addresses (constant across intervals)
  int gbase[PFN];
  int ldsoff[PFN];
  bool act[PFN], gval[PFN];
#pragma unroll
  for (int k = 0; k < PFN; ++k) {
    int i = tid + k * 256;
    act[k] = (i < HALO * C4);
    int px = i / C4, cg = i - (i / C4) * C4;
    int hy = px / WB, hx = px - hy * WB;
    int gy = h0 + hy - 1, gx = w0 + hx - 1;
    gval[k] = act[k] && gy >= 0 && gy < H && gx >= 0 && gx < W;
    gbase[k] = gval[k] ? ((gy * W + gx) * C4 + cg) : 0;
    ldsoff[k] = px * SROW4 + cg;
  }

  float4 pf[PFN];
  auto prefetch = [&](int ds) {
    const bool dv = (ds >= 0) && (ds < DTOT);
    const size_t so = (size_t)max(ds, 0) * SL;
#pragma unroll
    for (int k = 0; k < PFN; ++k) {
      float4 r = make_float4(0.f, 0.f, 0.f, 0.f);
      if (dv && gval[k]) r = var_in[so + gbase[k]];
      pf[k] = r;
    }
  };
  auto commit = [&](int b) {
#pragma unroll
    for (int k = 0; k < PFN; ++k)
      if (act[k]) s_in[b][ldsoff[k]] = pf[k];
  };

  const int grp = tid >> 6;   // wave id
  const int opx = tid & 63;
  const int py = opx >> 3, pxx = opx & 7;
  const int gq = __builtin_amdgcn_readfirstlane(grp * Q);  // uniform -> s_load

  auto conv_accum = [&](int ds, int sb) {
    float a0 = 0.f, a1 = 0.f, a2 = 0.f;  // kd = 0,1,2
#pragma unroll
    for (int t = 0; t < 9; ++t) {
      const int kh = t / 3, kw = t - 3 * kh;
      const int hp = (py + kh) * WB + (pxx + kw);
      float4 v[Q];
      const float4* vp = &s_in[sb][hp * SROW4 + gq];
#pragma unroll
      for (int q = 0; q < Q; ++q) v[q] = vp[q];
#pragma unroll
      for (int kd = 0; kd < 3; ++kd) {
        float acc = 0.f;
#pragma unroll
        for (int q = 0; q < Q; ++q) {
          float4 wv = w2[(t * 3 + kd) * C4 + gq + q];  // uniform address
          acc += v[q].x * wv.x + v[q].y * wv.y + v[q].z * wv.z + v[q].w * wv.w;
        }
        if (kd == 0) a0 += acc;
        else if (kd == 1) a1 += acc;
        else a2 += acc;
      }
    }
    int t0 = ds + 1 - d0;  // kd=0 feeds cost slice ds+1
    int t1 = ds - d0;      // kd=1
    int t2 = ds - 1 - d0;  // kd=2
    if (t0 >= 0 && t0 < DC) atomicAdd(&s_cost[t0 * NPX + opx], a0);
    if (t1 >= 0 && t1 < DC) atomicAdd(&s_cost[t1 * NPX + opx], a1);
    if (t2 >= 0 && t2 < DC) atomicAdd(&s_cost[t2 * NPX + opx], a2);
  };

  prefetch(d0 - 1);
  commit(0);
  __syncthreads();
  for (int s = 1; s <= NS; ++s) {
    if (s < NS) prefetch(d0 - 1 + s);           // global loads in flight...
    conv_accum(d0 - 1 + (s - 1), (s - 1) & 1);  // ...hidden under conv
    if (s < NS) commit(s & 1);
    __syncthreads();
  }

  for (int i = tid; i < DC * NPX; i += 256) {
    int dd = i / NPX, o = i - dd * NPX;
    int oy = o / TW, ox = o - oy * TW;
    g_cost[(size_t)(d0 + dd) * (H * W) + (h0 + oy) * W + (w0 + ox)] = s_cost[i];
  }
}

template <int D, int H, int W, bool STAGE2>
__global__ void epilogue_kernel(const float* __restrict__ g_cost,
                                const float* __restrict__ dpar,
                                const float2* __restrict__ rng,
                                float* __restrict__ out_d,
                                float* __restrict__ out_c,
                                float* __restrict__ out_v) {
  int pix = blockIdx.x * 256 + threadIdx.x;
  if (pix >= H * W) return;
  float base, st;
  if constexpr (STAGE2) {
    float2 r = rng[pix];
    base = r.x;
    st = r.y;
  } else {
    base = dpar[0];
    st = dpar[1];
  }
  float c[D];
#pragma unroll
  for (int dd = 0; dd < D; ++dd) c[dd] = g_cost[(size_t)dd * (H * W) + pix];
  float mx = -3.0e38f;
#pragma unroll
  for (int dd = 0; dd < D; ++dd) mx = fmaxf(mx, c[dd]);
  float se = 0.f;
#pragma unroll
  for (int dd = 0; dd < D; ++dd) {
    float e = expf(c[dd] - mx);
    c[dd] = e;
    se += e;
  }
  float depth = 0.f, dif = 0.f;
#pragma unroll
  for (int dd = 0; dd < D; ++dd) {
    float p = c[dd] / se;
    c[dd] = p;
    depth += p * (base + (float)dd * st);
    dif += p * (float)dd;
  }
  int di = (int)dif;
  di = min(max(di, 0), D - 1);
  float conf = 0.f;
#pragma unroll
  for (int dd = 0; dd < D; ++dd)
    if (dd >= di - 1 && dd <= di + 2) conf += c[dd];
  float ev = 0.f;
#pragma unroll
  for (int dd = 0; dd < D; ++dd) {
    float sv = base + (float)dd * st - depth;
    ev += sv * sv * c[dd];
  }
  ev = 1.5f * sqrtf(ev);
  out_d[pix] = depth;
  out_c[pix] = conf;
  out_v[pix] = ev;
}

// -------------------- fused fallback (R4, small-ws tiers) --------------------

template <int C, int DTOT, int DC, int TH, int TW, int H, int W, bool STAGE2, bool CL, bool EPI>
__launch_bounds__(256)
__global__ void cost_kernel(const float* __restrict__ feats,
                            const float* __restrict__ wconv,
                            const float* __restrict__ bconv,
                            const float* __restrict__ mats,
                            const float* __restrict__ dpar,
                            const float* __restrict__ prev_d,
                            const float* __restrict__ prev_v,
                            float* __restrict__ g_cost,
                            float* __restrict__ out_d,
                            float* __restrict__ out_c,
                            float* __restrict__ out_v) {
  constexpr int HB = TH + 2, WB = TW + 2, HALO = HB * WB, NPX = TH * TW;
  constexpr int HP = HALO + 1;
  constexpr int C4 = C / 4;
  constexpr int CG = C / 4;
  constexpr int NS = DC + 2;
  constexpr int VITEMS = CL ? (HALO * C4) : (HALO * C);

  __shared__ float s_var[2][C * HP];
  __shared__ float s_cost[DC * NPX];
  __shared__ float s_w[C * 27];
  __shared__ float s_rx[2][HALO], s_ry[2][HALO], s_rz[2][HALO];
  __shared__ float s_cw[2][2][4][HALO];
  __shared__ int s_ci[2][2][4][HALO];
  __shared__ int s_gidx[HALO];
  __shared__ float s_dbase[HALO], s_dstep[HALO];
  __shared__ unsigned char s_inb[HALO];

  const int tid = threadIdx.x;
  const int h0 = blockIdx.y * TH;
  const int w0 = blockIdx.x * TW;
  const int d0 = EPI ? 0 : blockIdx.z * DC;

  for (int i = tid; i < C * 27; i += 256) s_w[i] = wconv[i];

  for (int i = tid; i < HALO; i += 256) {
    int hy = i / WB, hx = i - hy * WB;
    int gy = h0 + hy - 1, gx = w0 + hx - 1;
    bool inb = (gy >= 0) && (gy < H) && (gx >= 0) && (gx < W);
    s_inb[i] = inb ? 1 : 0;
    s_gidx[i] = inb ? (gy * W + gx) : 0;
    float fx = (float)gx, fy = (float)gy;
#pragma unroll
    for (int v = 0; v < 2; ++v) {
      const float* M = mats + v * 12;
      s_rx[v][i] = M[0] * fx + M[1] * fy + M[2];
      s_ry[v][i] = M[3] * fx + M[4] * fy + M[5];
      s_rz[v][i] = M[6] * fx + M[7] * fy + M[8];
    }
    if constexpr (STAGE2) {
      float b, stp;
      stage2_range<DTOT, H, W>(prev_d, prev_v, gy, gx, b, stp);
      s_dbase[i] = b;
      s_dstep[i] = stp;
    } else {
      s_dbase[i] = dpar[0];
      s_dstep[i] = dpar[1];
    }
  }
  {
    float bias = bconv[0];
    for (int i = tid; i < DC * NPX; i += 256) s_cost[i] = bias;
  }
  __syncthreads();

  auto do_coords = [&](int ds, int b, int i) {
    int v = (i >= HALO) ? 1 : 0;
    int px = i - v * HALO;
    float dep = s_dbase[px] + (float)ds * s_dstep[px];
    const float* M = mats + v * 12;
    float X = s_rx[v][px] * dep + M[9];
    float Y = s_ry[v][px] * dep + M[10];
    float Z = s_rz[v][px] * dep + M[11];
    float inv = 1.0f / Z;
    float xz = X * inv, yz = Y * inv;
    float gxn = xz * (2.0f / (float)(W - 1)) - 1.0f;
    float gyn = yz * (2.0f / (float)(H - 1)) - 1.0f;
    float ix = ((gxn + 1.0f) * (float)W - 1.0f) * 0.5f;
    float iy = ((gyn + 1.0f) * (float)H - 1.0f) * 0.5f;
    float x0f = floorf(ix), y0f = floorf(iy);
    float wx = ix - x0f, wy = iy - y0f;
    float x1f = x0f + 1.0f, y1f = y0f + 1.0f;
    bool vx0 = (x0f >= 0.0f) && (x0f <= (float)(W - 1));
    bool vx1 = (x1f >= 0.0f) && (x1f <= (float)(W - 1));
    bool vy0 = (y0f >= 0.0f) && (y0f <= (float)(H - 1));
    bool vy1 = (y1f >= 0.0f) && (y1f <= (float)(H - 1));
    int xc0 = (int)fminf(fmaxf(x0f, 0.0f), (float)(W - 1));
    int xc1 = (int)fminf(fmaxf(x1f, 0.0f), (float)(W - 1));
    int yc0 = (int)fminf(fmaxf(y0f, 0.0f), (float)(H - 1));
    int yc1 = (int)fminf(fmaxf(y1f, 0.0f), (float)(H - 1));
    s_ci[b][v][0][px] = yc0 * W + xc0;
    s_ci[b][v][1][px] = yc0 * W + xc1;
    s_ci[b][v][2][px] = yc1 * W + xc0;
    s_ci[b][v][3][px] = yc1 * W + xc1;
    float wxm = 1.0f - wx, wym = 1.0f - wy;
    s_cw[b][v][0][px] = (vx0 && vy0) ? wxm * wym : 0.0f;
    s_cw[b][v][1][px] = (vx1 && vy0) ? wx * wym : 0.0f;
    s_cw[b][v][2][px] = (vx0 && vy1) ? wxm * wy : 0.0f;
    s_cw[b][v][3][px] = (vx1 && vy1) ? wx * wy : 0.0f;
  };

  auto do_variance = [&](int b, int b2, int i) {
    if constexpr (CL) {
      int px = i / C4, cg = i - (i / C4) * C4;
      float o0 = 0.f, o1 = 0.f, o2 = 0.f, o3 = 0.f;
      if (s_inb[px]) {
        const float4* fp = (const float4*)feats;
        float4 r = fp[(size_t)s_gidx[px] * C4 + cg];
        float s0 = r.x, s1 = r.y, s2 = r.z, s3 = r.w;
        float q0 = r.x * r.x, q1 = r.y * r.y, q2 = r.z * r.z, q3 = r.w * r.w;
#pragma unroll
        for (int v = 0; v < 2; ++v) {
          const float4* fv = fp + (size_t)(v + 1) * H * W * C4 + cg;
          float a00 = s_cw[b][v][0][px], a10 = s_cw[b][v][1][px];
          float a01 = s_cw[b][v][2][px], a11 = s_cw[b][v][3][px];
          float4 p00 = fv[(size_t)s_ci[b][v][0][px] * C4];
          float4 p10 = fv[(size_t)s_ci[b][v][1][px] * C4];
          float4 p01 = fv[(size_t)s_ci[b][v][2][px] * C4];
          float4 p11 = fv[(size_t)s_ci[b][v][3][px] * C4];
          float g0 = a00 * p00.x + a10 * p10.x + a01 * p01.x + a11 * p11.x;
          float g1 = a00 * p00.y + a10 * p10.y + a01 * p01.y + a11 * p11.y;
          float g2 = a00 * p00.z + a10 * p10.z + a01 * p01.z + a11 * p11.z;
          float g3 = a00 * p00.w + a10 * p10.w + a01 * p01.w + a11 * p11.w;
          s0 += g0; q0 += g0 * g0;
          s1 += g1; q1 += g1 * g1;
          s2 += g2; q2 += g2 * g2;
          s3 += g3; q3 += g3 * g3;
        }
        float m;
        m = s0 / 3.0f; o0 = q0 / 3.0f - m * m;
        m = s1 / 3.0f; o1 = q1 / 3.0f - m * m;
        m = s2 / 3.0f; o2 = q2 / 3.0f - m * m;
        m = s3 / 3.0f; o3 = q3 / 3.0f - m * m;
      }
      int cb = cg * 4;
      s_var[b2][(cb + 0) * HP + px] = o0;
      s_var[b2][(cb + 1) * HP + px] = o1;
      s_var[b2][(cb + 2) * HP + px] = o2;
      s_var[b2][(cb + 3) * HP + px] = o3;
    } else {
      int c = i / HALO, px = i - (i / HALO) * HALO;
      float var = 0.f;
      if (s_inb[px]) {
        const float* f0 = feats + (size_t)c * (H * W);
        float rr = f0[s_gidx[px]];
        float sum = rr, ssq = rr * rr;
#pragma unroll
        for (int v = 0; v < 2; ++v) {
          const float* fv = feats + ((size_t)(v + 1) * C + c) * (H * W);
          float val = s_cw[b][v][0][px] * fv[s_ci[b][v][0][px]] +
                      s_cw[b][v][1][px] * fv[s_ci[b][v][1][px]] +
                      s_cw[b][v][2][px] * fv[s_ci[b][v][2][px]] +
                      s_cw[b][v][3][px] * fv[s_ci[b][v][3][px]];
          sum += val;
          ssq += val * val;
        }
        float m = sum / 3.0f;
        var = ssq / 3.0f - m * m;
      }
      s_var[b2][c * HP + px] = var;
    }
  };

  auto conv_accum = [&](int ds, int sb) {
    for (int i = tid; i < NPX * 4; i += 256) {
      int grp = i / NPX, opx = i - grp * NPX;
      int py = opx / TW, pxx = opx - py * TW;
      float a0 = 0.f, a1 = 0.f, a2 = 0.f;
      int cbase = grp * CG;
#pragma unroll
      for (int kh = 0; kh < 3; ++kh) {
#pragma unroll
        for (int kw = 0; kw < 3; ++kw) {
          int hp = (py + kh) * WB + (pxx + kw);
#pragma unroll
          for (int cc = 0; cc < CG; ++cc) {
            int c = cbase + cc;
            float vv = s_var[sb][c * HP + hp];
            const float* wp = s_w + c * 27 + kh * 3 + kw;
            a0 += vv * wp[0];
            a1 += vv * wp[9];
            a2 += vv * wp[18];
          }
        }
      }
      int t0 = ds + 1 - d0;
      int t1 = ds - d0;
      int t2 = ds - 1 - d0;
      if (t0 >= 0 && t0 < DC) atomicAdd(&s_cost[t0 * NPX + opx], a0);
      if (t1 >= 0 && t1 < DC) atomicAdd(&s_cost[t1 * NPX + opx], a1);
      if (t2 >= 0 && t2 < DC) atomicAdd(&s_cost[t2 * NPX + opx], a2);
    }
  };

  {
    int ds0 = d0 - 1;
    if (ds0 >= 0 && ds0 < DTOT)
      for (int i = tid; i < 2 * HALO; i += 256) do_coords(ds0, 0, i);
  }
  __syncthreads();

  for (int s = 0; s <= NS; ++s) {
    const int ds = d0 - 1 + s;
    const bool val_cur = (s < NS) && (ds >= 0) && (ds < DTOT);
    const bool val_next = (s + 1 < NS) && (ds + 1 >= 0) && (ds + 1 < DTOT);
    const bool val_prev = (s >= 1) && (ds - 1 >= 0) && (ds - 1 < DTOT);
    if (val_cur)
      for (int i = tid; i < VITEMS; i += 256) do_variance(s & 1, s & 1, i);
    if (val_next)
      for (int i = tid; i < 2 * HALO; i += 256) do_coords(ds + 1, (s + 1) & 1, i);
    if (val_prev) conv_accum(ds - 1, (s - 1) & 1);
    __syncthreads();
  }

  if constexpr (!EPI) {
    for (int i = tid; i < DC * NPX; i += 256) {
      int dd = i / NPX, opx = i - dd * NPX;
      int py = opx / TW, pxx = opx - py * TW;
      g_cost[(size_t)(d0 + dd) * (H * W) + (h0 + py) * W + (w0 + pxx)] = s_cost[i];
    }
  } else if (tid < NPX) {
    const int opx = tid;
    const int py = opx / TW, pxx = opx - py * TW;
    const int hp = (py + 1) * WB + (pxx + 1);
    const float base = s_dbase[hp], st = s_dstep[hp];
    float mx = -3.0e38f;
    for (int dd = 0; dd < DTOT; ++dd) mx = fmaxf(mx, s_cost[dd * NPX + opx]);
    float se = 0.f;
    for (int dd = 0; dd < DTOT; ++dd) {
      float e = expf(s_cost[dd * NPX + opx] - mx);
      s_cost[dd * NPX + opx] = e;
      se += e;
    }
    float depth = 0.f, dif = 0.f;
    for (int dd = 0; dd < DTOT; ++dd) {
      float p = s_cost[dd * NPX + opx] / se;
      s_cost[dd * NPX + opx] = p;
      depth += p * (base + (float)dd * st);
      dif += p * (float)dd;
    }
    int di = (int)dif;
    di = min(max(di, 0), DTOT - 1);
    float conf = 0.f;
    for (int k = di - 1; k <= di + 2; ++k)
      if (k >= 0 && k < DTOT) conf += s_cost[k * NPX + opx];
    float ev = 0.f;
    for (int dd = 0; dd < DTOT; ++dd) {
      float sv = base + (float)dd * st - depth;
      ev += sv * sv * s_cost[dd * NPX + opx];
    }
    ev = 1.5f * sqrtf(ev);
    int gy = h0 + py, gx = w0 + pxx;
    out_d[gy * W + gx] = depth;
    out_c[gy * W + gx] = conf;
    out_v[gy * W + gx] = ev;
  }
}

extern "C" void kernel_launch(void* const* d_in, const int* in_sizes, int n_in,
                              void* d_out, int out_size, void* d_ws, size_t ws_size,
                              hipStream_t stream) {
  const float* feats1 = (const float*)d_in[0];
  const float* feats2 = (const float*)d_in[1];
  const float* proj1 = (const float*)d_in[2];
  const float* proj2 = (const float*)d_in[3];
  const float* depthv = (const float*)d_in[4];
  const float* w1 = (const float*)d_in[6];
  const float* b1 = (const float*)d_in[7];
  const float* w2 = (const float*)d_in[8];
  const float* b2 = (const float*)d_in[9];
  float* out = (float*)d_out;
  float* ws = (float*)d_ws;

  const int nd = in_sizes[4];
  const size_t F1 = (size_t)3 * 32 * 128 * 160;     // 1,966,080
  const size_t F2 = (size_t)3 * 16 * 256 * 320;     // 3,932,160
  const size_t COST1 = (size_t)48 * 128 * 160;      // 983,040
  const size_t COST2 = (size_t)8 * 256 * 320;       // 655,360
  const size_t VAR1 = (size_t)48 * 128 * 160 * 32;  // 31,457,280
  const size_t VAR2 = (size_t)8 * 256 * 320 * 16;   // 10,485,760
  const size_t RNG2 = (size_t)2 * 256 * 320;        // float2 per px
  const size_t HDR = 1408;                           // mats+dpar+w2a+w2b
  const size_t HUGE_FLOATS = HDR + COST1 + COST2 + F1 + F2 + VAR1 + VAR2 + RNG2;
  const bool huge = ws_size >= HUGE_FLOATS * sizeof(float);
  const bool big = ws_size >= (64 + COST1 + F1 + F2) * sizeof(float);
  const bool mid = ws_size >= (64 + COST1) * sizeof(float);

  setup_mats_kernel<<<1, 64, 0, stream>>>(proj1, proj2, depthv, nd, ws);

  float* d1 = out;
  float* c1 = out + 20480;
  float* v1 = out + 40960;
  float* d2 = out + 61440;
  float* c2 = out + 143360;
  float* v2 = out + 225280;

  dim3 g1c(160 / 8, 128 / 8, 6), g1f(160 / 8, 128 / 8, 1), g2(320 / 8, 256 / 8, 1);

  if (huge) {
    float* w2a = ws + 64;          // 864 floats (stage-1 relayout)
    float* w2b = ws + 960;         // 432 floats (stage-2 relayout)
    float* cost1 = ws + HDR;
    float* cost2 = cost1 + COST1;
    float* f1t = cost2 + COST2;
    float* f2t = f1t + F1;
    float* var1 = f2t + F2;
    float* var2 = var1 + VAR1;
    float2* rng2 = (float2*)(var2 + VAR2);
    relayout_w_kernel<<<4, 256, 0, stream>>>(w1, w2a, 32);
    relayout_w_kernel<<<2, 256, 0, stream>>>(w2, w2b, 16);
    transpose_cl_kernel<<<(int)((F1 + 255) / 256), 256, 0, stream>>>(feats1, f1t, 32, 128, 160);
    transpose_cl_kernel<<<(int)((F2 + 255) / 256), 256, 0, stream>>>(feats2, f2t, 16, 256, 320);
    // stage 1
    gather_var_kernel<32, 48, 128, 160, false><<<(int)(VAR1 / 4 / 256), 256, 0, stream>>>(
        f1t, ws, ws + 48, nullptr, (float4*)var1);
    conv_cost_kernel<32, 48, 8, 128, 160><<<g1c, 256, 0, stream>>>(
        (const float4*)var1, (const float4*)w2a, b1, cost1);
    epilogue_kernel<48, 128, 160, false><<<80, 256, 0, stream>>>(
        cost1, ws + 48, nullptr, d1, c1, v1);
    // stage 2
    range_kernel<8, 256, 320><<<320, 256, 0, stream>>>(d1, v1, rng2);
    gather_var_kernel<16, 8, 256, 320, true><<<(int)(VAR2 / 4 / 256), 256, 0, stream>>>(
        f2t, ws + 24, ws + 48, rng2, (float4*)var2);
    conv_cost_kernel<16, 8, 8, 256, 320><<<dim3(40, 32, 1), 256, 0, stream>>>(
        (const float4*)var2, (const float4*)w2b, b2, cost2);
    epilogue_kernel<8, 256, 320, true><<<320, 256, 0, stream>>>(
        cost2, ws + 48, rng2, d2, c2, v2);
  } else if (big) {
    float* cost1 = ws + 64;
    float* f1t = ws + 64 + COST1;
    float* f2t = f1t + F1;
    transpose_cl_kernel<<<(int)((F1 + 255) / 256), 256, 0, stream>>>(feats1, f1t, 32, 128, 160);
    transpose_cl_kernel<<<(int)((F2 + 255) / 256), 256, 0, stream>>>(feats2, f2t, 16, 256, 320);
    cost_kernel<32, 48, 8, 8, 8, 128, 160, false, true, false><<<g1c, 256, 0, stream>>>(
        f1t, w1, b1, ws, ws + 48, nullptr, nullptr, cost1, nullptr, nullptr, nullptr);
    epilogue_kernel<48, 128, 160, false><<<80, 256, 0, stream>>>(
        cost1, ws + 48, nullptr, d1, c1, v1);
    cost_kernel<16, 8, 8, 8, 8, 256, 320, true, true, true><<<g2, 256, 0, stream>>>(
        f2t, w2, b2, ws + 24, ws + 48, d1, v1, nullptr, d2, c2, v2);
  } else if (mid) {
    float* cost1 = ws + 64;
    cost_kernel<32, 48, 8, 8, 8, 128, 160, false, false, false><<<g1c, 256, 0, stream>>>(
        feats1, w1, b1, ws, ws + 48, nullptr, nullptr, cost1, nullptr, nullptr, nullptr);
    epilogue_kernel<48, 128, 160, false><<<80, 256, 0, stream>>>(
        cost1, ws + 48, nullptr, d1, c1, v1);
    cost_kernel<16, 8, 8, 8, 8, 256, 320, true, false, true><<<g2, 256, 0, stream>>>(
        feats2, w2, b2, ws + 24, ws + 48, d1, v1, nullptr, d2, c2, v2);
  } else {
    cost_kernel<32, 48, 48, 8, 8, 128, 160, false, false, true><<<g1f, 256, 0, stream>>>(
        feats1, w1, b1, ws, ws + 48, nullptr, nullptr, nullptr, d1, c1, v1);
    cost_kernel<16, 8, 8, 8, 8, 256, 320, true, false, true><<<g2, 256, 0, stream>>>(
        feats2, w2, b2, ws + 24, ws + 48, d1, v1, nullptr, d2, c2, v2);
  }
}

// Round 8
// 310.535 us; speedup vs baseline: 4.6929x; 1.1801x over previous
//
#include <hip/hip_runtime.h>
#include <math.h>

// ---------------------------------------------------------------------------
// CoarseMVSNet, de-fused fp16 pipeline (R8):
//   transpose_f16_kernel : feats (V,C,H,W) fp32 -> (V,H,W,C) fp16
//   gather_var_kernel    : 1 thread = 8 channels of var volume (fp16 in/out,
//                          fp32 math). No LDS, no barriers.
//   relayout_w_f16_kernel: w[c][kd][kh][kw] -> w2h[tap][kd][c] fp16
//   conv_cost_kernel     : 3x3x3 conv, fp16 var via 1 ds_read_b128 per
//                          tap/group, v_dot2_f32_f16 inner product, batched
//                          uniform weight loads, register-prefetch staging.
//   range/epilogue       : fp32 softmax head.
// R7 post-mortem: conv was ~1 TB/s var-volume stream + VALU ~46% — fp16
// halves fetch, LDS, and FMA count simultaneously.
// __launch_bounds__(256) ONLY (R2: (256,4) forced VGPR->64, 4.2 GB spill).
// ---------------------------------------------------------------------------

typedef _Float16 half2_t __attribute__((ext_vector_type(2)));
typedef _Float16 half8_t __attribute__((ext_vector_type(8)));

union U4H { uint4 u; half2_t h[4]; };
union U2H { uint2 u; half2_t h[2]; };

static __device__ inline float fdot2f(half2_t a, half2_t b, float c) {
#if __has_builtin(__builtin_amdgcn_fdot2)
  return __builtin_amdgcn_fdot2(a, b, c, false);
#else
  return c + (float)a[0] * (float)b[0] + (float)a[1] * (float)b[1];
#endif
}

__global__ void setup_mats_kernel(const float* __restrict__ proj1,
                                  const float* __restrict__ proj2,
                                  const float* __restrict__ depthv, int nd,
                                  float* __restrict__ ws) {
  if (threadIdx.x != 0 || blockIdx.x != 0) return;
  for (int s = 0; s < 2; ++s) {
    const float* P = s ? proj2 : proj1;  // (3,2,4,4) flat
    double comp[3][4][4];
    for (int v = 0; v < 3; ++v) {
      const float* E = P + v * 32;       // [v][0]
      const float* K = P + v * 32 + 16;  // [v][1]
      for (int r = 0; r < 3; ++r)
        for (int c = 0; c < 4; ++c) {
          double acc = 0.0;
          for (int k = 0; k < 3; ++k) acc += (double)K[r * 4 + k] * (double)E[k * 4 + c];
          comp[v][r][c] = acc;
        }
      for (int c = 0; c < 4; ++c) comp[v][3][c] = (double)E[12 + c];
    }
    double a[4][8];
    for (int r = 0; r < 4; ++r)
      for (int c = 0; c < 4; ++c) {
        a[r][c] = comp[0][r][c];
        a[r][4 + c] = (r == c) ? 1.0 : 0.0;
      }
    for (int col = 0; col < 4; ++col) {
      int piv = col;
      double best = fabs(a[col][col]);
      for (int r = col + 1; r < 4; ++r) {
        double t = fabs(a[r][col]);
        if (t > best) { best = t; piv = r; }
      }
      if (piv != col)
        for (int c = 0; c < 8; ++c) { double t = a[col][c]; a[col][c] = a[piv][c]; a[piv][c] = t; }
      double dv = a[col][col];
      for (int c = 0; c < 8; ++c) a[col][c] /= dv;
      for (int r = 0; r < 4; ++r)
        if (r != col) {
          double f = a[r][col];
          if (f != 0.0)
            for (int c = 0; c < 8; ++c) a[r][c] -= f * a[col][c];
        }
    }
    for (int v = 1; v < 3; ++v) {
      double Pm[3][4];
      for (int r = 0; r < 3; ++r)
        for (int c = 0; c < 4; ++c) {
          double acc = 0.0;
          for (int k = 0; k < 4; ++k) acc += comp[v][r][k] * a[k][4 + c];
          Pm[r][c] = acc;
        }
      float* o = ws + s * 24 + (v - 1) * 12;
      o[0] = (float)Pm[0][0]; o[1] = (float)Pm[0][1]; o[2] = (float)Pm[0][2];
      o[3] = (float)Pm[1][0]; o[4] = (float)Pm[1][1]; o[5] = (float)Pm[1][2];
      o[6] = (float)Pm[2][0]; o[7] = (float)Pm[2][1]; o[8] = (float)Pm[2][2];
      o[9] = (float)Pm[0][3]; o[10] = (float)Pm[1][3]; o[11] = (float)Pm[2][3];
    }
  }
  ws[48] = depthv[0];
  ws[49] = (depthv[nd - 1] - depthv[0]) / 47.0f;  // (dmax-dmin)/(ND1-1)
}

// fp32 (V,C,H,W) -> fp16 (V,H,W,C)
__global__ void transpose_f16_kernel(const float* __restrict__ in,
                                     _Float16* __restrict__ out,
                                     int C, int H, int W) {
  int total = 3 * C * H * W;
  int idx = blockIdx.x * 256 + threadIdx.x;
  if (idx >= total) return;
  int c = idx % C;
  int t = idx / C;
  int w = t % W;
  int t2 = t / W;
  int h = t2 % H;
  int v = t2 / H;
  out[idx] = (_Float16)in[((size_t)(v * C + c) * H + h) * W + w];
}

// w[c][kd][kh][kw] -> w2h[(kh*3+kw)*3+kd][c] fp16
__global__ void relayout_w_f16_kernel(const float* __restrict__ w,
                                      _Float16* __restrict__ w2h, int C) {
  int i = blockIdx.x * 256 + threadIdx.x;
  if (i >= 27 * C) return;
  int c = i % C;
  int r = i / C;
  int kd = r % 3;
  int t = r / 3;  // kh*3+kw
  w2h[(t * 3 + kd) * C + c] = (_Float16)w[c * 27 + kd * 9 + t];
}

// Per-pixel depth range for STAGE2: bilinear 2x upsample of d1/v1.
template <int D, int H, int W>
__device__ inline void stage2_range(const float* __restrict__ prev_d,
                                    const float* __restrict__ prev_v,
                                    int gy, int gx, float& base, float& st) {
  constexpr int SH = H / 2, SW = W / 2;
  float syf = 0.5f * (float)gy - 0.25f;
  float sxf = 0.5f * (float)gx - 0.25f;
  syf = fminf(fmaxf(syf, 0.0f), (float)(SH - 1));
  sxf = fminf(fmaxf(sxf, 0.0f), (float)(SW - 1));
  int sy0 = (int)syf, sx0 = (int)sxf;
  float fy2 = syf - (float)sy0, fx2 = sxf - (float)sx0;
  int sy1 = min(sy0 + 1, SH - 1), sx1 = min(sx0 + 1, SW - 1);
  int j00 = sy0 * SW + sx0, j01 = sy0 * SW + sx1;
  int j10 = sy1 * SW + sx0, j11 = sy1 * SW + sx1;
  float cd = (prev_d[j00] * (1.f - fx2) + prev_d[j01] * fx2) * (1.f - fy2) +
             (prev_d[j10] * (1.f - fx2) + prev_d[j11] * fx2) * fy2;
  float cv = (prev_v[j00] * (1.f - fx2) + prev_v[j01] * fx2) * (1.f - fy2) +
             (prev_v[j10] * (1.f - fx2) + prev_v[j11] * fx2) * fy2;
  float lo = -fminf(cd, cv);
  base = cd + lo + 1e-12f;
  st = (cv - lo) / (float)(D - 1);
}

template <int D, int H, int W>
__global__ void range_kernel(const float* __restrict__ prev_d,
                             const float* __restrict__ prev_v,
                             float2* __restrict__ rng) {
  int pix = blockIdx.x * 256 + threadIdx.x;
  if (pix >= H * W) return;
  float b, s;
  stage2_range<D, H, W>(prev_d, prev_v, pix / W, pix % W, b, s);
  rng[pix] = make_float2(b, s);
}

// One thread computes 8 channels of the variance volume at (d, gy, gx).
// feats fp16 channel-last (V,H,W,C); var_out fp16 [d][pix][C]. fp32 math.
template <int C, int DTOT, int H, int W, bool STAGE2>
__launch_bounds__(256)
__global__ void gather_var_kernel(const _Float16* __restrict__ feats,
                                  const float* __restrict__ mats,
                                  const float* __restrict__ dpar,
                                  const float2* __restrict__ rng,
                                  _Float16* __restrict__ var_out) {
  constexpr int C8 = C / 8;
  const int idx = blockIdx.x * 256 + threadIdx.x;
  if (idx >= DTOT * H * W * C8) return;
  const int cg = idx % C8;
  const int t = idx / C8;          // (d*H + gy)*W + gx
  const int gx = t % W;
  const int t2 = t / W;
  const int gy = t2 % H;
  const int d = t2 / H;
  const int pix = gy * W + gx;

  float base, st;
  if constexpr (STAGE2) {
    float2 r = rng[pix];
    base = r.x;
    st = r.y;
  } else {
    base = dpar[0];
    st = dpar[1];
  }
  const float dep = base + (float)d * st;

  const half8_t* fp = (const half8_t*)feats;
  half8_t rh = fp[(size_t)pix * C8 + cg];
  float s[8], q[8];
#pragma unroll
  for (int j = 0; j < 8; ++j) {
    float x = (float)rh[j];
    s[j] = x;
    q[j] = x * x;
  }

#pragma unroll
  for (int v = 0; v < 2; ++v) {
    const float* M = mats + v * 12;
    float fx = (float)gx, fy = (float)gy;
    float X = (M[0] * fx + M[1] * fy + M[2]) * dep + M[9];
    float Y = (M[3] * fx + M[4] * fy + M[5]) * dep + M[10];
    float Z = (M[6] * fx + M[7] * fy + M[8]) * dep + M[11];
    float inv = 1.0f / Z;
    float xz = X * inv, yz = Y * inv;
    float gxn = xz * (2.0f / (float)(W - 1)) - 1.0f;
    float gyn = yz * (2.0f / (float)(H - 1)) - 1.0f;
    float ix = ((gxn + 1.0f) * (float)W - 1.0f) * 0.5f;
    float iy = ((gyn + 1.0f) * (float)H - 1.0f) * 0.5f;
    float x0f = floorf(ix), y0f = floorf(iy);
    float wx = ix - x0f, wy = iy - y0f;
    float x1f = x0f + 1.0f, y1f = y0f + 1.0f;
    bool vx0 = (x0f >= 0.0f) && (x0f <= (float)(W - 1));
    bool vx1 = (x1f >= 0.0f) && (x1f <= (float)(W - 1));
    bool vy0 = (y0f >= 0.0f) && (y0f <= (float)(H - 1));
    bool vy1 = (y1f >= 0.0f) && (y1f <= (float)(H - 1));
    int xc0 = (int)fminf(fmaxf(x0f, 0.0f), (float)(W - 1));
    int xc1 = (int)fminf(fmaxf(x1f, 0.0f), (float)(W - 1));
    int yc0 = (int)fminf(fmaxf(y0f, 0.0f), (float)(H - 1));
    int yc1 = (int)fminf(fmaxf(y1f, 0.0f), (float)(H - 1));
    float wxm = 1.0f - wx, wym = 1.0f - wy;
    float a00 = (vx0 && vy0) ? wxm * wym : 0.0f;
    float a10 = (vx1 && vy0) ? wx * wym : 0.0f;
    float a01 = (vx0 && vy1) ? wxm * wy : 0.0f;
    float a11 = (vx1 && vy1) ? wx * wy : 0.0f;
    const size_t vb = (size_t)(v + 1) * H * W * C8 + cg;
    half8_t p00 = fp[vb + (size_t)(yc0 * W + xc0) * C8];
    half8_t p10 = fp[vb + (size_t)(yc0 * W + xc1) * C8];
    half8_t p01 = fp[vb + (size_t)(yc1 * W + xc0) * C8];
    half8_t p11 = fp[vb + (size_t)(yc1 * W + xc1) * C8];
#pragma unroll
    for (int j = 0; j < 8; ++j) {
      float g = a00 * (float)p00[j] + a10 * (float)p10[j] +
                a01 * (float)p01[j] + a11 * (float)p11[j];
      s[j] += g;
      q[j] += g * g;
    }
  }
  half8_t o;
#pragma unroll
  for (int j = 0; j < 8; ++j) {
    float m = s[j] * (1.0f / 3.0f);
    o[j] = (_Float16)(q[j] * (1.0f / 3.0f) - m * m);
  }
  *(half8_t*)(var_out + ((size_t)(d * H + gy) * W + gx) * C + cg * 8) = o;
}

// 3x3x3 conv over fp16 var volume -> fp32 cost volume [d][pix].
// 8x8 tile, DC owned cost slices (blockIdx.z). fp16 var staged to LDS
// ([px][C + pad]), one ds_read_b128 per tap/group (C=32), v_dot2_f32_f16
// inner product, batched uniform weight loads, 1 barrier/slice.
template <int C, int DTOT, int DC, int H, int W>
__launch_bounds__(256)
__global__ void conv_cost_kernel(const uint4* __restrict__ var_in,   // fp16 [d][pix][C]
                                 const _Float16* __restrict__ w2h,   // [tap][kd][C]
                                 const float* __restrict__ bconv,
                                 float* __restrict__ g_cost) {
  constexpr int TH = 8, TW = 8, HB = 10, WB = 10, HALO = 100, NPX = 64;
  constexpr int CU4 = C / 8;       // uint4 (8 fp16) per px row
  constexpr int SR4 = CU4 + 1;     // padded row stride (uint4 units)
  constexpr int NS = DC + 2;
  constexpr int NIT = HALO * CU4;  // staging items per slice
  constexpr int PFN = (NIT + 255) / 256;
  constexpr int SL = H * W * CU4;  // uint4 per var slice
  constexpr int CPG = C / 4;       // channels per wave-group

  __shared__ uint4 s_in[2][HALO * SR4];
  __shared__ float s_cost[DC * NPX];

  const int tid = threadIdx.x;
  const int h0 = blockIdx.y * TH;
  const int w0 = blockIdx.x * TW;
  const int d0 = blockIdx.z * DC;

  {
    float bias = bconv[0];
    for (int i = tid; i < DC * NPX; i += 256) s_cost[i] = bias;
  }

  // hoisted staging addresses
  int gbase[PFN], ldsoff[PFN];
  bool act[PFN], gval[PFN];
#pragma unroll
  for (int k = 0; k < PFN; ++k) {
    int i = tid + k * 256;
    act[k] = (i < NIT);
    int px = i / CU4, cg = i - (i / CU4) * CU4;
    int hy = px / WB, hx = px - hy * WB;
    int gy = h0 + hy - 1, gx = w0 + hx - 1;
    gval[k] = act[k] && gy >= 0 && gy < H && gx >= 0 && gx < W;
    gbase[k] = gval[k] ? ((gy * W + gx) * CU4 + cg) : 0;
    ldsoff[k] = px * SR4 + cg;
  }

  uint4 pf[PFN];
  auto prefetch = [&](int ds) {
    const bool dv = (ds >= 0) && (ds < DTOT);
    const size_t so = (size_t)max(ds, 0) * SL;
#pragma unroll
    for (int k = 0; k < PFN; ++k) {
      uint4 r = make_uint4(0u, 0u, 0u, 0u);
      if (dv && gval[k]) r = var_in[so + gbase[k]];
      pf[k] = r;
    }
  };
  auto commit = [&](int b) {
#pragma unroll
    for (int k = 0; k < PFN; ++k)
      if (act[k]) s_in[b][ldsoff[k]] = pf[k];
  };

  const int grp = tid >> 6;   // wave id; channels grp*CPG .. +CPG-1
  const int opx = tid & 63;
  const int py = opx >> 3, pxx = opx & 7;
  // uniform weight base -> scalar loads
  const _Float16* __restrict__ wg = w2h + __builtin_amdgcn_readfirstlane(grp * CPG);

  auto conv_accum = [&](int ds, int sb) {
    float a0 = 0.f, a1 = 0.f, a2 = 0.f;  // kd = 0,1,2
#pragma unroll
    for (int t = 0; t < 9; ++t) {
      const int kh = t / 3, kw = t - 3 * kh;
      const int hp = (py + kh) * WB + (pxx + kw);
      if constexpr (CPG == 8) {
        U4H v;
        v.u = s_in[sb][hp * SR4 + grp];
#pragma unroll
        for (int kd = 0; kd < 3; ++kd) {
          U4H w;
          w.u = *(const uint4*)(wg + (t * 3 + kd) * C);
          float acc = 0.f;
#pragma unroll
          for (int j = 0; j < 4; ++j) acc = fdot2f(v.h[j], w.h[j], acc);
          if (kd == 0) a0 += acc;
          else if (kd == 1) a1 += acc;
          else a2 += acc;
        }
      } else {  // CPG == 4
        U2H v;
        v.u = ((const uint2*)&s_in[sb][hp * SR4])[grp];
#pragma unroll
        for (int kd = 0; kd < 3; ++kd) {
          U2H w;
          w.u = *(const uint2*)(wg + (t * 3 + kd) * C);
          float acc = 0.f;
#pragma unroll
          for (int j = 0; j < 2; ++j) acc = fdot2f(v.h[j], w.h[j], acc);
          if (kd == 0) a0 += acc;
          else if (kd == 1) a1 += acc;
          else a2 += acc;
        }
      }
    }
    int t0 = ds + 1 - d0;  // kd=0 feeds cost slice ds+1
    int t1 = ds - d0;      // kd=1
    int t2 = ds - 1 - d0;  // kd=2
    if (t0 >= 0 && t0 < DC) atomicAdd(&s_cost[t0 * NPX + opx], a0);
    if (t1 >= 0 && t1 < DC) atomicAdd(&s_cost[t1 * NPX + opx], a1);
    if (t2 >= 0 && t2 < DC) atomicAdd(&s_cost[t2 * NPX + opx], a2);
  };

  prefetch(d0 - 1);
  commit(0);
  __syncthreads();
  for (int s = 1; s <= NS; ++s) {
    if (s < NS) prefetch(d0 - 1 + s);           // loads in flight...
    conv_accum(d0 - 1 + (s - 1), (s - 1) & 1);  // ...hidden under conv
    if (s < NS) commit(s & 1);
    __syncthreads();
  }

  for (int i = tid; i < DC * NPX; i += 256) {
    int dd = i / NPX, o = i - dd * NPX;
    int oy = o / TW, ox = o - oy * TW;
    g_cost[(size_t)(d0 + dd) * (H * W) + (h0 + oy) * W + (w0 + ox)] = s_cost[i];
  }
}

template <int D, int H, int W, bool STAGE2>
__global__ void epilogue_kernel(const float* __restrict__ g_cost,
                                const float* __restrict__ dpar,
                                const float2* __restrict__ rng,
                                float* __restrict__ out_d,
                                float* __restrict__ out_c,
                                float* __restrict__ out_v) {
  int pix = blockIdx.x * 256 + threadIdx.x;
  if (pix >= H * W) return;
  float base, st;
  if constexpr (STAGE2) {
    float2 r = rng[pix];
    base = r.x;
    st = r.y;
  } else {
    base = dpar[0];
    st = dpar[1];
  }
  float c[D];
#pragma unroll
  for (int dd = 0; dd < D; ++dd) c[dd] = g_cost[(size_t)dd * (H * W) + pix];
  float mx = -3.0e38f;
#pragma unroll
  for (int dd = 0; dd < D; ++dd) mx = fmaxf(mx, c[dd]);
  float se = 0.f;
#pragma unroll
  for (int dd = 0; dd < D; ++dd) {
    float e = expf(c[dd] - mx);
    c[dd] = e;
    se += e;
  }
  float depth = 0.f, dif = 0.f;
#pragma unroll
  for (int dd = 0; dd < D; ++dd) {
    float p = c[dd] / se;
    c[dd] = p;
    depth += p * (base + (float)dd * st);
    dif += p * (float)dd;
  }
  int di = (int)dif;
  di = min(max(di, 0), D - 1);
  float conf = 0.f;
#pragma unroll
  for (int dd = 0; dd < D; ++dd)
    if (dd >= di - 1 && dd <= di + 2) conf += c[dd];
  float ev = 0.f;
#pragma unroll
  for (int dd = 0; dd < D; ++dd) {
    float sv = base + (float)dd * st - depth;
    ev += sv * sv * c[dd];
  }
  ev = 1.5f * sqrtf(ev);
  out_d[pix] = depth;
  out_c[pix] = conf;
  out_v[pix] = ev;
}

// -------------------- fused fp32 fallback (small-ws tiers) --------------------

template <int C, int DTOT, int DC, int TH, int TW, int H, int W, bool STAGE2, bool EPI>
__launch_bounds__(256)
__global__ void cost_kernel(const float* __restrict__ feats,
                            const float* __restrict__ wconv,
                            const float* __restrict__ bconv,
                            const float* __restrict__ mats,
                            const float* __restrict__ dpar,
                            const float* __restrict__ prev_d,
                            const float* __restrict__ prev_v,
                            float* __restrict__ g_cost,
                            float* __restrict__ out_d,
                            float* __restrict__ out_c,
                            float* __restrict__ out_v) {
  constexpr int HB = TH + 2, WB = TW + 2, HALO = HB * WB, NPX = TH * TW;
  constexpr int HP = HALO + 1;
  constexpr int CG = C / 4;
  constexpr int NS = DC + 2;
  constexpr int VITEMS = HALO * C;

  __shared__ float s_var[2][C * HP];
  __shared__ float s_cost[DC * NPX];
  __shared__ float s_w[C * 27];
  __shared__ float s_rx[2][HALO], s_ry[2][HALO], s_rz[2][HALO];
  __shared__ float s_cw[2][2][4][HALO];
  __shared__ int s_ci[2][2][4][HALO];
  __shared__ int s_gidx[HALO];
  __shared__ float s_dbase[HALO], s_dstep[HALO];
  __shared__ unsigned char s_inb[HALO];

  const int tid = threadIdx.x;
  const int h0 = blockIdx.y * TH;
  const int w0 = blockIdx.x * TW;
  const int d0 = EPI ? 0 : blockIdx.z * DC;

  for (int i = tid; i < C * 27; i += 256) s_w[i] = wconv[i];

  for (int i = tid; i < HALO; i += 256) {
    int hy = i / WB, hx = i - hy * WB;
    int gy = h0 + hy - 1, gx = w0 + hx - 1;
    bool inb = (gy >= 0) && (gy < H) && (gx >= 0) && (gx < W);
    s_inb[i] = inb ? 1 : 0;
    s_gidx[i] = inb ? (gy * W + gx) : 0;
    float fx = (float)gx, fy = (float)gy;
#pragma unroll
    for (int v = 0; v < 2; ++v) {
      const float* M = mats + v * 12;
      s_rx[v][i] = M[0] * fx + M[1] * fy + M[2];
      s_ry[v][i] = M[3] * fx + M[4] * fy + M[5];
      s_rz[v][i] = M[6] * fx + M[7] * fy + M[8];
    }
    if constexpr (STAGE2) {
      float b, stp;
      stage2_range<DTOT, H, W>(prev_d, prev_v, gy, gx, b, stp);
      s_dbase[i] = b;
      s_dstep[i] = stp;
    } else {
      s_dbase[i] = dpar[0];
      s_dstep[i] = dpar[1];
    }
  }
  {
    float bias = bconv[0];
    for (int i = tid; i < DC * NPX; i += 256) s_cost[i] = bias;
  }
  __syncthreads();

  auto do_coords = [&](int ds, int b, int i) {
    int v = (i >= HALO) ? 1 : 0;
    int px = i - v * HALO;
    float dep = s_dbase[px] + (float)ds * s_dstep[px];
    const float* M = mats + v * 12;
    float X = s_rx[v][px] * dep + M[9];
    float Y = s_ry[v][px] * dep + M[10];
    float Z = s_rz[v][px] * dep + M[11];
    float inv = 1.0f / Z;
    float xz = X * inv, yz = Y * inv;
    float gxn = xz * (2.0f / (float)(W - 1)) - 1.0f;
    float gyn = yz * (2.0f / (float)(H - 1)) - 1.0f;
    float ix = ((gxn + 1.0f) * (float)W - 1.0f) * 0.5f;
    float iy = ((gyn + 1.0f) * (float)H - 1.0f) * 0.5f;
    float x0f = floorf(ix), y0f = floorf(iy);
    float wx = ix - x0f, wy = iy - y0f;
    float x1f = x0f + 1.0f, y1f = y0f + 1.0f;
    bool vx0 = (x0f >= 0.0f) && (x0f <= (float)(W - 1));
    bool vx1 = (x1f >= 0.0f) && (x1f <= (float)(W - 1));
    bool vy0 = (y0f >= 0.0f) && (y0f <= (float)(H - 1));
    bool vy1 = (y1f >= 0.0f) && (y1f <= (float)(H - 1));
    int xc0 = (int)fminf(fmaxf(x0f, 0.0f), (float)(W - 1));
    int xc1 = (int)fminf(fmaxf(x1f, 0.0f), (float)(W - 1));
    int yc0 = (int)fminf(fmaxf(y0f, 0.0f), (float)(H - 1));
    int yc1 = (int)fminf(fmaxf(y1f, 0.0f), (float)(H - 1));
    s_ci[b][v][0][px] = yc0 * W + xc0;
    s_ci[b][v][1][px] = yc0 * W + xc1;
    s_ci[b][v][2][px] = yc1 * W + xc0;
    s_ci[b][v][3][px] = yc1 * W + xc1;
    float wxm = 1.0f - wx, wym = 1.0f - wy;
    s_cw[b][v][0][px] = (vx0 && vy0) ? wxm * wym : 0.0f;
    s_cw[b][v][1][px] = (vx1 && vy0) ? wx * wym : 0.0f;
    s_cw[b][v][2][px] = (vx0 && vy1) ? wxm * wy : 0.0f;
    s_cw[b][v][3][px] = (vx1 && vy1) ? wx * wy : 0.0f;
  };

  auto do_variance = [&](int b, int b2, int i) {
    int c = i / HALO, px = i - (i / HALO) * HALO;
    float var = 0.f;
    if (s_inb[px]) {
      const float* f0 = feats + (size_t)c * (H * W);
      float rr = f0[s_gidx[px]];
      float sum = rr, ssq = rr * rr;
#pragma unroll
      for (int v = 0; v < 2; ++v) {
        const float* fv = feats + ((size_t)(v + 1) * C + c) * (H * W);
        float val = s_cw[b][v][0][px] * fv[s_ci[b][v][0][px]] +
                    s_cw[b][v][1][px] * fv[s_ci[b][v][1][px]] +
                    s_cw[b][v][2][px] * fv[s_ci[b][v][2][px]] +
                    s_cw[b][v][3][px] * fv[s_ci[b][v][3][px]];
        sum += val;
        ssq += val * val;
      }
      float m = sum / 3.0f;
      var = ssq / 3.0f - m * m;
    }
    s_var[b2][c * HP + px] = var;
  };

  auto conv_accum = [&](int ds, int sb) {
    for (int i = tid; i < NPX * 4; i += 256) {
      int grp = i / NPX, opx = i - grp * NPX;
      int py = opx / TW, pxx = opx - py * TW;
      float a0 = 0.f, a1 = 0.f, a2 = 0.f;
      int cbase = grp * CG;
#pragma unroll
      for (int kh = 0; kh < 3; ++kh) {
#pragma unroll
        for (int kw = 0; kw < 3; ++kw) {
          int hp = (py + kh) * WB + (pxx + kw);
#pragma unroll
          for (int cc = 0; cc < CG; ++cc) {
            int c = cbase + cc;
            float vv = s_var[sb][c * HP + hp];
            const float* wp = s_w + c * 27 + kh * 3 + kw;
            a0 += vv * wp[0];
            a1 += vv * wp[9];
            a2 += vv * wp[18];
          }
        }
      }
      int t0 = ds + 1 - d0;
      int t1 = ds - d0;
      int t2 = ds - 1 - d0;
      if (t0 >= 0 && t0 < DC) atomicAdd(&s_cost[t0 * NPX + opx], a0);
      if (t1 >= 0 && t1 < DC) atomicAdd(&s_cost[t1 * NPX + opx], a1);
      if (t2 >= 0 && t2 < DC) atomicAdd(&s_cost[t2 * NPX + opx], a2);
    }
  };

  {
    int ds0 = d0 - 1;
    if (ds0 >= 0 && ds0 < DTOT)
      for (int i = tid; i < 2 * HALO; i += 256) do_coords(ds0, 0, i);
  }
  __syncthreads();

  for (int s = 0; s <= NS; ++s) {
    const int ds = d0 - 1 + s;
    const bool val_cur = (s < NS) && (ds >= 0) && (ds < DTOT);
    const bool val_next = (s + 1 < NS) && (ds + 1 >= 0) && (ds + 1 < DTOT);
    const bool val_prev = (s >= 1) && (ds - 1 >= 0) && (ds - 1 < DTOT);
    if (val_cur)
      for (int i = tid; i < VITEMS; i += 256) do_variance(s & 1, s & 1, i);
    if (val_next)
      for (int i = tid; i < 2 * HALO; i += 256) do_coords(ds + 1, (s + 1) & 1, i);
    if (val_prev) conv_accum(ds - 1, (s - 1) & 1);
    __syncthreads();
  }

  if constexpr (!EPI) {
    for (int i = tid; i < DC * NPX; i += 256) {
      int dd = i / NPX, opx = i - dd * NPX;
      int py = opx / TW, pxx = opx - py * TW;
      g_cost[(size_t)(d0 + dd) * (H * W) + (h0 + py) * W + (w0 + pxx)] = s_cost[i];
    }
  } else if (tid < NPX) {
    const int opx = tid;
    const int py = opx / TW, pxx = opx - py * TW;
    const int hp = (py + 1) * WB + (pxx + 1);
    const float base = s_dbase[hp], st = s_dstep[hp];
    float mx = -3.0e38f;
    for (int dd = 0; dd < DTOT; ++dd) mx = fmaxf(mx, s_cost[dd * NPX + opx]);
    float se = 0.f;
    for (int dd = 0; dd < DTOT; ++dd) {
      float e = expf(s_cost[dd * NPX + opx] - mx);
      s_cost[dd * NPX + opx] = e;
      se += e;
    }
    float depth = 0.f, dif = 0.f;
    for (int dd = 0; dd < DTOT; ++dd) {
      float p = s_cost[dd * NPX + opx] / se;
      s_cost[dd * NPX + opx] = p;
      depth += p * (base + (float)dd * st);
      dif += p * (float)dd;
    }
    int di = (int)dif;
    di = min(max(di, 0), DTOT - 1);
    float conf = 0.f;
    for (int k = di - 1; k <= di + 2; ++k)
      if (k >= 0 && k < DTOT) conf += s_cost[k * NPX + opx];
    float ev = 0.f;
    for (int dd = 0; dd < DTOT; ++dd) {
      float sv = base + (float)dd * st - depth;
      ev += sv * sv * s_cost[dd * NPX + opx];
    }
    ev = 1.5f * sqrtf(ev);
    int gy = h0 + py, gx = w0 + pxx;
    out_d[gy * W + gx] = depth;
    out_c[gy * W + gx] = conf;
    out_v[gy * W + gx] = ev;
  }
}

extern "C" void kernel_launch(void* const* d_in, const int* in_sizes, int n_in,
                              void* d_out, int out_size, void* d_ws, size_t ws_size,
                              hipStream_t stream) {
  const float* feats1 = (const float*)d_in[0];
  const float* feats2 = (const float*)d_in[1];
  const float* proj1 = (const float*)d_in[2];
  const float* proj2 = (const float*)d_in[3];
  const float* depthv = (const float*)d_in[4];
  const float* w1 = (const float*)d_in[6];
  const float* b1 = (const float*)d_in[7];
  const float* w2 = (const float*)d_in[8];
  const float* b2 = (const float*)d_in[9];
  float* out = (float*)d_out;
  float* ws = (float*)d_ws;

  const int nd = in_sizes[4];
  const size_t F1 = (size_t)3 * 32 * 128 * 160;     // elements
  const size_t F2 = (size_t)3 * 16 * 256 * 320;
  const size_t COST1 = (size_t)48 * 128 * 160;
  const size_t COST2 = (size_t)8 * 256 * 320;
  const size_t VAR1 = (size_t)48 * 128 * 160 * 32;  // fp16 elements
  const size_t VAR2 = (size_t)8 * 256 * 320 * 16;
  const size_t RNG2 = (size_t)2 * 256 * 320;
  const size_t HDR = 1408;
  // float-unit accounting (fp16 arrays occupy elements/2 floats)
  const size_t HUGE_FLOATS =
      HDR + COST1 + COST2 + F1 / 2 + F2 / 2 + VAR1 / 2 + VAR2 / 2 + RNG2;
  const bool huge = ws_size >= HUGE_FLOATS * sizeof(float);
  const bool mid = ws_size >= (64 + COST1) * sizeof(float);

  setup_mats_kernel<<<1, 64, 0, stream>>>(proj1, proj2, depthv, nd, ws);

  float* d1 = out;
  float* c1 = out + 20480;
  float* v1 = out + 40960;
  float* d2 = out + 61440;
  float* c2 = out + 143360;
  float* v2 = out + 225280;

  dim3 g1c(160 / 8, 128 / 8, 6), g1f(160 / 8, 128 / 8, 1), g2(320 / 8, 256 / 8, 1);

  if (huge) {
    _Float16* w2a = (_Float16*)(ws + 64);   // 864 fp16
    _Float16* w2b = (_Float16*)(ws + 512);  // 432 fp16
    float* cost1 = ws + HDR;
    float* cost2 = cost1 + COST1;
    _Float16* f1t = (_Float16*)(cost2 + COST2);
    _Float16* f2t = (_Float16*)(cost2 + COST2 + F1 / 2);
    _Float16* var1 = (_Float16*)(cost2 + COST2 + F1 / 2 + F2 / 2);
    _Float16* var2 = (_Float16*)(cost2 + COST2 + F1 / 2 + F2 / 2 + VAR1 / 2);
    float2* rng2 = (float2*)(cost2 + COST2 + F1 / 2 + F2 / 2 + VAR1 / 2 + VAR2 / 2);
    relayout_w_f16_kernel<<<4, 256, 0, stream>>>(w1, w2a, 32);
    relayout_w_f16_kernel<<<2, 256, 0, stream>>>(w2, w2b, 16);
    transpose_f16_kernel<<<(int)((F1 + 255) / 256), 256, 0, stream>>>(feats1, f1t, 32, 128, 160);
    transpose_f16_kernel<<<(int)((F2 + 255) / 256), 256, 0, stream>>>(feats2, f2t, 16, 256, 320);
    // stage 1
    gather_var_kernel<32, 48, 128, 160, false>
        <<<(int)((VAR1 / 8 + 255) / 256), 256, 0, stream>>>(f1t, ws, ws + 48, nullptr, var1);
    conv_cost_kernel<32, 48, 8, 128, 160><<<g1c, 256, 0, stream>>>(
        (const uint4*)var1, w2a, b1, cost1);
    epilogue_kernel<48, 128, 160, false><<<80, 256, 0, stream>>>(
        cost1, ws + 48, nullptr, d1, c1, v1);
    // stage 2
    range_kernel<8, 256, 320><<<320, 256, 0, stream>>>(d1, v1, rng2);
    gather_var_kernel<16, 8, 256, 320, true>
        <<<(int)((VAR2 / 8 + 255) / 256), 256, 0, stream>>>(f2t, ws + 24, ws + 48, rng2, var2);
    conv_cost_kernel<16, 8, 8, 256, 320><<<dim3(40, 32, 1), 256, 0, stream>>>(
        (const uint4*)var2, w2b, b2, cost2);
    epilogue_kernel<8, 256, 320, true><<<320, 256, 0, stream>>>(
        cost2, ws + 48, rng2, d2, c2, v2);
  } else if (mid) {
    float* cost1 = ws + 64;
    cost_kernel<32, 48, 8, 8, 8, 128, 160, false, false><<<g1c, 256, 0, stream>>>(
        feats1, w1, b1, ws, ws + 48, nullptr, nullptr, cost1, nullptr, nullptr, nullptr);
    epilogue_kernel<48, 128, 160, false><<<80, 256, 0, stream>>>(
        cost1, ws + 48, nullptr, d1, c1, v1);
    cost_kernel<16, 8, 8, 8, 8, 256, 320, true, true><<<g2, 256, 0, stream>>>(
        feats2, w2, b2, ws + 24, ws + 48, d1, v1, nullptr, d2, c2, v2);
  } else {
    cost_kernel<32, 48, 48, 8, 8, 128, 160, false, true><<<g1f, 256, 0, stream>>>(
        feats1, w1, b1, ws, ws + 48, nullptr, nullptr, nullptr, d1, c1, v1);
    cost_kernel<16, 8, 8, 8, 8, 256, 320, true, true><<<g2, 256, 0, stream>>>(
        feats2, w2, b2, ws + 24, ws + 48, d1, v1, nullptr, d2, c2, v2);
  }
}

// Round 9
// 301.501 us; speedup vs baseline: 4.8335x; 1.0300x over previous
//
#include <hip/hip_runtime.h>
#include <math.h>

// ---------------------------------------------------------------------------
// CoarseMVSNet, de-fused fp16 pipeline (R9):
//   setup_mats_kernel    : mats + fp16 weight relayout (merged, 1 dispatch)
//   transpose_f16_kernel : LDS-tiled coalesced fp32 (V,C,H,W) -> fp16 (V,H,W,C)
//   gather_var_kernel    : 1 thread = 8 channels of var volume, fp32 math.
//   conv_cost_kernel     : 3x3x3 conv, fp16 var, v_dot2_f32_f16, batched
//                          uniform weights, DEPTH-3 staging pipeline (R8
//                          post-mortem: only 2 loads in flight -> MLP-starved
//                          at 805 GB/s with VALU 26%).
//   range/epilogue       : fp32 softmax head.
// __launch_bounds__(256) ONLY (R2: (256,4) forced VGPR->64, 4.2 GB spill).
// ---------------------------------------------------------------------------

typedef _Float16 half2_t __attribute__((ext_vector_type(2)));
typedef _Float16 half8_t __attribute__((ext_vector_type(8)));

union U4H { uint4 u; half2_t h[4]; };
union U2H { uint2 u; half2_t h[2]; };

static __device__ inline float fdot2f(half2_t a, half2_t b, float c) {
#if __has_builtin(__builtin_amdgcn_fdot2)
  return __builtin_amdgcn_fdot2(a, b, c, false);
#else
  return c + (float)a[0] * (float)b[0] + (float)a[1] * (float)b[1];
#endif
}

// mats (thread 0) + fp16 weight relayout w[c][kd][kh][kw] -> w2h[(t*3+kd)][c]
__global__ void setup_mats_kernel(const float* __restrict__ proj1,
                                  const float* __restrict__ proj2,
                                  const float* __restrict__ depthv, int nd,
                                  float* __restrict__ ws,
                                  const float* __restrict__ w1,
                                  const float* __restrict__ w2,
                                  _Float16* __restrict__ w2a,
                                  _Float16* __restrict__ w2b) {
  const int tid = threadIdx.x;
  if (w2a != nullptr) {
    for (int i = tid; i < 27 * 32; i += 256) {
      int c = i % 32, r = i / 32, kd = r % 3, t = r / 3;
      w2a[(t * 3 + kd) * 32 + c] = (_Float16)w1[c * 27 + kd * 9 + t];
    }
    for (int i = tid; i < 27 * 16; i += 256) {
      int c = i % 16, r = i / 16, kd = r % 3, t = r / 3;
      w2b[(t * 3 + kd) * 16 + c] = (_Float16)w2[c * 27 + kd * 9 + t];
    }
  }
  if (tid != 0) return;
  for (int s = 0; s < 2; ++s) {
    const float* P = s ? proj2 : proj1;  // (3,2,4,4) flat
    double comp[3][4][4];
    for (int v = 0; v < 3; ++v) {
      const float* E = P + v * 32;
      const float* K = P + v * 32 + 16;
      for (int r = 0; r < 3; ++r)
        for (int c = 0; c < 4; ++c) {
          double acc = 0.0;
          for (int k = 0; k < 3; ++k) acc += (double)K[r * 4 + k] * (double)E[k * 4 + c];
          comp[v][r][c] = acc;
        }
      for (int c = 0; c < 4; ++c) comp[v][3][c] = (double)E[12 + c];
    }
    double a[4][8];
    for (int r = 0; r < 4; ++r)
      for (int c = 0; c < 4; ++c) {
        a[r][c] = comp[0][r][c];
        a[r][4 + c] = (r == c) ? 1.0 : 0.0;
      }
    for (int col = 0; col < 4; ++col) {
      int piv = col;
      double best = fabs(a[col][col]);
      for (int r = col + 1; r < 4; ++r) {
        double t = fabs(a[r][col]);
        if (t > best) { best = t; piv = r; }
      }
      if (piv != col)
        for (int c = 0; c < 8; ++c) { double t = a[col][c]; a[col][c] = a[piv][c]; a[piv][c] = t; }
      double dv = a[col][col];
      for (int c = 0; c < 8; ++c) a[col][c] /= dv;
      for (int r = 0; r < 4; ++r)
        if (r != col) {
          double f = a[r][col];
          if (f != 0.0)
            for (int c = 0; c < 8; ++c) a[r][c] -= f * a[col][c];
        }
    }
    for (int v = 1; v < 3; ++v) {
      double Pm[3][4];
      for (int r = 0; r < 3; ++r)
        for (int c = 0; c < 4; ++c) {
          double acc = 0.0;
          for (int k = 0; k < 4; ++k) acc += comp[v][r][k] * a[k][4 + c];
          Pm[r][c] = acc;
        }
      float* o = ws + s * 24 + (v - 1) * 12;
      o[0] = (float)Pm[0][0]; o[1] = (float)Pm[0][1]; o[2] = (float)Pm[0][2];
      o[3] = (float)Pm[1][0]; o[4] = (float)Pm[1][1]; o[5] = (float)Pm[1][2];
      o[6] = (float)Pm[2][0]; o[7] = (float)Pm[2][1]; o[8] = (float)Pm[2][2];
      o[9] = (float)Pm[0][3]; o[10] = (float)Pm[1][3]; o[11] = (float)Pm[2][3];
    }
  }
  ws[48] = depthv[0];
  ws[49] = (depthv[nd - 1] - depthv[0]) / 47.0f;
}

// LDS-tiled coalesced transpose: fp32 (V,C,H,W) -> fp16 (V,H,W,C).
// grid (W/32, H, 3). Reads: 32 consecutive w per c-row. Writes: contiguous
// fp16 along c. LDS [C][33] -> conflict-free both phases.
template <int C, int H, int W>
__global__ void transpose_f16_kernel(const float* __restrict__ in,
                                     _Float16* __restrict__ out) {
  __shared__ float s_t[C][33];
  const int v = blockIdx.z, h = blockIdx.y, w0 = blockIdx.x * 32;
  const int tid = threadIdx.x;
  for (int r = tid; r < C * 32; r += 256) {
    int c = r >> 5, w = r & 31;
    s_t[c][w] = in[((size_t)(v * C + c) * H + h) * W + w0 + w];
  }
  __syncthreads();
  for (int r = tid; r < 32 * C; r += 256) {
    int w = r / C, c = r - (r / C) * C;
    out[((size_t)(v * H + h) * W + w0 + w) * C + c] = (_Float16)s_t[c][w];
  }
}

// Per-pixel depth range for STAGE2: bilinear 2x upsample of d1/v1.
template <int D, int H, int W>
__device__ inline void stage2_range(const float* __restrict__ prev_d,
                                    const float* __restrict__ prev_v,
                                    int gy, int gx, float& base, float& st) {
  constexpr int SH = H / 2, SW = W / 2;
  float syf = 0.5f * (float)gy - 0.25f;
  float sxf = 0.5f * (float)gx - 0.25f;
  syf = fminf(fmaxf(syf, 0.0f), (float)(SH - 1));
  sxf = fminf(fmaxf(sxf, 0.0f), (float)(SW - 1));
  int sy0 = (int)syf, sx0 = (int)sxf;
  float fy2 = syf - (float)sy0, fx2 = sxf - (float)sx0;
  int sy1 = min(sy0 + 1, SH - 1), sx1 = min(sx0 + 1, SW - 1);
  int j00 = sy0 * SW + sx0, j01 = sy0 * SW + sx1;
  int j10 = sy1 * SW + sx0, j11 = sy1 * SW + sx1;
  float cd = (prev_d[j00] * (1.f - fx2) + prev_d[j01] * fx2) * (1.f - fy2) +
             (prev_d[j10] * (1.f - fx2) + prev_d[j11] * fx2) * fy2;
  float cv = (prev_v[j00] * (1.f - fx2) + prev_v[j01] * fx2) * (1.f - fy2) +
             (prev_v[j10] * (1.f - fx2) + prev_v[j11] * fx2) * fy2;
  float lo = -fminf(cd, cv);
  base = cd + lo + 1e-12f;
  st = (cv - lo) / (float)(D - 1);
}

template <int D, int H, int W>
__global__ void range_kernel(const float* __restrict__ prev_d,
                             const float* __restrict__ prev_v,
                             float2* __restrict__ rng) {
  int pix = blockIdx.x * 256 + threadIdx.x;
  if (pix >= H * W) return;
  float b, s;
  stage2_range<D, H, W>(prev_d, prev_v, pix / W, pix % W, b, s);
  rng[pix] = make_float2(b, s);
}

// One thread computes 8 channels of the variance volume at (d, gy, gx).
template <int C, int DTOT, int H, int W, bool STAGE2>
__launch_bounds__(256)
__global__ void gather_var_kernel(const _Float16* __restrict__ feats,
                                  const float* __restrict__ mats,
                                  const float* __restrict__ dpar,
                                  const float2* __restrict__ rng,
                                  _Float16* __restrict__ var_out) {
  constexpr int C8 = C / 8;
  const int idx = blockIdx.x * 256 + threadIdx.x;
  if (idx >= DTOT * H * W * C8) return;
  const int cg = idx % C8;
  const int t = idx / C8;
  const int gx = t % W;
  const int t2 = t / W;
  const int gy = t2 % H;
  const int d = t2 / H;
  const int pix = gy * W + gx;

  float base, st;
  if constexpr (STAGE2) {
    float2 r = rng[pix];
    base = r.x;
    st = r.y;
  } else {
    base = dpar[0];
    st = dpar[1];
  }
  const float dep = base + (float)d * st;

  const half8_t* fp = (const half8_t*)feats;
  half8_t rh = fp[(size_t)pix * C8 + cg];
  float s[8], q[8];
#pragma unroll
  for (int j = 0; j < 8; ++j) {
    float x = (float)rh[j];
    s[j] = x;
    q[j] = x * x;
  }

#pragma unroll
  for (int v = 0; v < 2; ++v) {
    const float* M = mats + v * 12;
    float fx = (float)gx, fy = (float)gy;
    float X = (M[0] * fx + M[1] * fy + M[2]) * dep + M[9];
    float Y = (M[3] * fx + M[4] * fy + M[5]) * dep + M[10];
    float Z = (M[6] * fx + M[7] * fy + M[8]) * dep + M[11];
    float inv = 1.0f / Z;
    float xz = X * inv, yz = Y * inv;
    float gxn = xz * (2.0f / (float)(W - 1)) - 1.0f;
    float gyn = yz * (2.0f / (float)(H - 1)) - 1.0f;
    float ix = ((gxn + 1.0f) * (float)W - 1.0f) * 0.5f;
    float iy = ((gyn + 1.0f) * (float)H - 1.0f) * 0.5f;
    float x0f = floorf(ix), y0f = floorf(iy);
    float wx = ix - x0f, wy = iy - y0f;
    float x1f = x0f + 1.0f, y1f = y0f + 1.0f;
    bool vx0 = (x0f >= 0.0f) && (x0f <= (float)(W - 1));
    bool vx1 = (x1f >= 0.0f) && (x1f <= (float)(W - 1));
    bool vy0 = (y0f >= 0.0f) && (y0f <= (float)(H - 1));
    bool vy1 = (y1f >= 0.0f) && (y1f <= (float)(H - 1));
    int xc0 = (int)fminf(fmaxf(x0f, 0.0f), (float)(W - 1));
    int xc1 = (int)fminf(fmaxf(x1f, 0.0f), (float)(W - 1));
    int yc0 = (int)fminf(fmaxf(y0f, 0.0f), (float)(H - 1));
    int yc1 = (int)fminf(fmaxf(y1f, 0.0f), (float)(H - 1));
    float wxm = 1.0f - wx, wym = 1.0f - wy;
    float a00 = (vx0 && vy0) ? wxm * wym : 0.0f;
    float a10 = (vx1 && vy0) ? wx * wym : 0.0f;
    float a01 = (vx0 && vy1) ? wxm * wy : 0.0f;
    float a11 = (vx1 && vy1) ? wx * wy : 0.0f;
    const size_t vb = (size_t)(v + 1) * H * W * C8 + cg;
    half8_t p00 = fp[vb + (size_t)(yc0 * W + xc0) * C8];
    half8_t p10 = fp[vb + (size_t)(yc0 * W + xc1) * C8];
    half8_t p01 = fp[vb + (size_t)(yc1 * W + xc0) * C8];
    half8_t p11 = fp[vb + (size_t)(yc1 * W + xc1) * C8];
#pragma unroll
    for (int j = 0; j < 8; ++j) {
      float g = a00 * (float)p00[j] + a10 * (float)p10[j] +
                a01 * (float)p01[j] + a11 * (float)p11[j];
      s[j] += g;
      q[j] += g * g;
    }
  }
  half8_t o;
#pragma unroll
  for (int j = 0; j < 8; ++j) {
    float m = s[j] * (1.0f / 3.0f);
    o[j] = (_Float16)(q[j] * (1.0f / 3.0f) - m * m);
  }
  *(half8_t*)(var_out + ((size_t)(d * H + gy) * W + gx) * C + cg * 8) = o;
}

// 3x3x3 conv over fp16 var volume -> fp32 cost volume [d][pix].
// DEPTH-3 staging pipeline: loads for slice s+2 issue while conv(s) runs and
// commit(s+1) lands -> ~2 intervals of latency budget per load (R9 fix).
template <int C, int DTOT, int DC, int H, int W>
__launch_bounds__(256)
__global__ void conv_cost_kernel(const uint4* __restrict__ var_in,   // fp16 [d][pix][C]
                                 const _Float16* __restrict__ w2h,   // [tap][kd][C]
                                 const float* __restrict__ bconv,
                                 float* __restrict__ g_cost) {
  constexpr int TH = 8, TW = 8, WB = 10, HALO = 100, NPX = 64;
  constexpr int CU4 = C / 8;       // uint4 (8 fp16) per px row
  constexpr int SR4 = CU4 + 1;     // padded row stride (uint4 units)
  constexpr int NS = DC + 2;
  constexpr int NIT = HALO * CU4;
  constexpr int PFN = (NIT + 255) / 256;
  constexpr int SL = H * W * CU4;
  constexpr int CPG = C / 4;       // channels per wave-group

  __shared__ uint4 s_in[3][HALO * SR4];
  __shared__ float s_cost[DC * NPX];

  const int tid = threadIdx.x;
  const int h0 = blockIdx.y * TH;
  const int w0 = blockIdx.x * TW;
  const int d0 = blockIdx.z * DC;

  {
    float bias = bconv[0];
    for (int i = tid; i < DC * NPX; i += 256) s_cost[i] = bias;
  }

  // hoisted staging addresses
  int gbase[PFN], ldsoff[PFN];
  bool act[PFN], gval[PFN];
#pragma unroll
  for (int k = 0; k < PFN; ++k) {
    int i = tid + k * 256;
    act[k] = (i < NIT);
    int px = i / CU4, cg = i - (i / CU4) * CU4;
    int hy = px / WB, hx = px - hy * WB;
    int gy = h0 + hy - 1, gx = w0 + hx - 1;
    gval[k] = act[k] && gy >= 0 && gy < H && gx >= 0 && gx < W;
    gbase[k] = gval[k] ? ((gy * W + gx) * CU4 + cg) : 0;
    ldsoff[k] = px * SR4 + cg;
  }

  uint4 pf[2][PFN];
  auto prefetch = [&](int slot, int ds) {
    const bool dv = (ds >= 0) && (ds < DTOT);
    const size_t so = (size_t)max(ds, 0) * SL;
#pragma unroll
    for (int k = 0; k < PFN; ++k) {
      uint4 r = make_uint4(0u, 0u, 0u, 0u);
      if (dv && gval[k]) r = var_in[so + gbase[k]];
      pf[slot][k] = r;
    }
  };
  auto commit = [&](int slot, int b) {
#pragma unroll
    for (int k = 0; k < PFN; ++k)
      if (act[k]) s_in[b][ldsoff[k]] = pf[slot][k];
  };

  const int grp = tid >> 6;
  const int opx = tid & 63;
  const int py = opx >> 3, pxx = opx & 7;
  const _Float16* __restrict__ wg = w2h + __builtin_amdgcn_readfirstlane(grp * CPG);

  auto conv_accum = [&](int ds, int sb) {
    float a0 = 0.f, a1 = 0.f, a2 = 0.f;  // kd = 0,1,2
#pragma unroll
    for (int t = 0; t < 9; ++t) {
      const int kh = t / 3, kw = t - 3 * kh;
      const int hp = (py + kh) * WB + (pxx + kw);
      if constexpr (CPG == 8) {
        U4H v;
        v.u = s_in[sb][hp * SR4 + grp];
#pragma unroll
        for (int kd = 0; kd < 3; ++kd) {
          U4H w;
          w.u = *(const uint4*)(wg + (t * 3 + kd) * C);
          float acc = 0.f;
#pragma unroll
          for (int j = 0; j < 4; ++j) acc = fdot2f(v.h[j], w.h[j], acc);
          if (kd == 0) a0 += acc;
          else if (kd == 1) a1 += acc;
          else a2 += acc;
        }
      } else {  // CPG == 4
        U2H v;
        v.u = ((const uint2*)&s_in[sb][hp * SR4])[grp];
#pragma unroll
        for (int kd = 0; kd < 3; ++kd) {
          U2H w;
          w.u = *(const uint2*)(wg + (t * 3 + kd) * C);
          float acc = 0.f;
#pragma unroll
          for (int j = 0; j < 2; ++j) acc = fdot2f(v.h[j], w.h[j], acc);
          if (kd == 0) a0 += acc;
          else if (kd == 1) a1 += acc;
          else a2 += acc;
        }
      }
    }
    int t0 = ds + 1 - d0;
    int t1 = ds - d0;
    int t2 = ds - 1 - d0;
    if (t0 >= 0 && t0 < DC) atomicAdd(&s_cost[t0 * NPX + opx], a0);
    if (t1 >= 0 && t1 < DC) atomicAdd(&s_cost[t1 * NPX + opx], a1);
    if (t2 >= 0 && t2 < DC) atomicAdd(&s_cost[t2 * NPX + opx], a2);
  };

  // depth-3 pipeline over staged slices s = 0..NS-1 (ds = d0-1+s)
  prefetch(0, d0 - 1);
  commit(0, 0);
  prefetch(1, d0);
  __syncthreads();
  for (int s = 0; s < NS; ++s) {
    if (s + 2 < NS) prefetch(s & 1, d0 - 1 + s + 2);  // 2 intervals ahead
    conv_accum(d0 - 1 + s, s % 3);
    if (s + 1 < NS) commit((s + 1) & 1, (s + 1) % 3);
    __syncthreads();
  }

  for (int i = tid; i < DC * NPX; i += 256) {
    int dd = i / NPX, o = i - dd * NPX;
    int oy = o / TW, ox = o - oy * TW;
    g_cost[(size_t)(d0 + dd) * (H * W) + (h0 + oy) * W + (w0 + ox)] = s_cost[i];
  }
}

template <int D, int H, int W, bool STAGE2>
__global__ void epilogue_kernel(const float* __restrict__ g_cost,
                                const float* __restrict__ dpar,
                                const float2* __restrict__ rng,
                                float* __restrict__ out_d,
                                float* __restrict__ out_c,
                                float* __restrict__ out_v) {
  int pix = blockIdx.x * 256 + threadIdx.x;
  if (pix >= H * W) return;
  float base, st;
  if constexpr (STAGE2) {
    float2 r = rng[pix];
    base = r.x;
    st = r.y;
  } else {
    base = dpar[0];
    st = dpar[1];
  }
  float c[D];
#pragma unroll
  for (int dd = 0; dd < D; ++dd) c[dd] = g_cost[(size_t)dd * (H * W) + pix];
  float mx = -3.0e38f;
#pragma unroll
  for (int dd = 0; dd < D; ++dd) mx = fmaxf(mx, c[dd]);
  float se = 0.f;
#pragma unroll
  for (int dd = 0; dd < D; ++dd) {
    float e = expf(c[dd] - mx);
    c[dd] = e;
    se += e;
  }
  float depth = 0.f, dif = 0.f;
#pragma unroll
  for (int dd = 0; dd < D; ++dd) {
    float p = c[dd] / se;
    c[dd] = p;
    depth += p * (base + (float)dd * st);
    dif += p * (float)dd;
  }
  int di = (int)dif;
  di = min(max(di, 0), D - 1);
  float conf = 0.f;
#pragma unroll
  for (int dd = 0; dd < D; ++dd)
    if (dd >= di - 1 && dd <= di + 2) conf += c[dd];
  float ev = 0.f;
#pragma unroll
  for (int dd = 0; dd < D; ++dd) {
    float sv = base + (float)dd * st - depth;
    ev += sv * sv * c[dd];
  }
  ev = 1.5f * sqrtf(ev);
  out_d[pix] = depth;
  out_c[pix] = conf;
  out_v[pix] = ev;
}

// -------------------- fused fp32 fallback (small-ws tiers) --------------------

template <int C, int DTOT, int DC, int TH, int TW, int H, int W, bool STAGE2, bool EPI>
__launch_bounds__(256)
__global__ void cost_kernel(const float* __restrict__ feats,
                            const float* __restrict__ wconv,
                            const float* __restrict__ bconv,
                            const float* __restrict__ mats,
                            const float* __restrict__ dpar,
                            const float* __restrict__ prev_d,
                            const float* __restrict__ prev_v,
                            float* __restrict__ g_cost,
                            float* __restrict__ out_d,
                            float* __restrict__ out_c,
                            float* __restrict__ out_v) {
  constexpr int HB = TH + 2, WB = TW + 2, HALO = HB * WB, NPX = TH * TW;
  constexpr int HP = HALO + 1;
  constexpr int CG = C / 4;
  constexpr int NS = DC + 2;
  constexpr int VITEMS = HALO * C;

  __shared__ float s_var[2][C * HP];
  __shared__ float s_cost[DC * NPX];
  __shared__ float s_w[C * 27];
  __shared__ float s_rx[2][HALO], s_ry[2][HALO], s_rz[2][HALO];
  __shared__ float s_cw[2][2][4][HALO];
  __shared__ int s_ci[2][2][4][HALO];
  __shared__ int s_gidx[HALO];
  __shared__ float s_dbase[HALO], s_dstep[HALO];
  __shared__ unsigned char s_inb[HALO];

  const int tid = threadIdx.x;
  const int h0 = blockIdx.y * TH;
  const int w0 = blockIdx.x * TW;
  const int d0 = EPI ? 0 : blockIdx.z * DC;

  for (int i = tid; i < C * 27; i += 256) s_w[i] = wconv[i];

  for (int i = tid; i < HALO; i += 256) {
    int hy = i / WB, hx = i - hy * WB;
    int gy = h0 + hy - 1, gx = w0 + hx - 1;
    bool inb = (gy >= 0) && (gy < H) && (gx >= 0) && (gx < W);
    s_inb[i] = inb ? 1 : 0;
    s_gidx[i] = inb ? (gy * W + gx) : 0;
    float fx = (float)gx, fy = (float)gy;
#pragma unroll
    for (int v = 0; v < 2; ++v) {
      const float* M = mats + v * 12;
      s_rx[v][i] = M[0] * fx + M[1] * fy + M[2];
      s_ry[v][i] = M[3] * fx + M[4] * fy + M[5];
      s_rz[v][i] = M[6] * fx + M[7] * fy + M[8];
    }
    if constexpr (STAGE2) {
      float b, stp;
      stage2_range<DTOT, H, W>(prev_d, prev_v, gy, gx, b, stp);
      s_dbase[i] = b;
      s_dstep[i] = stp;
    } else {
      s_dbase[i] = dpar[0];
      s_dstep[i] = dpar[1];
    }
  }
  {
    float bias = bconv[0];
    for (int i = tid; i < DC * NPX; i += 256) s_cost[i] = bias;
  }
  __syncthreads();

  auto do_coords = [&](int ds, int b, int i) {
    int v = (i >= HALO) ? 1 : 0;
    int px = i - v * HALO;
    float dep = s_dbase[px] + (float)ds * s_dstep[px];
    const float* M = mats + v * 12;
    float X = s_rx[v][px] * dep + M[9];
    float Y = s_ry[v][px] * dep + M[10];
    float Z = s_rz[v][px] * dep + M[11];
    float inv = 1.0f / Z;
    float xz = X * inv, yz = Y * inv;
    float gxn = xz * (2.0f / (float)(W - 1)) - 1.0f;
    float gyn = yz * (2.0f / (float)(H - 1)) - 1.0f;
    float ix = ((gxn + 1.0f) * (float)W - 1.0f) * 0.5f;
    float iy = ((gyn + 1.0f) * (float)H - 1.0f) * 0.5f;
    float x0f = floorf(ix), y0f = floorf(iy);
    float wx = ix - x0f, wy = iy - y0f;
    float x1f = x0f + 1.0f, y1f = y0f + 1.0f;
    bool vx0 = (x0f >= 0.0f) && (x0f <= (float)(W - 1));
    bool vx1 = (x1f >= 0.0f) && (x1f <= (float)(W - 1));
    bool vy0 = (y0f >= 0.0f) && (y0f <= (float)(H - 1));
    bool vy1 = (y1f >= 0.0f) && (y1f <= (float)(H - 1));
    int xc0 = (int)fminf(fmaxf(x0f, 0.0f), (float)(W - 1));
    int xc1 = (int)fminf(fmaxf(x1f, 0.0f), (float)(W - 1));
    int yc0 = (int)fminf(fmaxf(y0f, 0.0f), (float)(H - 1));
    int yc1 = (int)fminf(fmaxf(y1f, 0.0f), (float)(H - 1));
    s_ci[b][v][0][px] = yc0 * W + xc0;
    s_ci[b][v][1][px] = yc0 * W + xc1;
    s_ci[b][v][2][px] = yc1 * W + xc0;
    s_ci[b][v][3][px] = yc1 * W + xc1;
    float wxm = 1.0f - wx, wym = 1.0f - wy;
    s_cw[b][v][0][px] = (vx0 && vy0) ? wxm * wym : 0.0f;
    s_cw[b][v][1][px] = (vx1 && vy0) ? wx * wym : 0.0f;
    s_cw[b][v][2][px] = (vx0 && vy1) ? wxm * wy : 0.0f;
    s_cw[b][v][3][px] = (vx1 && vy1) ? wx * wy : 0.0f;
  };

  auto do_variance = [&](int b, int b2, int i) {
    int c = i / HALO, px = i - (i / HALO) * HALO;
    float var = 0.f;
    if (s_inb[px]) {
      const float* f0 = feats + (size_t)c * (H * W);
      float rr = f0[s_gidx[px]];
      float sum = rr, ssq = rr * rr;
#pragma unroll
      for (int v = 0; v < 2; ++v) {
        const float* fv = feats + ((size_t)(v + 1) * C + c) * (H * W);
        float val = s_cw[b][v][0][px] * fv[s_ci[b][v][0][px]] +
                    s_cw[b][v][1][px] * fv[s_ci[b][v][1][px]] +
                    s_cw[b][v][2][px] * fv[s_ci[b][v][2][px]] +
                    s_cw[b][v][3][px] * fv[s_ci[b][v][3][px]];
        sum += val;
        ssq += val * val;
      }
      float m = sum / 3.0f;
      var = ssq / 3.0f - m * m;
    }
    s_var[b2][c * HP + px] = var;
  };

  auto conv_accum = [&](int ds, int sb) {
    for (int i = tid; i < NPX * 4; i += 256) {
      int grp = i / NPX, opx = i - grp * NPX;
      int py = opx / TW, pxx = opx - py * TW;
      float a0 = 0.f, a1 = 0.f, a2 = 0.f;
      int cbase = grp * CG;
#pragma unroll
      for (int kh = 0; kh < 3; ++kh) {
#pragma unroll
        for (int kw = 0; kw < 3; ++kw) {
          int hp = (py + kh) * WB + (pxx + kw);
#pragma unroll
          for (int cc = 0; cc < CG; ++cc) {
            int c = cbase + cc;
            float vv = s_var[sb][c * HP + hp];
            const float* wp = s_w + c * 27 + kh * 3 + kw;
            a0 += vv * wp[0];
            a1 += vv * wp[9];
            a2 += vv * wp[18];
          }
        }
      }
      int t0 = ds + 1 - d0;
      int t1 = ds - d0;
      int t2 = ds - 1 - d0;
      if (t0 >= 0 && t0 < DC) atomicAdd(&s_cost[t0 * NPX + opx], a0);
      if (t1 >= 0 && t1 < DC) atomicAdd(&s_cost[t1 * NPX + opx], a1);
      if (t2 >= 0 && t2 < DC) atomicAdd(&s_cost[t2 * NPX + opx], a2);
    }
  };

  {
    int ds0 = d0 - 1;
    if (ds0 >= 0 && ds0 < DTOT)
      for (int i = tid; i < 2 * HALO; i += 256) do_coords(ds0, 0, i);
  }
  __syncthreads();

  for (int s = 0; s <= NS; ++s) {
    const int ds = d0 - 1 + s;
    const bool val_cur = (s < NS) && (ds >= 0) && (ds < DTOT);
    const bool val_next = (s + 1 < NS) && (ds + 1 >= 0) && (ds + 1 < DTOT);
    const bool val_prev = (s >= 1) && (ds - 1 >= 0) && (ds - 1 < DTOT);
    if (val_cur)
      for (int i = tid; i < VITEMS; i += 256) do_variance(s & 1, s & 1, i);
    if (val_next)
      for (int i = tid; i < 2 * HALO; i += 256) do_coords(ds + 1, (s + 1) & 1, i);
    if (val_prev) conv_accum(ds - 1, (s - 1) & 1);
    __syncthreads();
  }

  if constexpr (!EPI) {
    for (int i = tid; i < DC * NPX; i += 256) {
      int dd = i / NPX, opx = i - dd * NPX;
      int py = opx / TW, pxx = opx - py * TW;
      g_cost[(size_t)(d0 + dd) * (H * W) + (h0 + py) * W + (w0 + pxx)] = s_cost[i];
    }
  } else if (tid < NPX) {
    const int opx = tid;
    const int py = opx / TW, pxx = opx - py * TW;
    const int hp = (py + 1) * WB + (pxx + 1);
    const float base = s_dbase[hp], st = s_dstep[hp];
    float mx = -3.0e38f;
    for (int dd = 0; dd < DTOT; ++dd) mx = fmaxf(mx, s_cost[dd * NPX + opx]);
    float se = 0.f;
    for (int dd = 0; dd < DTOT; ++dd) {
      float e = expf(s_cost[dd * NPX + opx] - mx);
      s_cost[dd * NPX + opx] = e;
      se += e;
    }
    float depth = 0.f, dif = 0.f;
    for (int dd = 0; dd < DTOT; ++dd) {
      float p = s_cost[dd * NPX + opx] / se;
      s_cost[dd * NPX + opx] = p;
      depth += p * (base + (float)dd * st);
      dif += p * (float)dd;
    }
    int di = (int)dif;
    di = min(max(di, 0), DTOT - 1);
    float conf = 0.f;
    for (int k = di - 1; k <= di + 2; ++k)
      if (k >= 0 && k < DTOT) conf += s_cost[k * NPX + opx];
    float ev = 0.f;
    for (int dd = 0; dd < DTOT; ++dd) {
      float sv = base + (float)dd * st - depth;
      ev += sv * sv * s_cost[dd * NPX + opx];
    }
    ev = 1.5f * sqrtf(ev);
    int gy = h0 + py, gx = w0 + pxx;
    out_d[gy * W + gx] = depth;
    out_c[gy * W + gx] = conf;
    out_v[gy * W + gx] = ev;
  }
}

extern "C" void kernel_launch(void* const* d_in, const int* in_sizes, int n_in,
                              void* d_out, int out_size, void* d_ws, size_t ws_size,
                              hipStream_t stream) {
  const float* feats1 = (const float*)d_in[0];
  const float* feats2 = (const float*)d_in[1];
  const float* proj1 = (const float*)d_in[2];
  const float* proj2 = (const float*)d_in[3];
  const float* depthv = (const float*)d_in[4];
  const float* w1 = (const float*)d_in[6];
  const float* b1 = (const float*)d_in[7];
  const float* w2 = (const float*)d_in[8];
  const float* b2 = (const float*)d_in[9];
  float* out = (float*)d_out;
  float* ws = (float*)d_ws;

  const int nd = in_sizes[4];
  const size_t F1 = (size_t)3 * 32 * 128 * 160;     // elements
  const size_t F2 = (size_t)3 * 16 * 256 * 320;
  const size_t COST1 = (size_t)48 * 128 * 160;
  const size_t COST2 = (size_t)8 * 256 * 320;
  const size_t VAR1 = (size_t)48 * 128 * 160 * 32;  // fp16 elements
  const size_t VAR2 = (size_t)8 * 256 * 320 * 16;
  const size_t RNG2 = (size_t)2 * 256 * 320;
  const size_t HDR = 1408;
  const size_t HUGE_FLOATS =
      HDR + COST1 + COST2 + F1 / 2 + F2 / 2 + VAR1 / 2 + VAR2 / 2 + RNG2;
  const bool huge = ws_size >= HUGE_FLOATS * sizeof(float);
  const bool mid = ws_size >= (64 + COST1) * sizeof(float);

  float* d1 = out;
  float* c1 = out + 20480;
  float* v1 = out + 40960;
  float* d2 = out + 61440;
  float* c2 = out + 143360;
  float* v2 = out + 225280;

  dim3 g1c(160 / 8, 128 / 8, 6), g1f(160 / 8, 128 / 8, 1), g2(320 / 8, 256 / 8, 1);

  if (huge) {
    _Float16* w2a = (_Float16*)(ws + 64);   // 864 fp16
    _Float16* w2b = (_Float16*)(ws + 512);  // 432 fp16
    float* cost1 = ws + HDR;
    float* cost2 = cost1 + COST1;
    _Float16* f1t = (_Float16*)(cost2 + COST2);
    _Float16* f2t = (_Float16*)(cost2 + COST2 + F1 / 2);
    _Float16* var1 = (_Float16*)(cost2 + COST2 + F1 / 2 + F2 / 2);
    _Float16* var2 = (_Float16*)(cost2 + COST2 + F1 / 2 + F2 / 2 + VAR1 / 2);
    float2* rng2 = (float2*)(cost2 + COST2 + F1 / 2 + F2 / 2 + VAR1 / 2 + VAR2 / 2);
    setup_mats_kernel<<<1, 256, 0, stream>>>(proj1, proj2, depthv, nd, ws, w1, w2, w2a, w2b);
    transpose_f16_kernel<32, 128, 160><<<dim3(5, 128, 3), 256, 0, stream>>>(feats1, f1t);
    transpose_f16_kernel<16, 256, 320><<<dim3(10, 256, 3), 256, 0, stream>>>(feats2, f2t);
    // stage 1
    gather_var_kernel<32, 48, 128, 160, false>
        <<<(int)((VAR1 / 8 + 255) / 256), 256, 0, stream>>>(f1t, ws, ws + 48, nullptr, var1);
    conv_cost_kernel<32, 48, 8, 128, 160><<<g1c, 256, 0, stream>>>(
        (const uint4*)var1, w2a, b1, cost1);
    epilogue_kernel<48, 128, 160, false><<<80, 256, 0, stream>>>(
        cost1, ws + 48, nullptr, d1, c1, v1);
    // stage 2
    range_kernel<8, 256, 320><<<320, 256, 0, stream>>>(d1, v1, rng2);
    gather_var_kernel<16, 8, 256, 320, true>
        <<<(int)((VAR2 / 8 + 255) / 256), 256, 0, stream>>>(f2t, ws + 24, ws + 48, rng2, var2);
    conv_cost_kernel<16, 8, 8, 256, 320><<<dim3(40, 32, 1), 256, 0, stream>>>(
        (const uint4*)var2, w2b, b2, cost2);
    epilogue_kernel<8, 256, 320, true><<<320, 256, 0, stream>>>(
        cost2, ws + 48, rng2, d2, c2, v2);
  } else if (mid) {
    float* cost1 = ws + 64;
    setup_mats_kernel<<<1, 256, 0, stream>>>(proj1, proj2, depthv, nd, ws, w1, w2,
                                             nullptr, nullptr);
    cost_kernel<32, 48, 8, 8, 8, 128, 160, false, false><<<g1c, 256, 0, stream>>>(
        feats1, w1, b1, ws, ws + 48, nullptr, nullptr, cost1, nullptr, nullptr, nullptr);
    epilogue_kernel<48, 128, 160, false><<<80, 256, 0, stream>>>(
        cost1, ws + 48, nullptr, d1, c1, v1);
    cost_kernel<16, 8, 8, 8, 8, 256, 320, true, true><<<g2, 256, 0, stream>>>(
        feats2, w2, b2, ws + 24, ws + 48, d1, v1, nullptr, d2, c2, v2);
  } else {
    setup_mats_kernel<<<1, 256, 0, stream>>>(proj1, proj2, depthv, nd, ws, w1, w2,
                                             nullptr, nullptr);
    cost_kernel<32, 48, 48, 8, 8, 128, 160, false, true><<<g1f, 256, 0, stream>>>(
        feats1, w1, b1, ws, ws + 48, nullptr, nullptr, nullptr, d1, c1, v1);
    cost_kernel<16, 8, 8, 8, 8, 256, 320, true, true><<<g2, 256, 0, stream>>>(
        feats2, w2, b2, ws + 24, ws + 48, d1, v1, nullptr, d2, c2, v2);
  }
}